// Round 2
// baseline (527.979 us; speedup 1.0000x reference)
//
#include <hip/hip_runtime.h>
#include <hip/hip_bf16.h>

// Problem constants (B,S,D fixed by the reference)
#define B_ 4
#define S_ 2048
#define D_ 1024
#define CCH 64                    // chunks along S
#define LCH 32                    // chunk length; CCH*LCH == S_
#define NELEM ((size_t)B_*S_*D_)  // 8388608
#define MROWS (B_*S_)             // 8192

typedef __attribute__((ext_vector_type(4))) float f32x4;
typedef __attribute__((ext_vector_type(8))) short s16x8;  // 8 x bf16 fragment

__device__ __forceinline__ ushort f2bf(float v) {
  __hip_bfloat16 h = __float2bfloat16(v);
  return __builtin_bit_cast(ushort, h);
}
__device__ __forceinline__ float bf2f(ushort u) {
  return __bfloat162float(__builtin_bit_cast(__hip_bfloat16, u));
}

// ---------------- conversions ----------------

// x -> bf16 hi + bf16 lo (error-compensated split for the phase-critical GEMMs)
__global__ void split_x_kernel(const float* __restrict__ x,
                               ushort* __restrict__ xh, ushort* __restrict__ xl) {
  size_t i = ((size_t)blockIdx.x * blockDim.x + threadIdx.x) * 4;
  if (i >= NELEM) return;
  float4 v = *(const float4*)(x + i);
  float vv[4] = {v.x, v.y, v.z, v.w};
  ushort h[4], l[4];
#pragma unroll
  for (int j = 0; j < 4; ++j) {
    h[j] = f2bf(vv[j]);
    l[j] = f2bf(vv[j] - bf2f(h[j]));
  }
  *(ushort4*)(xh + i) = make_ushort4(h[0], h[1], h[2], h[3]);
  *(ushort4*)(xl + i) = make_ushort4(l[0], l[1], l[2], l[3]);
}

// W [Kd][Nd] f32 -> WT [Nd][Kd] bf16 (hi, optional lo). LDS-tiled, coalesced both sides.
template <int LO>
__global__ void transpose_convert(const float* __restrict__ W, ushort* __restrict__ Th,
                                  ushort* __restrict__ Tl, int Kd, int Nd) {
  __shared__ float tile[64][65];  // +1 pad: conflict-free column reads
  const int k0 = blockIdx.x * 64, n0 = blockIdx.y * 64;
  const int tx = threadIdx.x & 63, ty = threadIdx.x >> 6;  // 64 x 4
#pragma unroll
  for (int i = 0; i < 16; ++i)
    tile[ty * 16 + i][tx] = W[(size_t)(k0 + ty * 16 + i) * Nd + n0 + tx];
  __syncthreads();
#pragma unroll
  for (int i = 0; i < 16; ++i) {
    const int nn = ty * 16 + i;
    float v = tile[tx][nn];
    size_t o = (size_t)(n0 + nn) * Kd + k0 + tx;
    ushort h = f2bf(v);
    Th[o] = h;
    if (LO) Tl[o] = f2bf(v - bf2f(h));
  }
}

// ---------------- bf16 MFMA GEMM (m97-style 128x128 tile, BK=64) ----------------
// A [M][K] bf16 row-major; Bw [N][K] bf16 (pre-transposed weights).
// C addressing: logical col n maps to fp32 plane (n>>10) in a contiguous stack
// of [M][1024] arrays -> one launch can fill omega|gate|mag|phi0.
// BETA: accumulate into C. FINAL: out = acc + x + b_out.
template <int BETA, int FINAL>
__global__ __launch_bounds__(256, 2) void gemm_bf16(
    const ushort* __restrict__ A, const ushort* __restrict__ Bw,
    float* __restrict__ C, const float* __restrict__ xres,
    const float* __restrict__ bias, int M, int N, int K) {
  __shared__ __align__(16) ushort lA[128 * 64];
  __shared__ __align__(16) ushort lB[128 * 64];
  const int nTm = M >> 7;
  const int tm = blockIdx.x % nTm, tn = blockIdx.x / nTm;
  const int t = threadIdx.x, lane = t & 63;
  const int wm = (t >> 6) >> 1, wn = (t >> 6) & 1;  // 2x2 wave grid, 64x64 each

  f32x4 acc[4][4];
#pragma unroll
  for (int i = 0; i < 4; ++i)
#pragma unroll
    for (int j = 0; j < 4; ++j) acc[i][j] = (f32x4){0.f, 0.f, 0.f, 0.f};

  const ushort* aT = A + (size_t)(tm * 128) * K;
  const ushort* bT = Bw + (size_t)(tn * 128) * K;

  for (int kt = 0; kt < K; kt += 64) {
    // stage 128x64 bf16 tiles of A and B: 4 x (256 lanes x 16B) each, LDS linear
#pragma unroll
    for (int i = 0; i < 4; ++i) {
      const int off = t * 16 + i * 4096;  // byte offset in tile
      const int row = off >> 7;           // /128B per row
      const int ke = (off & 127) >> 1;    // element offset in k
      __builtin_amdgcn_global_load_lds(
          (const __attribute__((address_space(1))) void*)(aT + (size_t)row * K + kt + ke),
          (__attribute__((address_space(3))) void*)((char*)lA + off), 16, 0, 0);
      __builtin_amdgcn_global_load_lds(
          (const __attribute__((address_space(1))) void*)(bT + (size_t)row * K + kt + ke),
          (__attribute__((address_space(3))) void*)((char*)lB + off), 16, 0, 0);
    }
    __syncthreads();  // compiler emits vmcnt(0) drain before barrier (m97 structure)

    const ushort* ab = lA + ((wm * 64 + (lane & 15)) * 64) + ((lane >> 4) * 8);
    const ushort* bb = lB + ((wn * 64 + (lane & 15)) * 64) + ((lane >> 4) * 8);
#pragma unroll
    for (int ks = 0; ks < 2; ++ks) {
      s16x8 af[4], bfr[4];
#pragma unroll
      for (int i = 0; i < 4; ++i) af[i] = *(const s16x8*)(ab + i * 16 * 64 + ks * 32);
#pragma unroll
      for (int j = 0; j < 4; ++j) bfr[j] = *(const s16x8*)(bb + j * 16 * 64 + ks * 32);
#pragma unroll
      for (int i = 0; i < 4; ++i)
#pragma unroll
        for (int j = 0; j < 4; ++j)
          acc[i][j] = __builtin_amdgcn_mfma_f32_16x16x32_bf16(af[i], bfr[j], acc[i][j], 0, 0, 0);
    }
    __syncthreads();
  }

  // epilogue. C/D layout: col=lane&15, row=(lane>>4)*4+reg  [m89-verified]
#pragma unroll
  for (int i = 0; i < 4; ++i) {
    const int row0 = tm * 128 + wm * 64 + i * 16 + ((lane >> 4) << 2);
#pragma unroll
    for (int j = 0; j < 4; ++j) {
      const int col = tn * 128 + wn * 64 + j * 16 + (lane & 15);
      const size_t cb = (size_t)(col >> 10) * (size_t)M;
#pragma unroll
      for (int r = 0; r < 4; ++r) {
        const size_t idx = (cb + row0 + r) * 1024 + (col & 1023);
        float v = acc[i][j][r];
        if (BETA) v += C[idx];
        if (FINAL) v += xres[idx] + bias[col];
        C[idx] = v;
      }
    }
  }
}

// ---------------- fused elementwise / scan passes ----------------

// P1: omega_lin -> gated_omega (in place), mag_lin -> magnitude (in place)
__global__ void prep_kernel(float* __restrict__ omega_go, const float* __restrict__ gate_lin,
                            float* __restrict__ mag_io,
                            const float* __restrict__ b_om, const float* __restrict__ b_gate,
                            const float* __restrict__ b_mag, const float* __restrict__ isc) {
  size_t i = (size_t)blockIdx.x * blockDim.x + threadIdx.x;
  if (i >= NELEM) return;
  int d = (int)(i & (D_ - 1));
  float om = omega_go[i] + b_om[d];
  float g = 1.f / (1.f + __expf(-(gate_lin[i] + b_gate[d])));
  float mg = 5.f / (1.f + __expf(-(mag_io[i] + b_mag[d])));
  omega_go[i] = g * (om * fabsf(isc[d]));
  mag_io[i] = mg;
}

// P2: per-(b,chunk,d) sums of gated_omega and magnitude
__global__ void chunk_sum_kernel(const float* __restrict__ go, const float* __restrict__ mg,
                                 float* __restrict__ gsum, float* __restrict__ msum) {
  int tid = blockIdx.x * blockDim.x + threadIdx.x;
  if (tid >= B_ * CCH * D_) return;
  int d = tid & (D_ - 1), c = (tid >> 10) & (CCH - 1), b = tid >> 16;
  size_t base = ((size_t)(b * S_) + c * LCH) * D_ + d;
  float sg = 0.f, sm = 0.f;
  for (int s = 0; s < LCH; ++s) {
    sg += go[base + (size_t)s * D_];
    sm += mg[base + (size_t)s * D_];
  }
  gsum[tid] = sg;
  msum[tid] = sm;
}

// P3/P5: in-place exclusive scan of chunk totals along c, per (b,d) chain
__global__ void scan_offsets_kernel(float* __restrict__ s1, float* __restrict__ s2) {
  int tid = blockIdx.x * blockDim.x + threadIdx.x;
  if (tid >= B_ * D_) return;
  int d = tid & (D_ - 1), b = tid >> 10;
  float a1 = 0.f, a2 = 0.f;
  for (int c = 0; c < CCH; ++c) {
    size_t idx = ((size_t)(b * CCH) + c) * D_ + d;
    float v1 = s1[idx], v2 = s2[idx];
    s1[idx] = a1;
    s2[idx] = a2;
    a1 += v1;
    a2 += v2;
  }
}

// P4: chunked scan -> phi (over go), mag cumsum (over mag), local memory-term
// cumsums (over gate/phi0 bufs), ctx parts 0,1; emits tr/ti chunk totals.
__global__ void phase_scan_kernel(const float* __restrict__ x,
                                  float* __restrict__ goPhi, float* __restrict__ magC,
                                  float* __restrict__ trC, float* __restrict__ tiC,
                                  const float* __restrict__ goff, const float* __restrict__ moff,
                                  float* __restrict__ trsum, float* __restrict__ tisum,
                                  const float* __restrict__ b_phi, ushort* __restrict__ ctx) {
  int tid = blockIdx.x * blockDim.x + threadIdx.x;
  if (tid >= B_ * CCH * D_) return;
  int d = tid & (D_ - 1), c = (tid >> 10) & (CCH - 1), b = tid >> 16;
  size_t base = ((size_t)(b * S_) + c * LCH) * D_ + d;
  float phi_run = goff[tid], mag_run = moff[tid];
  float tr = 0.f, ti = 0.f;
  const float bp = b_phi[d];
  size_t crow = ((size_t)(b * S_ + c * LCH)) * 4096 + d;
  for (int s = 0; s < LCH; ++s) {
    size_t i = base + (size_t)s * D_;
    phi_run += goPhi[i];
    float phi = tiC[i] + bp + phi_run;  // tiC holds phi0_lin before overwrite
    float sp, cp;
    __sincosf(phi, &sp, &cp);
    float m = magC[i];
    mag_run += m;
    float xv = x[i];
    float wr = m * xv;
    tr += wr * cp;
    ti += wr * sp;
    goPhi[i] = phi;
    magC[i] = mag_run;
    trC[i] = tr;
    tiC[i] = ti;
    ctx[crow] = f2bf(xv * cp);
    ctx[crow + 1024] = f2bf(xv * sp);
    crow += 4096;
  }
  trsum[tid] = tr;
  tisum[tid] = ti;
}

// P6: memory normalization + complex retrieval -> ctx parts 2,3
__global__ void retrieve_kernel(const float* __restrict__ phi, const float* __restrict__ magC,
                                const float* __restrict__ trC, const float* __restrict__ tiC,
                                const float* __restrict__ qlin,
                                const float* __restrict__ troff, const float* __restrict__ tioff,
                                const float* __restrict__ b_q, ushort* __restrict__ ctx) {
  size_t i = (size_t)blockIdx.x * blockDim.x + threadIdx.x;
  if (i >= NELEM) return;
  int d = (int)(i & (D_ - 1));
  int m_ = (int)(i >> 10);
  int srow = m_ & (S_ - 1), b = m_ >> 11;
  int c = srow >> 5;  // /LCH
  int cs = ((b * CCH) + c) * D_ + d;
  float rs = rsqrtf(magC[i] + 1e-8f);
  float mr = (troff[cs] + trC[i]) * rs;
  float mi = (tioff[cs] + tiC[i]) * rs;
  float phq = phi[i] + qlin[i] + b_q[d];
  float sq, cq;
  __sincosf(phq, &sq, &cq);
  size_t crow = (size_t)m_ * 4096 + d;
  ctx[crow + 2048] = f2bf(mr * cq + mi * sq);
  ctx[crow + 3072] = f2bf(mi * cq - mr * sq);
}

// ---------------- launcher ----------------
extern "C" void kernel_launch(void* const* d_in, const int* in_sizes, int n_in,
                              void* d_out, int out_size, void* d_ws, size_t ws_size,
                              hipStream_t stream) {
  const float* x      = (const float*)d_in[0];
  const float* W_om   = (const float*)d_in[1];
  const float* b_om   = (const float*)d_in[2];
  const float* W_mag  = (const float*)d_in[3];
  const float* b_mag  = (const float*)d_in[4];
  const float* W_phi  = (const float*)d_in[5];
  const float* b_phi  = (const float*)d_in[6];
  const float* W_gate = (const float*)d_in[7];
  const float* b_gate = (const float*)d_in[8];
  const float* W_q    = (const float*)d_in[9];
  const float* b_q    = (const float*)d_in[10];
  const float* isc    = (const float*)d_in[11];
  const float* W_out  = (const float*)d_in[12];
  const float* b_out  = (const float*)d_in[13];
  float* out = (float*)d_out;

  // ---- ws layout, 213,909,504 bytes total ----
  // [0)                4 fp32 planes: omega|gate|mag|phi0 (in-place reuse)
  // [134,217,728)      ctx bf16 [8192][4096]  (67,108,864 B)
  //    overlapped (dead before ctx is written): x_hi, x_lo, WT(5 planes), WTlo(2)
  // [201,326,592)      WoutT bf16 [1024][4096] (8,388,608 B)
  // [209,715,200)      gsum|msum|trsum|tisum (4 x 1,048,576 B)
  // q_lin lives in d_out (overwritten by the final GEMM afterwards).
  const size_t WS_NEEDED = 213909504ull;
  if (ws_size < WS_NEEDED) {
    // diagnostic: clean zero output (absmax == max|ref|) instead of OOB crash
    hipMemsetAsync(d_out, 0, (size_t)out_size * sizeof(float), stream);
    return;
  }
  char* w = (char*)d_ws;
  float* planes    = (float*)w;                       // 4 x NELEM fp32
  float* omega_buf = planes;                          // omega_lin -> gated_omega -> phi
  float* gate_buf  = planes + NELEM;                  // gate_lin  -> trcum (local)
  float* mag_buf   = planes + 2 * NELEM;              // mag_lin -> magnitude -> mag cumsum
  float* phi0_buf  = planes + 3 * NELEM;              // phi0_lin -> ticum (local)
  float* q_buf     = out;                             // q_lin (d_out as scratch)
  char* ctxb = w + 4 * NELEM * 4;
  ushort* ctx  = (ushort*)ctxb;                       // [8192][4096] bf16
  ushort* x_hi = (ushort*)ctxb;                       // overlap: dead after GEMM1
  ushort* x_lo = (ushort*)(ctxb + 16777216);
  ushort* WT   = (ushort*)(ctxb + 33554432);          // hi: om|gate|mag|phi0|q
  ushort* WTlo = (ushort*)(ctxb + 44040192);          // lo: om|gate
  ushort* WoutT = (ushort*)(w + 201326592);           // [1024][4096]
  float* gsum  = (float*)(w + 209715200);
  float* msum  = (float*)(w + 210763776);
  float* trsum = (float*)(w + 211812352);
  float* tisum = (float*)(w + 212860928);

  const size_t DD = (size_t)D_ * D_;

  // conversions
  split_x_kernel<<<(int)(NELEM / 1024), 256, 0, stream>>>(x, x_hi, x_lo);
  dim3 tg(16, 16);
  transpose_convert<1><<<tg, 256, 0, stream>>>(W_om,   WT + 0 * DD, WTlo + 0 * DD, D_, D_);
  transpose_convert<1><<<tg, 256, 0, stream>>>(W_gate, WT + 1 * DD, WTlo + 1 * DD, D_, D_);
  transpose_convert<0><<<tg, 256, 0, stream>>>(W_mag,  WT + 2 * DD, nullptr, D_, D_);
  transpose_convert<0><<<tg, 256, 0, stream>>>(W_phi,  WT + 3 * DD, nullptr, D_, D_);
  transpose_convert<0><<<tg, 256, 0, stream>>>(W_q,    WT + 4 * DD, nullptr, D_, D_);
  transpose_convert<0><<<dim3(64, 16), 256, 0, stream>>>(W_out, WoutT, nullptr, 4 * D_, D_);

  // GEMM1: 4 projections into planes (hi*hi); q projection into d_out;
  // then hi/lo compensation for omega & gate (first two planes / WT cols)
  gemm_bf16<0, 0><<<64 * 32, 256, 0, stream>>>(x_hi, WT,          planes, nullptr, nullptr, MROWS, 4 * D_, D_);
  gemm_bf16<0, 0><<<64 * 8,  256, 0, stream>>>(x_hi, WT + 4 * DD, q_buf,  nullptr, nullptr, MROWS, D_, D_);
  gemm_bf16<1, 0><<<64 * 16, 256, 0, stream>>>(x_hi, WTlo,        planes, nullptr, nullptr, MROWS, 2 * D_, D_);
  gemm_bf16<1, 0><<<64 * 16, 256, 0, stream>>>(x_lo, WT,          planes, nullptr, nullptr, MROWS, 2 * D_, D_);

  // scans + fused elementwise
  prep_kernel<<<(int)((NELEM + 255) / 256), 256, 0, stream>>>(omega_buf, gate_buf, mag_buf,
                                                              b_om, b_gate, b_mag, isc);
  chunk_sum_kernel<<<(B_ * CCH * D_ + 255) / 256, 256, 0, stream>>>(omega_buf, mag_buf, gsum, msum);
  scan_offsets_kernel<<<(B_ * D_ + 255) / 256, 256, 0, stream>>>(gsum, msum);
  phase_scan_kernel<<<(B_ * CCH * D_ + 255) / 256, 256, 0, stream>>>(
      x, omega_buf, mag_buf, gate_buf, phi0_buf, gsum, msum, trsum, tisum, b_phi, ctx);
  scan_offsets_kernel<<<(B_ * D_ + 255) / 256, 256, 0, stream>>>(trsum, tisum);
  retrieve_kernel<<<(int)((NELEM + 255) / 256), 256, 0, stream>>>(
      omega_buf, mag_buf, gate_buf, phi0_buf, q_buf, trsum, tisum, b_q, ctx);

  // final: out = x + ctx @ W_out + b_out  (overwrites q_lin scratch)
  gemm_bf16<0, 1><<<64 * 8, 256, 0, stream>>>(ctx, WoutT, out, x, b_out, MROWS, D_, 4 * D_);
}

// Round 3
// 483.487 us; speedup vs baseline: 1.0920x; 1.0920x over previous
//
#include <hip/hip_runtime.h>
#include <hip/hip_bf16.h>

// Problem constants (B,S,D fixed by the reference)
#define B_ 4
#define S_ 2048
#define D_ 1024
#define CCH 64                    // chunks along S
#define LCH 32                    // chunk length; CCH*LCH == S_
#define NELEM ((size_t)B_*S_*D_)  // 8388608
#define MROWS (B_*S_)             // 8192

typedef __attribute__((ext_vector_type(4))) float f32x4;
typedef __attribute__((ext_vector_type(8))) short s16x8;  // 8 x bf16 fragment

__device__ __forceinline__ ushort f2bf(float v) {
  __hip_bfloat16 h = __float2bfloat16(v);
  return __builtin_bit_cast(ushort, h);
}
__device__ __forceinline__ float bf2f(ushort u) {
  return __bfloat162float(__builtin_bit_cast(__hip_bfloat16, u));
}

__device__ __forceinline__ void gload16(const ushort* src, char* ldsdst) {
  __builtin_amdgcn_global_load_lds(
      (const __attribute__((address_space(1))) void*)src,
      (__attribute__((address_space(3))) void*)ldsdst, 16, 0, 0);
}

// ---------------- conversions ----------------

// x -> A2 = [x_hi | x_lo] row-major [M][2048] (error-compensated split)
__global__ void split_x_kernel(const float* __restrict__ x, ushort* __restrict__ x2) {
  size_t i = ((size_t)blockIdx.x * blockDim.x + threadIdx.x) * 4;
  if (i >= NELEM) return;
  float4 v = *(const float4*)(x + i);
  float vv[4] = {v.x, v.y, v.z, v.w};
  ushort h[4], l[4];
#pragma unroll
  for (int j = 0; j < 4; ++j) {
    h[j] = f2bf(vv[j]);
    l[j] = f2bf(vv[j] - bf2f(h[j]));
  }
  size_t m = i >> 10, d = i & 1023;
  *(ushort4*)(x2 + m * 2048 + d) = make_ushort4(h[0], h[1], h[2], h[3]);
  *(ushort4*)(x2 + m * 2048 + 1024 + d) = make_ushort4(l[0], l[1], l[2], l[3]);
}

// W [Kd][Nd] f32 -> Th[n*sh+k] bf16 hi; if LO also Tl[n*sl+k] = lo, Th2[n*sl+k] = hi.
template <int LO>
__global__ void transpose_convert(const float* __restrict__ W, ushort* __restrict__ Th, int sh,
                                  ushort* __restrict__ Tl, ushort* __restrict__ Th2, int sl,
                                  int Kd, int Nd) {
  __shared__ float tile[64][65];  // +1 pad: conflict-free column reads
  const int k0 = blockIdx.x * 64, n0 = blockIdx.y * 64;
  const int tx = threadIdx.x & 63, ty = threadIdx.x >> 6;  // 64 x 4
#pragma unroll
  for (int i = 0; i < 16; ++i)
    tile[ty * 16 + i][tx] = W[(size_t)(k0 + ty * 16 + i) * Nd + n0 + tx];
  __syncthreads();
#pragma unroll
  for (int i = 0; i < 16; ++i) {
    const int nn = ty * 16 + i;
    float v = tile[tx][nn];
    ushort h = f2bf(v);
    Th[(size_t)(n0 + nn) * sh + k0 + tx] = h;
    if (LO) {
      size_t o = (size_t)(n0 + nn) * sl + k0 + tx;
      Tl[o] = f2bf(v - bf2f(h));
      Th2[o] = h;
    }
  }
}

// ---------------- 256x256 deep-pipelined bf16 MFMA GEMM ----------------
// A [M][lda] bf16; Bw [N][K] bf16 (pre-transposed weights, stride == K).
// 8 waves (2m x 4n), wave tile 128x64, BK=32 slices, 4 LDS slice buffers.
// Counted vmcnt: stage slice j+3 while computing j; wait leaves j+2,j+3 in flight.
// C plane stacking: col>>10 selects fp32 plane in C (or C4 for plane 4).
template <int BETA, int FINAL>
__global__ __launch_bounds__(512, 2) void gemm256(
    const ushort* __restrict__ A, int lda, const ushort* __restrict__ Bw,
    float* __restrict__ C, float* __restrict__ C4,
    const float* __restrict__ xres, const float* __restrict__ bias,
    int M, int N, int K) {
  __shared__ __align__(16) ushort lds[4 * 16384];  // 4 slices x 32KB (A 16KB | B 16KB)
  const int nTm = M >> 8;
  const int tm = blockIdx.x % nTm, tn = blockIdx.x / nTm;
  const int t = threadIdx.x, lane = t & 63, wid = t >> 6;
  const int wm = wid >> 2, wn = wid & 3;

  f32x4 acc[8][4];
#pragma unroll
  for (int i = 0; i < 8; ++i)
#pragma unroll
    for (int j = 0; j < 4; ++j) acc[i][j] = (f32x4){0.f, 0.f, 0.f, 0.f};

  const int NS = K >> 5;  // BK=32 slices

  // ---- stage addressing (pre-swizzled global source, linear LDS dest) ----
  // LDS A region: [256 rows][32 k] bf16, row = 64B. physical granule g holds
  // logical granule g ^ ((row>>1)&3)  (2-way bank aliasing on reads = free).
  const int rowA = wid * 16 + (lane >> 2);              // 0..255 over q in {0,1}
  const int gl = (lane & 3) ^ ((lane >> 3) & 3);        // logical granule fetched
  const ushort* pA0 = A + (size_t)(tm * 256 + rowA) * lda + gl * 8;
  const ushort* pA1 = pA0 + (size_t)128 * lda;
  const ushort* pB0 = Bw + (size_t)(tn * 256 + rowA) * K + gl * 8;
  const ushort* pB1 = pB0 + (size_t)128 * K;
  const int dstOff = wid * 1024 + lane * 16;            // bytes, wave-uniform + lane*16

  auto STAGE = [&](int s) {
    char* base = (char*)lds + (size_t)(s & 3) * 32768;
    const int ke = s * 32;
    gload16(pA0 + ke, base + dstOff);
    gload16(pA1 + ke, base + 8192 + dstOff);
    gload16(pB0 + ke, base + 16384 + dstOff);
    gload16(pB1 + ke, base + 24576 + dstOff);
  };

  // ---- fragment read addressing (swizzled granule) ----
  const int sR = ((lane & 15) >> 1) & 3;
  const int gp = (lane >> 4) ^ sR;                      // physical granule
  const int aoffB = (wm * 128 + (lane & 15)) * 64 + (gp << 4);
  const int boffB = 16384 + (wn * 64 + (lane & 15)) * 64 + (gp << 4);

  // prologue: 3 slices in flight
  STAGE(0); STAGE(1); STAGE(2);
  asm volatile("s_waitcnt vmcnt(8)" ::: "memory");      // slice 0 landed
  __builtin_amdgcn_sched_barrier(0);
  __builtin_amdgcn_s_barrier();

  for (int j = 0; j < NS; ++j) {
    if (j + 3 < NS) STAGE(j + 3);
    __builtin_amdgcn_sched_barrier(0);
    const char* buf = (const char*)lds + (size_t)(j & 3) * 32768;
    s16x8 af[8], bfr[4];
#pragma unroll
    for (int i = 0; i < 8; ++i) af[i] = *(const s16x8*)(buf + aoffB + i * 1024);
#pragma unroll
    for (int jj = 0; jj < 4; ++jj) bfr[jj] = *(const s16x8*)(buf + boffB + jj * 1024);
    __builtin_amdgcn_s_setprio(1);
#pragma unroll
    for (int i = 0; i < 8; ++i)
#pragma unroll
      for (int jj = 0; jj < 4; ++jj)
        acc[i][jj] = __builtin_amdgcn_mfma_f32_16x16x32_bf16(af[i], bfr[jj], acc[i][jj], 0, 0, 0);
    __builtin_amdgcn_s_setprio(0);
    if (j < NS - 1) {
      const int rem = NS - 2 - j;  // slices staged after j+1
      if (rem >= 2)      asm volatile("s_waitcnt vmcnt(8)" ::: "memory");
      else if (rem == 1) asm volatile("s_waitcnt vmcnt(4)" ::: "memory");
      else               asm volatile("s_waitcnt vmcnt(0)" ::: "memory");
      __builtin_amdgcn_sched_barrier(0);
      __builtin_amdgcn_s_barrier();
    }
  }

  // epilogue. C/D layout: col=lane&15, row=(lane>>4)*4+reg  [m89-verified]
#pragma unroll
  for (int i = 0; i < 8; ++i) {
    const int row0 = tm * 256 + wm * 128 + i * 16 + ((lane >> 4) << 2);
#pragma unroll
    for (int jj = 0; jj < 4; ++jj) {
      const int col = tn * 256 + wn * 64 + jj * 16 + (lane & 15);
      const int pl = col >> 10;
      float* base = (FINAL || pl < 4) ? (C + (size_t)pl * (size_t)M * 1024) : C4;
#pragma unroll
      for (int r = 0; r < 4; ++r) {
        const size_t idx = (size_t)(row0 + r) * 1024 + (col & 1023);
        float v = acc[i][jj][r];
        if (BETA) v += base[idx];
        if (FINAL) v += xres[idx] + bias[col];
        base[idx] = v;
      }
    }
  }
}

// ---------------- fused elementwise / scan passes ----------------

// P1: omega_lin -> gated_omega (in place), mag_lin -> magnitude (in place)
__global__ void prep_kernel(float* __restrict__ omega_go, const float* __restrict__ gate_lin,
                            float* __restrict__ mag_io,
                            const float* __restrict__ b_om, const float* __restrict__ b_gate,
                            const float* __restrict__ b_mag, const float* __restrict__ isc) {
  size_t i = (size_t)blockIdx.x * blockDim.x + threadIdx.x;
  if (i >= NELEM) return;
  int d = (int)(i & (D_ - 1));
  float om = omega_go[i] + b_om[d];
  float g = 1.f / (1.f + __expf(-(gate_lin[i] + b_gate[d])));
  float mg = 5.f / (1.f + __expf(-(mag_io[i] + b_mag[d])));
  omega_go[i] = g * (om * fabsf(isc[d]));
  mag_io[i] = mg;
}

// P2: per-(b,chunk,d) sums of gated_omega and magnitude
__global__ void chunk_sum_kernel(const float* __restrict__ go, const float* __restrict__ mg,
                                 float* __restrict__ gsum, float* __restrict__ msum) {
  int tid = blockIdx.x * blockDim.x + threadIdx.x;
  if (tid >= B_ * CCH * D_) return;
  int d = tid & (D_ - 1), c = (tid >> 10) & (CCH - 1), b = tid >> 16;
  size_t base = ((size_t)(b * S_) + c * LCH) * D_ + d;
  float sg = 0.f, sm = 0.f;
  for (int s = 0; s < LCH; ++s) {
    sg += go[base + (size_t)s * D_];
    sm += mg[base + (size_t)s * D_];
  }
  gsum[tid] = sg;
  msum[tid] = sm;
}

// P3/P5: in-place exclusive scan of chunk totals along c, per (b,d) chain
__global__ void scan_offsets_kernel(float* __restrict__ s1, float* __restrict__ s2) {
  int tid = blockIdx.x * blockDim.x + threadIdx.x;
  if (tid >= B_ * D_) return;
  int d = tid & (D_ - 1), b = tid >> 10;
  float a1 = 0.f, a2 = 0.f;
  for (int c = 0; c < CCH; ++c) {
    size_t idx = ((size_t)(b * CCH) + c) * D_ + d;
    float v1 = s1[idx], v2 = s2[idx];
    s1[idx] = a1;
    s2[idx] = a2;
    a1 += v1;
    a2 += v2;
  }
}

// P4: chunked scan -> phi (over go), mag cumsum (over mag), local memory-term
// cumsums (over gate/phi0 bufs), ctx parts 0,1; emits tr/ti chunk totals.
__global__ void phase_scan_kernel(const float* __restrict__ x,
                                  float* __restrict__ goPhi, float* __restrict__ magC,
                                  float* __restrict__ trC, float* __restrict__ tiC,
                                  const float* __restrict__ goff, const float* __restrict__ moff,
                                  float* __restrict__ trsum, float* __restrict__ tisum,
                                  const float* __restrict__ b_phi, ushort* __restrict__ ctx) {
  int tid = blockIdx.x * blockDim.x + threadIdx.x;
  if (tid >= B_ * CCH * D_) return;
  int d = tid & (D_ - 1), c = (tid >> 10) & (CCH - 1), b = tid >> 16;
  size_t base = ((size_t)(b * S_) + c * LCH) * D_ + d;
  float phi_run = goff[tid], mag_run = moff[tid];
  float tr = 0.f, ti = 0.f;
  const float bp = b_phi[d];
  size_t crow = ((size_t)(b * S_ + c * LCH)) * 4096 + d;
  for (int s = 0; s < LCH; ++s) {
    size_t i = base + (size_t)s * D_;
    phi_run += goPhi[i];
    float phi = tiC[i] + bp + phi_run;  // tiC holds phi0_lin before overwrite
    float sp, cp;
    __sincosf(phi, &sp, &cp);
    float m = magC[i];
    mag_run += m;
    float xv = x[i];
    float wr = m * xv;
    tr += wr * cp;
    ti += wr * sp;
    goPhi[i] = phi;
    magC[i] = mag_run;
    trC[i] = tr;
    tiC[i] = ti;
    ctx[crow] = f2bf(xv * cp);
    ctx[crow + 1024] = f2bf(xv * sp);
    crow += 4096;
  }
  trsum[tid] = tr;
  tisum[tid] = ti;
}

// P6: memory normalization + complex retrieval -> ctx parts 2,3
__global__ void retrieve_kernel(const float* __restrict__ phi, const float* __restrict__ magC,
                                const float* __restrict__ trC, const float* __restrict__ tiC,
                                const float* __restrict__ qlin,
                                const float* __restrict__ troff, const float* __restrict__ tioff,
                                const float* __restrict__ b_q, ushort* __restrict__ ctx) {
  size_t i = (size_t)blockIdx.x * blockDim.x + threadIdx.x;
  if (i >= NELEM) return;
  int d = (int)(i & (D_ - 1));
  int m_ = (int)(i >> 10);
  int srow = m_ & (S_ - 1), b = m_ >> 11;
  int c = srow >> 5;  // /LCH
  int cs = ((b * CCH) + c) * D_ + d;
  float rs = rsqrtf(magC[i] + 1e-8f);
  float mr = (troff[cs] + trC[i]) * rs;
  float mi = (tioff[cs] + tiC[i]) * rs;
  float phq = phi[i] + qlin[i] + b_q[d];
  float sq, cq;
  __sincosf(phq, &sq, &cq);
  size_t crow = (size_t)m_ * 4096 + d;
  ctx[crow + 2048] = f2bf(mr * cq + mi * sq);
  ctx[crow + 3072] = f2bf(mi * cq - mr * sq);
}

// ---------------- launcher ----------------
extern "C" void kernel_launch(void* const* d_in, const int* in_sizes, int n_in,
                              void* d_out, int out_size, void* d_ws, size_t ws_size,
                              hipStream_t stream) {
  const float* x      = (const float*)d_in[0];
  const float* W_om   = (const float*)d_in[1];
  const float* b_om   = (const float*)d_in[2];
  const float* W_mag  = (const float*)d_in[3];
  const float* b_mag  = (const float*)d_in[4];
  const float* W_phi  = (const float*)d_in[5];
  const float* b_phi  = (const float*)d_in[6];
  const float* W_gate = (const float*)d_in[7];
  const float* b_gate = (const float*)d_in[8];
  const float* W_q    = (const float*)d_in[9];
  const float* b_q    = (const float*)d_in[10];
  const float* isc    = (const float*)d_in[11];
  const float* W_out  = (const float*)d_in[12];
  const float* b_out  = (const float*)d_in[13];
  float* out = (float*)d_out;

  // ---- ws layout, 213,909,504 bytes total ----
  // [0)             4 fp32 planes: omega|gate|mag|phi0 (in-place reuse)
  // [134,217,728)   ctx bf16 [8192][4096] (67,108,864 B)
  //    overlapped (dead before ctx written): x2 (32MB), WT (10MB), Wcomp (8MB)
  // [201,326,592)   WoutT bf16 [1024][4096]
  // [209,715,200)   gsum|msum|trsum|tisum (4 x 1,048,576 B)
  // q_lin lives in d_out (overwritten by the final GEMM afterwards).
  const size_t WS_NEEDED = 213909504ull;
  if (ws_size < WS_NEEDED) {
    hipMemsetAsync(d_out, 0, (size_t)out_size * sizeof(float), stream);
    return;
  }
  char* w = (char*)d_ws;
  float* planes    = (float*)w;                       // 4 x NELEM fp32
  float* omega_buf = planes;                          // omega_lin -> gated_omega -> phi
  float* gate_buf  = planes + NELEM;                  // gate_lin  -> trcum (local)
  float* mag_buf   = planes + 2 * NELEM;              // mag_lin -> magnitude -> mag cumsum
  float* phi0_buf  = planes + 3 * NELEM;              // phi0_lin -> ticum (local)
  float* q_buf     = out;                             // q_lin (d_out as scratch)
  char* ctxb = w + 4 * NELEM * 4;
  ushort* ctx   = (ushort*)ctxb;                      // [8192][4096] bf16
  ushort* x2    = (ushort*)ctxb;                      // [8192][2048] = [hi|lo]
  ushort* WT    = (ushort*)(ctxb + 33554432);         // hi: om|gate|mag|phi0|q, [n][1024]
  ushort* Wcomp = (ushort*)(ctxb + 44040192);         // [2048 n][2048 k] = [W_lo | W_hi]
  ushort* WoutT = (ushort*)(w + 201326592);           // [1024][4096]
  float* gsum  = (float*)(w + 209715200);
  float* msum  = (float*)(w + 210763776);
  float* trsum = (float*)(w + 211812352);
  float* tisum = (float*)(w + 212860928);

  const size_t DD = (size_t)D_ * D_;

  // conversions
  split_x_kernel<<<(int)(NELEM / 1024), 256, 0, stream>>>(x, x2);
  dim3 tg(16, 16);
  transpose_convert<1><<<tg, 256, 0, stream>>>(W_om,   WT + 0 * DD, 1024,
                                               Wcomp, Wcomp + 1024, 2048, D_, D_);
  transpose_convert<1><<<tg, 256, 0, stream>>>(W_gate, WT + 1 * DD, 1024,
                                               Wcomp + 1024 * 2048, Wcomp + 1024 * 2048 + 1024,
                                               2048, D_, D_);
  transpose_convert<0><<<tg, 256, 0, stream>>>(W_mag,  WT + 2 * DD, 1024, nullptr, nullptr, 0, D_, D_);
  transpose_convert<0><<<tg, 256, 0, stream>>>(W_phi,  WT + 3 * DD, 1024, nullptr, nullptr, 0, D_, D_);
  transpose_convert<0><<<tg, 256, 0, stream>>>(W_q,    WT + 4 * DD, 1024, nullptr, nullptr, 0, D_, D_);
  transpose_convert<0><<<dim3(64, 16), 256, 0, stream>>>(W_out, WoutT, 4096, nullptr, nullptr, 0,
                                                         4 * D_, D_);

  // GEMM1: 5 projections (hi*hi), q plane -> d_out scratch. N=5120, K=1024.
  gemm256<0, 0><<<32 * 20, 512, 0, stream>>>(x2, 2048, WT, planes, q_buf, nullptr, nullptr,
                                             MROWS, 5 * D_, D_);
  // compensation: omega/gate += x_hi@W_lo + x_lo@W_hi. N=2048, K=2048.
  gemm256<1, 0><<<32 * 8, 512, 0, stream>>>(x2, 2048, Wcomp, planes, nullptr, nullptr, nullptr,
                                            MROWS, 2 * D_, 2 * D_);

  // scans + fused elementwise
  prep_kernel<<<(int)((NELEM + 255) / 256), 256, 0, stream>>>(omega_buf, gate_buf, mag_buf,
                                                              b_om, b_gate, b_mag, isc);
  chunk_sum_kernel<<<(B_ * CCH * D_ + 255) / 256, 256, 0, stream>>>(omega_buf, mag_buf, gsum, msum);
  scan_offsets_kernel<<<(B_ * D_ + 255) / 256, 256, 0, stream>>>(gsum, msum);
  phase_scan_kernel<<<(B_ * CCH * D_ + 255) / 256, 256, 0, stream>>>(
      x, omega_buf, mag_buf, gate_buf, phi0_buf, gsum, msum, trsum, tisum, b_phi, ctx);
  scan_offsets_kernel<<<(B_ * D_ + 255) / 256, 256, 0, stream>>>(trsum, tisum);
  retrieve_kernel<<<(int)((NELEM + 255) / 256), 256, 0, stream>>>(
      omega_buf, mag_buf, gate_buf, phi0_buf, q_buf, trsum, tisum, b_q, ctx);

  // final: out = x + ctx @ W_out + b_out  (overwrites q_lin scratch). K=4096.
  gemm256<0, 1><<<32 * 4, 512, 0, stream>>>(ctx, 4096, WoutT, out, nullptr, x, b_out,
                                            MROWS, D_, 4 * D_);
}

// Round 4
// 475.066 us; speedup vs baseline: 1.1114x; 1.0177x over previous
//
#include <hip/hip_runtime.h>
#include <hip/hip_bf16.h>

// Problem constants (B,S,D fixed by the reference)
#define B_ 4
#define S_ 2048
#define D_ 1024
#define CCH 64                    // chunks along S
#define LCH 32                    // chunk length; CCH*LCH == S_
#define NELEM ((size_t)B_*S_*D_)  // 8388608
#define MROWS (B_*S_)             // 8192

typedef __attribute__((ext_vector_type(4))) float f32x4;
typedef __attribute__((ext_vector_type(8))) short s16x8;  // 8 x bf16 fragment

__device__ __forceinline__ ushort f2bf(float v) {
  __hip_bfloat16 h = __float2bfloat16(v);
  return __builtin_bit_cast(ushort, h);
}
__device__ __forceinline__ float bf2f(ushort u) {
  return __bfloat162float(__builtin_bit_cast(__hip_bfloat16, u));
}

__device__ __forceinline__ void gload16(const ushort* src, char* ldsdst) {
  __builtin_amdgcn_global_load_lds(
      (const __attribute__((address_space(1))) void*)src,
      (__attribute__((address_space(3))) void*)ldsdst, 16, 0, 0);
}

// ---------------- conversions ----------------

// x -> A2 = [x_hi | x_lo] row-major [M][2048] (error-compensated split)
__global__ void split_x_kernel(const float* __restrict__ x, ushort* __restrict__ x2) {
  size_t i = ((size_t)blockIdx.x * blockDim.x + threadIdx.x) * 4;
  if (i >= NELEM) return;
  float4 v = *(const float4*)(x + i);
  float vv[4] = {v.x, v.y, v.z, v.w};
  ushort h[4], l[4];
#pragma unroll
  for (int j = 0; j < 4; ++j) {
    h[j] = f2bf(vv[j]);
    l[j] = f2bf(vv[j] - bf2f(h[j]));
  }
  size_t m = i >> 10, d = i & 1023;
  *(ushort4*)(x2 + m * 2048 + d) = make_ushort4(h[0], h[1], h[2], h[3]);
  *(ushort4*)(x2 + m * 2048 + 1024 + d) = make_ushort4(l[0], l[1], l[2], l[3]);
}

// W [Kd][Nd] f32 -> Th[n*sh+k] bf16 hi; if LO also Tl[n*sl+k] = lo, Th2[n*sl+k] = hi.
template <int LO>
__global__ void transpose_convert(const float* __restrict__ W, ushort* __restrict__ Th, int sh,
                                  ushort* __restrict__ Tl, ushort* __restrict__ Th2, int sl,
                                  int Kd, int Nd) {
  __shared__ float tile[64][65];  // +1 pad: conflict-free column reads
  const int k0 = blockIdx.x * 64, n0 = blockIdx.y * 64;
  const int tx = threadIdx.x & 63, ty = threadIdx.x >> 6;  // 64 x 4
#pragma unroll
  for (int i = 0; i < 16; ++i)
    tile[ty * 16 + i][tx] = W[(size_t)(k0 + ty * 16 + i) * Nd + n0 + tx];
  __syncthreads();
#pragma unroll
  for (int i = 0; i < 16; ++i) {
    const int nn = ty * 16 + i;
    float v = tile[tx][nn];
    ushort h = f2bf(v);
    Th[(size_t)(n0 + nn) * sh + k0 + tx] = h;
    if (LO) {
      size_t o = (size_t)(n0 + nn) * sl + k0 + tx;
      Tl[o] = f2bf(v - bf2f(h));
      Th2[o] = h;
    }
  }
}

// ---------------- 256x256 8-phase bf16 MFMA GEMM (m201-style port) ----------------
// A [M][lda] bf16; Bw [N][K] bf16 (pre-transposed weights, stride K).
// 8 waves (2m x 4n), wave tile 128x64. K-tile = 64 (BK); 2 K-tiles per iteration,
// 8 phases/iter, one 16KB part staged per phase, vmcnt(6) at phases 4/8 only.
// LDS: 2 buffers x (A 256x64 + B 256x64) = 128 KB. XOR-swizzle: granule^=(row&7).
// C plane stacking: col>>10 selects fp32 plane in C (or C4 for plane 4).
template <int BETA, int FINAL>
__global__ __launch_bounds__(512, 2) void gemm256(
    const ushort* __restrict__ A, int lda, const ushort* __restrict__ Bw,
    float* __restrict__ C, float* __restrict__ C4,
    const float* __restrict__ xres, const float* __restrict__ bias,
    int M, int N, int K) {
  __shared__ __align__(16) char ldsc[2 * 65536];
  const int nTm = M >> 8;
  const int tm = blockIdx.x % nTm, tn = blockIdx.x / nTm;
  const int t = threadIdx.x, lane = t & 63, wid = t >> 6;
  const int wm = wid >> 2, wn = wid & 3;
  const int NT = K >> 6, NIT = K >> 7;

  f32x4 acc[8][4];
#pragma unroll
  for (int i = 0; i < 8; ++i)
#pragma unroll
    for (int j = 0; j < 4; ++j) acc[i][j] = (f32x4){0.f, 0.f, 0.f, 0.f};

  // ---- staging (pre-swizzled global source, linear LDS dest; T21-correct) ----
  const int gl8 = ((lane & 7) ^ (lane >> 3)) * 8;  // logical granule fetched by lane
  const ushort* srcA = A + (size_t)(tm * 256 + (t >> 3)) * lda + gl8;
  const ushort* srcB =
      Bw + (size_t)(tn * 256 + (wid >> 2) * 64 + (wid & 3) * 8 + (lane >> 3)) * K + gl8;
  char* dstA = ldsc + (size_t)t * 16;  // + buf + rb*128
  char* dstB = ldsc + 32768 + ((wid >> 2) * 64 + (wid & 3) * 8) * 128 + lane * 16;

  // A part: rows {rb..rb+63} U {128+rb..}, B part: 32-row groups at `off` parity
  auto SA = [&](int tile, int rb) {
    if (tile < NT) {
      char* d = dstA + (tile & 1) * 65536 + rb * 128;
      const ushort* s = srcA + (size_t)rb * lda + tile * 64;
      gload16(s, d);
      gload16(s + (size_t)128 * lda, d + 16384);
    }
  };
  auto SB = [&](int tile, int off) {
    if (tile < NT) {
      char* d = dstB + (tile & 1) * 65536 + off * 128;
      const ushort* s = srcB + (size_t)off * K + tile * 64;
      gload16(s, d);
      gload16(s + (size_t)128 * K, d + 16384);
    }
  };

  // ---- fragment reads (swizzled granule: phys = logical ^ (row&7)) ----
  const int lane15 = lane & 15;
  const int swz0 = ((lane >> 4) ^ (lane & 7)) << 4;
  const int swz1 = swz0 ^ 64;
  const char* aB = ldsc + (wm * 128 + lane15) * 128;
  const char* bB = ldsc + 32768 + (wn * 64 + lane15) * 128;

  s16x8 af[4][2], b0[2][2], b1[2][2];
  auto RA = [&](int buf, int h) {
#pragma unroll
    for (int f = 0; f < 4; ++f) {
      af[f][0] = *(const s16x8*)(aB + buf + (h * 64 + f * 16) * 128 + swz0);
      af[f][1] = *(const s16x8*)(aB + buf + (h * 64 + f * 16) * 128 + swz1);
    }
  };
  auto RB0 = [&](int buf, int ch) {
#pragma unroll
    for (int c = 0; c < 2; ++c) {
      b0[c][0] = *(const s16x8*)(bB + buf + (ch * 32 + c * 16) * 128 + swz0);
      b0[c][1] = *(const s16x8*)(bB + buf + (ch * 32 + c * 16) * 128 + swz1);
    }
  };
  auto RB1 = [&](int buf, int ch) {
#pragma unroll
    for (int c = 0; c < 2; ++c) {
      b1[c][0] = *(const s16x8*)(bB + buf + (ch * 32 + c * 16) * 128 + swz0);
      b1[c][1] = *(const s16x8*)(bB + buf + (ch * 32 + c * 16) * 128 + swz1);
    }
  };
  auto MM0 = [&](int h, int ch) {  // MFMA quadrant with b0
#pragma unroll
    for (int f = 0; f < 4; ++f)
#pragma unroll
      for (int c = 0; c < 2; ++c)
#pragma unroll
        for (int ks = 0; ks < 2; ++ks)
          acc[h * 4 + f][ch * 2 + c] = __builtin_amdgcn_mfma_f32_16x16x32_bf16(
              af[f][ks], b0[c][ks], acc[h * 4 + f][ch * 2 + c], 0, 0, 0);
  };
  auto MM1 = [&](int h, int ch) {  // MFMA quadrant with b1
#pragma unroll
    for (int f = 0; f < 4; ++f)
#pragma unroll
      for (int c = 0; c < 2; ++c)
#pragma unroll
        for (int ks = 0; ks < 2; ++ks)
          acc[h * 4 + f][ch * 2 + c] = __builtin_amdgcn_mfma_f32_16x16x32_bf16(
              af[f][ks], b1[c][ks], acc[h * 4 + f][ch * 2 + c], 0, 0, 0);
  };

#define BAR_IN()                                         \
  __builtin_amdgcn_s_barrier();                          \
  asm volatile("s_waitcnt lgkmcnt(0)" ::: "memory");     \
  __builtin_amdgcn_sched_barrier(0);                     \
  __builtin_amdgcn_s_setprio(1)
#define BAR_OUT()                                        \
  __builtin_amdgcn_s_setprio(0);                         \
  __builtin_amdgcn_s_barrier();                          \
  __builtin_amdgcn_sched_barrier(0)
#define LGKM8() asm volatile("s_waitcnt lgkmcnt(8)" ::: "memory")

  // prologue: T0 all 4 parts, T1 parts 0-2 (issue order matters for vmcnt)
  SA(0, 0); SB(0, 32); SA(0, 64); SB(0, 0); SA(1, 0); SB(1, 32); SA(1, 64);
  asm volatile("s_waitcnt vmcnt(6)" ::: "memory");  // T0 fully landed
  __builtin_amdgcn_sched_barrier(0);
  __builtin_amdgcn_s_barrier();
  __builtin_amdgcn_sched_barrier(0);

#pragma unroll 1
  for (int it = 0; it < NIT; ++it) {
    const int t1 = 2 * it + 1, t2 = 2 * it + 2, t3 = 2 * it + 3;
    const bool last = (it == NIT - 1);
    // phase 1: q0 of tile 2it (buf 0): rows 0-63 x cols 0-31
    RA(0, 0); RB0(0, 0); SB(t1, 0);
    LGKM8();
    BAR_IN(); MM0(0, 0); BAR_OUT();
    // phase 2: q1: rows 0-63 x cols 32-63 (A regs reused)
    RB1(0, 1); SA(t2, 0);
    BAR_IN(); MM1(0, 1); BAR_OUT();
    // phase 3: q2: rows 64-127 x cols 0-31 (B0 regs reused)
    RA(0, 1); SB(t2, 32);
    BAR_IN(); MM0(1, 0); BAR_OUT();
    // phase 4: q3: rows 64-127 x cols 32-63 (no reads)
    SA(t2, 64);
    BAR_IN(); MM1(1, 1);
    __builtin_amdgcn_s_setprio(0);
    if (last) { asm volatile("s_waitcnt vmcnt(0)" ::: "memory"); }
    else      { asm volatile("s_waitcnt vmcnt(6)" ::: "memory"); }
    __builtin_amdgcn_sched_barrier(0);
    __builtin_amdgcn_s_barrier();
    __builtin_amdgcn_sched_barrier(0);
    // phase 5: q0 of tile 2it+1 (buf 1)
    RA(65536, 0); RB0(65536, 0); SB(t2, 0);
    LGKM8();
    BAR_IN(); MM0(0, 0); BAR_OUT();
    // phase 6
    RB1(65536, 1); SA(t3, 0);
    BAR_IN(); MM1(0, 1); BAR_OUT();
    // phase 7
    RA(65536, 1); SB(t3, 32);
    BAR_IN(); MM0(1, 0); BAR_OUT();
    // phase 8
    SA(t3, 64);
    BAR_IN(); MM1(1, 1);
    __builtin_amdgcn_s_setprio(0);
    if (last) { asm volatile("s_waitcnt vmcnt(0)" ::: "memory"); }
    else      { asm volatile("s_waitcnt vmcnt(6)" ::: "memory"); }
    __builtin_amdgcn_sched_barrier(0);
    __builtin_amdgcn_s_barrier();
    __builtin_amdgcn_sched_barrier(0);
  }
#undef BAR_IN
#undef BAR_OUT
#undef LGKM8

  // epilogue. C/D layout: col=lane&15, row=(lane>>4)*4+reg  [m89-verified]
#pragma unroll
  for (int i = 0; i < 8; ++i) {
    const int row0 = tm * 256 + wm * 128 + i * 16 + ((lane >> 4) << 2);
#pragma unroll
    for (int jj = 0; jj < 4; ++jj) {
      const int col = tn * 256 + wn * 64 + jj * 16 + (lane & 15);
      const int pl = col >> 10;
      float* base = (FINAL || pl < 4) ? (C + (size_t)pl * (size_t)M * 1024) : C4;
#pragma unroll
      for (int r = 0; r < 4; ++r) {
        const size_t idx = (size_t)(row0 + r) * 1024 + (col & 1023);
        float v = acc[i][jj][r];
        if (BETA) v += base[idx];
        if (FINAL) v += xres[idx] + bias[col];
        base[idx] = v;
      }
    }
  }
}

// ---------------- fused elementwise / scan passes ----------------

// P1: omega_lin -> gated_omega (in place), mag_lin -> magnitude (in place)
__global__ void prep_kernel(float* __restrict__ omega_go, const float* __restrict__ gate_lin,
                            float* __restrict__ mag_io,
                            const float* __restrict__ b_om, const float* __restrict__ b_gate,
                            const float* __restrict__ b_mag, const float* __restrict__ isc) {
  size_t i = (size_t)blockIdx.x * blockDim.x + threadIdx.x;
  if (i >= NELEM) return;
  int d = (int)(i & (D_ - 1));
  float om = omega_go[i] + b_om[d];
  float g = 1.f / (1.f + __expf(-(gate_lin[i] + b_gate[d])));
  float mg = 5.f / (1.f + __expf(-(mag_io[i] + b_mag[d])));
  omega_go[i] = g * (om * fabsf(isc[d]));
  mag_io[i] = mg;
}

// P2: per-(b,chunk,d) sums of gated_omega and magnitude
__global__ void chunk_sum_kernel(const float* __restrict__ go, const float* __restrict__ mg,
                                 float* __restrict__ gsum, float* __restrict__ msum) {
  int tid = blockIdx.x * blockDim.x + threadIdx.x;
  if (tid >= B_ * CCH * D_) return;
  int d = tid & (D_ - 1), c = (tid >> 10) & (CCH - 1), b = tid >> 16;
  size_t base = ((size_t)(b * S_) + c * LCH) * D_ + d;
  float sg = 0.f, sm = 0.f;
  for (int s = 0; s < LCH; ++s) {
    sg += go[base + (size_t)s * D_];
    sm += mg[base + (size_t)s * D_];
  }
  gsum[tid] = sg;
  msum[tid] = sm;
}

// P3/P5: in-place exclusive scan of chunk totals along c, per (b,d) chain
__global__ void scan_offsets_kernel(float* __restrict__ s1, float* __restrict__ s2) {
  int tid = blockIdx.x * blockDim.x + threadIdx.x;
  if (tid >= B_ * D_) return;
  int d = tid & (D_ - 1), b = tid >> 10;
  float a1 = 0.f, a2 = 0.f;
  for (int c = 0; c < CCH; ++c) {
    size_t idx = ((size_t)(b * CCH) + c) * D_ + d;
    float v1 = s1[idx], v2 = s2[idx];
    s1[idx] = a1;
    s2[idx] = a2;
    a1 += v1;
    a2 += v2;
  }
}

// P4: chunked scan -> phi (over go), mag cumsum (over mag), local memory-term
// cumsums (over gate/phi0 bufs), ctx parts 0,1; emits tr/ti chunk totals.
__global__ void phase_scan_kernel(const float* __restrict__ x,
                                  float* __restrict__ goPhi, float* __restrict__ magC,
                                  float* __restrict__ trC, float* __restrict__ tiC,
                                  const float* __restrict__ goff, const float* __restrict__ moff,
                                  float* __restrict__ trsum, float* __restrict__ tisum,
                                  const float* __restrict__ b_phi, ushort* __restrict__ ctx) {
  int tid = blockIdx.x * blockDim.x + threadIdx.x;
  if (tid >= B_ * CCH * D_) return;
  int d = tid & (D_ - 1), c = (tid >> 10) & (CCH - 1), b = tid >> 16;
  size_t base = ((size_t)(b * S_) + c * LCH) * D_ + d;
  float phi_run = goff[tid], mag_run = moff[tid];
  float tr = 0.f, ti = 0.f;
  const float bp = b_phi[d];
  size_t crow = ((size_t)(b * S_ + c * LCH)) * 4096 + d;
  for (int s = 0; s < LCH; ++s) {
    size_t i = base + (size_t)s * D_;
    phi_run += goPhi[i];
    float phi = tiC[i] + bp + phi_run;  // tiC holds phi0_lin before overwrite
    float sp, cp;
    __sincosf(phi, &sp, &cp);
    float m = magC[i];
    mag_run += m;
    float xv = x[i];
    float wr = m * xv;
    tr += wr * cp;
    ti += wr * sp;
    goPhi[i] = phi;
    magC[i] = mag_run;
    trC[i] = tr;
    tiC[i] = ti;
    ctx[crow] = f2bf(xv * cp);
    ctx[crow + 1024] = f2bf(xv * sp);
    crow += 4096;
  }
  trsum[tid] = tr;
  tisum[tid] = ti;
}

// P6: memory normalization + complex retrieval -> ctx parts 2,3
__global__ void retrieve_kernel(const float* __restrict__ phi, const float* __restrict__ magC,
                                const float* __restrict__ trC, const float* __restrict__ tiC,
                                const float* __restrict__ qlin,
                                const float* __restrict__ troff, const float* __restrict__ tioff,
                                const float* __restrict__ b_q, ushort* __restrict__ ctx) {
  size_t i = (size_t)blockIdx.x * blockDim.x + threadIdx.x;
  if (i >= NELEM) return;
  int d = (int)(i & (D_ - 1));
  int m_ = (int)(i >> 10);
  int srow = m_ & (S_ - 1), b = m_ >> 11;
  int c = srow >> 5;  // /LCH
  int cs = ((b * CCH) + c) * D_ + d;
  float rs = rsqrtf(magC[i] + 1e-8f);
  float mr = (troff[cs] + trC[i]) * rs;
  float mi = (tioff[cs] + tiC[i]) * rs;
  float phq = phi[i] + qlin[i] + b_q[d];
  float sq, cq;
  __sincosf(phq, &sq, &cq);
  size_t crow = (size_t)m_ * 4096 + d;
  ctx[crow + 2048] = f2bf(mr * cq + mi * sq);
  ctx[crow + 3072] = f2bf(mi * cq - mr * sq);
}

// ---------------- launcher ----------------
extern "C" void kernel_launch(void* const* d_in, const int* in_sizes, int n_in,
                              void* d_out, int out_size, void* d_ws, size_t ws_size,
                              hipStream_t stream) {
  const float* x      = (const float*)d_in[0];
  const float* W_om   = (const float*)d_in[1];
  const float* b_om   = (const float*)d_in[2];
  const float* W_mag  = (const float*)d_in[3];
  const float* b_mag  = (const float*)d_in[4];
  const float* W_phi  = (const float*)d_in[5];
  const float* b_phi  = (const float*)d_in[6];
  const float* W_gate = (const float*)d_in[7];
  const float* b_gate = (const float*)d_in[8];
  const float* W_q    = (const float*)d_in[9];
  const float* b_q    = (const float*)d_in[10];
  const float* isc    = (const float*)d_in[11];
  const float* W_out  = (const float*)d_in[12];
  const float* b_out  = (const float*)d_in[13];
  float* out = (float*)d_out;

  // ---- ws layout, 213,909,504 bytes total ----
  const size_t WS_NEEDED = 213909504ull;
  if (ws_size < WS_NEEDED) {
    hipMemsetAsync(d_out, 0, (size_t)out_size * sizeof(float), stream);
    return;
  }
  char* w = (char*)d_ws;
  float* planes    = (float*)w;                       // 4 x NELEM fp32
  float* omega_buf = planes;                          // omega_lin -> gated_omega -> phi
  float* gate_buf  = planes + NELEM;                  // gate_lin  -> trcum (local)
  float* mag_buf   = planes + 2 * NELEM;              // mag_lin -> magnitude -> mag cumsum
  float* phi0_buf  = planes + 3 * NELEM;              // phi0_lin -> ticum (local)
  float* q_buf     = out;                             // q_lin (d_out as scratch)
  char* ctxb = w + 4 * NELEM * 4;
  ushort* ctx   = (ushort*)ctxb;                      // [8192][4096] bf16
  ushort* x2    = (ushort*)ctxb;                      // [8192][2048] = [hi|lo]
  ushort* WT    = (ushort*)(ctxb + 33554432);         // hi: om|gate|mag|phi0|q, [n][1024]
  ushort* Wcomp = (ushort*)(ctxb + 44040192);         // [2048 n][2048 k] = [W_lo | W_hi]
  ushort* WoutT = (ushort*)(w + 201326592);           // [1024][4096]
  float* gsum  = (float*)(w + 209715200);
  float* msum  = (float*)(w + 210763776);
  float* trsum = (float*)(w + 211812352);
  float* tisum = (float*)(w + 212860928);

  const size_t DD = (size_t)D_ * D_;

  // conversions
  split_x_kernel<<<(int)(NELEM / 1024), 256, 0, stream>>>(x, x2);
  dim3 tg(16, 16);
  transpose_convert<1><<<tg, 256, 0, stream>>>(W_om,   WT + 0 * DD, 1024,
                                               Wcomp, Wcomp + 1024, 2048, D_, D_);
  transpose_convert<1><<<tg, 256, 0, stream>>>(W_gate, WT + 1 * DD, 1024,
                                               Wcomp + 1024 * 2048, Wcomp + 1024 * 2048 + 1024,
                                               2048, D_, D_);
  transpose_convert<0><<<tg, 256, 0, stream>>>(W_mag,  WT + 2 * DD, 1024, nullptr, nullptr, 0, D_, D_);
  transpose_convert<0><<<tg, 256, 0, stream>>>(W_phi,  WT + 3 * DD, 1024, nullptr, nullptr, 0, D_, D_);
  transpose_convert<0><<<tg, 256, 0, stream>>>(W_q,    WT + 4 * DD, 1024, nullptr, nullptr, 0, D_, D_);
  transpose_convert<0><<<dim3(64, 16), 256, 0, stream>>>(W_out, WoutT, 4096, nullptr, nullptr, 0,
                                                         4 * D_, D_);

  // GEMM1: 5 projections (hi*hi), q plane -> d_out scratch. N=5120, K=1024.
  gemm256<0, 0><<<32 * 20, 512, 0, stream>>>(x2, 2048, WT, planes, q_buf, nullptr, nullptr,
                                             MROWS, 5 * D_, D_);
  // compensation: omega/gate += x_hi@W_lo + x_lo@W_hi. N=2048, K=2048.
  gemm256<1, 0><<<32 * 8, 512, 0, stream>>>(x2, 2048, Wcomp, planes, nullptr, nullptr, nullptr,
                                            MROWS, 2 * D_, 2 * D_);

  // scans + fused elementwise
  prep_kernel<<<(int)((NELEM + 255) / 256), 256, 0, stream>>>(omega_buf, gate_buf, mag_buf,
                                                              b_om, b_gate, b_mag, isc);
  chunk_sum_kernel<<<(B_ * CCH * D_ + 255) / 256, 256, 0, stream>>>(omega_buf, mag_buf, gsum, msum);
  scan_offsets_kernel<<<(B_ * D_ + 255) / 256, 256, 0, stream>>>(gsum, msum);
  phase_scan_kernel<<<(B_ * CCH * D_ + 255) / 256, 256, 0, stream>>>(
      x, omega_buf, mag_buf, gate_buf, phi0_buf, gsum, msum, trsum, tisum, b_phi, ctx);
  scan_offsets_kernel<<<(B_ * D_ + 255) / 256, 256, 0, stream>>>(trsum, tisum);
  retrieve_kernel<<<(int)((NELEM + 255) / 256), 256, 0, stream>>>(
      omega_buf, mag_buf, gate_buf, phi0_buf, q_buf, trsum, tisum, b_q, ctx);

  // final: out = x + ctx @ W_out + b_out  (overwrites q_lin scratch). K=4096.
  gemm256<0, 1><<<32 * 4, 512, 0, stream>>>(ctx, 4096, WoutT, out, nullptr, x, b_out,
                                            MROWS, D_, 4 * D_);
}

// Round 5
// 474.050 us; speedup vs baseline: 1.1138x; 1.0021x over previous
//
#include <hip/hip_runtime.h>
#include <hip/hip_bf16.h>

// Problem constants (B,S,D fixed by the reference)
#define B_ 4
#define S_ 2048
#define D_ 1024
#define CCH 64                    // chunks along S
#define LCH 32                    // chunk length; CCH*LCH == S_
#define NELEM ((size_t)B_*S_*D_)  // 8388608
#define MROWS (B_*S_)             // 8192

typedef __attribute__((ext_vector_type(4))) float f32x4;
typedef __attribute__((ext_vector_type(8))) short s16x8;  // 8 x bf16 fragment

__device__ __forceinline__ ushort f2bf(float v) {
  __hip_bfloat16 h = __float2bfloat16(v);
  return __builtin_bit_cast(ushort, h);
}
__device__ __forceinline__ float bf2f(ushort u) {
  return __bfloat162float(__builtin_bit_cast(__hip_bfloat16, u));
}

__device__ __forceinline__ void gload16(const ushort* src, char* ldsdst) {
  __builtin_amdgcn_global_load_lds(
      (const __attribute__((address_space(1))) void*)src,
      (__attribute__((address_space(3))) void*)ldsdst, 16, 0, 0);
}

// ---------------- conversions ----------------

// x -> A2 = [x_hi | x_lo] row-major [M][2048] (error-compensated split)
__global__ void split_x_kernel(const float* __restrict__ x, ushort* __restrict__ x2) {
  size_t i = ((size_t)blockIdx.x * blockDim.x + threadIdx.x) * 4;
  if (i >= NELEM) return;
  float4 v = *(const float4*)(x + i);
  float vv[4] = {v.x, v.y, v.z, v.w};
  ushort h[4], l[4];
#pragma unroll
  for (int j = 0; j < 4; ++j) {
    h[j] = f2bf(vv[j]);
    l[j] = f2bf(vv[j] - bf2f(h[j]));
  }
  size_t m = i >> 10, d = i & 1023;
  *(ushort4*)(x2 + m * 2048 + d) = make_ushort4(h[0], h[1], h[2], h[3]);
  *(ushort4*)(x2 + m * 2048 + 1024 + d) = make_ushort4(l[0], l[1], l[2], l[3]);
}

// W [Kd][Nd] f32 -> Th[n*sh+k] bf16 hi; if LO also Tl[n*sl+k] = lo, Th2[n*sl+k] = hi.
template <int LO>
__global__ void transpose_convert(const float* __restrict__ W, ushort* __restrict__ Th, int sh,
                                  ushort* __restrict__ Tl, ushort* __restrict__ Th2, int sl,
                                  int Kd, int Nd) {
  __shared__ float tile[64][65];  // +1 pad: conflict-free column reads
  const int k0 = blockIdx.x * 64, n0 = blockIdx.y * 64;
  const int tx = threadIdx.x & 63, ty = threadIdx.x >> 6;  // 64 x 4
#pragma unroll
  for (int i = 0; i < 16; ++i)
    tile[ty * 16 + i][tx] = W[(size_t)(k0 + ty * 16 + i) * Nd + n0 + tx];
  __syncthreads();
#pragma unroll
  for (int i = 0; i < 16; ++i) {
    const int nn = ty * 16 + i;
    float v = tile[tx][nn];
    ushort h = f2bf(v);
    Th[(size_t)(n0 + nn) * sh + k0 + tx] = h;
    if (LO) {
      size_t o = (size_t)(n0 + nn) * sl + k0 + tx;
      Tl[o] = f2bf(v - bf2f(h));
      Th2[o] = h;
    }
  }
}

// ---------------- 256x256 8-phase bf16 MFMA GEMM ----------------
// A [M][lda] bf16; Bw [N][K] bf16 (pre-transposed weights, row stride K).
// 8 waves (2m x 4n), wave tile 128x64. K-tile=64; 2 K-tiles/iter, 8 phases/iter,
// one 16KB part staged per phase, vmcnt(6) at phases 4/8 only.
// LDS: 2 buffers x (A 256x64 + B 256x64) = 128 KB. XOR-swizzle: granule^=(row&7).
// SPLITK: grid doubles; ks=1 blocks compute k in [K/2,K) and write plain to C4.
// C plane stacking: col>>10 selects fp32 plane in C (or C4 for plane 4).
template <int BETA, int FINAL, int SPLITK>
__global__ __launch_bounds__(512, 2) void gemm256(
    const ushort* __restrict__ A, int lda, const ushort* __restrict__ Bw,
    float* __restrict__ C, float* __restrict__ C4,
    const float* __restrict__ xres, const float* __restrict__ bias,
    int M, int N, int K) {
  __shared__ __align__(16) char ldsc[2 * 65536];
  const int nTm = M >> 8;
  int bid = blockIdx.x, ks = 0;
  if (SPLITK) {
    const int tilesPerK = nTm * (N >> 8);
    if (bid >= tilesPerK) { ks = 1; bid -= tilesPerK; }
  }
  const int tm = bid % nTm, tn = bid / nTm;
  const int Kk = SPLITK ? (K >> 1) : K;
  A += (size_t)ks * Kk;
  Bw += (size_t)ks * Kk;
  const int t = threadIdx.x, lane = t & 63, wid = t >> 6;
  const int wm = wid >> 2, wn = wid & 3;
  const int NT = Kk >> 6, NIT = Kk >> 7;

  f32x4 acc[8][4];
#pragma unroll
  for (int i = 0; i < 8; ++i)
#pragma unroll
    for (int j = 0; j < 4; ++j) acc[i][j] = (f32x4){0.f, 0.f, 0.f, 0.f};

  // ---- staging (pre-swizzled global source, linear LDS dest; T21-correct) ----
  const int gl8 = ((lane & 7) ^ (lane >> 3)) * 8;  // logical granule fetched by lane
  const ushort* srcA = A + (size_t)(tm * 256 + (t >> 3)) * lda + gl8;
  const ushort* srcB =
      Bw + (size_t)(tn * 256 + (wid >> 2) * 64 + (wid & 3) * 8 + (lane >> 3)) * K + gl8;
  char* dstA = ldsc + (size_t)t * 16;  // + buf + rb*128
  char* dstB = ldsc + 32768 + ((wid >> 2) * 64 + (wid & 3) * 8) * 128 + lane * 16;

  // A part: rows {rb..rb+63} U {128+rb..}, B part: 32-row groups at `off` parity
  auto SA = [&](int tile, int rb) {
    if (tile < NT) {
      char* d = dstA + (tile & 1) * 65536 + rb * 128;
      const ushort* s = srcA + (size_t)rb * lda + tile * 64;
      gload16(s, d);
      gload16(s + (size_t)128 * lda, d + 16384);
    }
  };
  auto SB = [&](int tile, int off) {
    if (tile < NT) {
      char* d = dstB + (tile & 1) * 65536 + off * 128;
      const ushort* s = srcB + (size_t)off * K + tile * 64;
      gload16(s, d);
      gload16(s + (size_t)128 * K, d + 16384);
    }
  };

  // ---- fragment reads (swizzled granule: phys = logical ^ (row&7)) ----
  const int lane15 = lane & 15;
  const int swz0 = ((lane >> 4) ^ (lane & 7)) << 4;
  const int swz1 = swz0 ^ 64;
  const char* aB = ldsc + (wm * 128 + lane15) * 128;
  const char* bB = ldsc + 32768 + (wn * 64 + lane15) * 128;

  s16x8 af[4][2], b0[2][2], b1[2][2];
  auto RA = [&](int buf, int h) {
#pragma unroll
    for (int f = 0; f < 4; ++f) {
      af[f][0] = *(const s16x8*)(aB + buf + (h * 64 + f * 16) * 128 + swz0);
      af[f][1] = *(const s16x8*)(aB + buf + (h * 64 + f * 16) * 128 + swz1);
    }
  };
  auto RB0 = [&](int buf, int ch) {
#pragma unroll
    for (int c = 0; c < 2; ++c) {
      b0[c][0] = *(const s16x8*)(bB + buf + (ch * 32 + c * 16) * 128 + swz0);
      b0[c][1] = *(const s16x8*)(bB + buf + (ch * 32 + c * 16) * 128 + swz1);
    }
  };
  auto RB1 = [&](int buf, int ch) {
#pragma unroll
    for (int c = 0; c < 2; ++c) {
      b1[c][0] = *(const s16x8*)(bB + buf + (ch * 32 + c * 16) * 128 + swz0);
      b1[c][1] = *(const s16x8*)(bB + buf + (ch * 32 + c * 16) * 128 + swz1);
    }
  };
  auto MM0 = [&](int h, int ch) {  // MFMA quadrant with b0
#pragma unroll
    for (int f = 0; f < 4; ++f)
#pragma unroll
      for (int c = 0; c < 2; ++c)
#pragma unroll
        for (int ks_ = 0; ks_ < 2; ++ks_)
          acc[h * 4 + f][ch * 2 + c] = __builtin_amdgcn_mfma_f32_16x16x32_bf16(
              af[f][ks_], b0[c][ks_], acc[h * 4 + f][ch * 2 + c], 0, 0, 0);
  };
  auto MM1 = [&](int h, int ch) {  // MFMA quadrant with b1
#pragma unroll
    for (int f = 0; f < 4; ++f)
#pragma unroll
      for (int c = 0; c < 2; ++c)
#pragma unroll
        for (int ks_ = 0; ks_ < 2; ++ks_)
          acc[h * 4 + f][ch * 2 + c] = __builtin_amdgcn_mfma_f32_16x16x32_bf16(
              af[f][ks_], b1[c][ks_], acc[h * 4 + f][ch * 2 + c], 0, 0, 0);
  };

#define BAR_IN()                                         \
  __builtin_amdgcn_s_barrier();                          \
  asm volatile("s_waitcnt lgkmcnt(0)" ::: "memory");     \
  __builtin_amdgcn_sched_barrier(0);                     \
  __builtin_amdgcn_s_setprio(1)
#define BAR_OUT()                                        \
  __builtin_amdgcn_s_setprio(0);                         \
  __builtin_amdgcn_s_barrier();                          \
  __builtin_amdgcn_sched_barrier(0)
#define LGKM8() asm volatile("s_waitcnt lgkmcnt(8)" ::: "memory")

  // prologue: T0 all 4 parts, T1 parts 0-2 (issue order matters for vmcnt)
  SA(0, 0); SB(0, 32); SA(0, 64); SB(0, 0); SA(1, 0); SB(1, 32); SA(1, 64);
  asm volatile("s_waitcnt vmcnt(6)" ::: "memory");  // T0 fully landed
  __builtin_amdgcn_sched_barrier(0);
  __builtin_amdgcn_s_barrier();
  __builtin_amdgcn_sched_barrier(0);

#pragma unroll 1
  for (int it = 0; it < NIT; ++it) {
    const int t1 = 2 * it + 1, t2 = 2 * it + 2, t3 = 2 * it + 3;
    const bool last = (it == NIT - 1);
    // phase 1: q0 of tile 2it (buf 0): rows 0-63 x cols 0-31
    RA(0, 0); RB0(0, 0); SB(t1, 0);
    LGKM8();
    BAR_IN(); MM0(0, 0); BAR_OUT();
    // phase 2: q1: rows 0-63 x cols 32-63 (A regs reused)
    RB1(0, 1); SA(t2, 0);
    BAR_IN(); MM1(0, 1); BAR_OUT();
    // phase 3: q2: rows 64-127 x cols 0-31 (B0 regs reused)
    RA(0, 1); SB(t2, 32);
    BAR_IN(); MM0(1, 0); BAR_OUT();
    // phase 4: q3: rows 64-127 x cols 32-63 (no reads)
    SA(t2, 64);
    BAR_IN(); MM1(1, 1);
    __builtin_amdgcn_s_setprio(0);
    if (last) { asm volatile("s_waitcnt vmcnt(0)" ::: "memory"); }
    else      { asm volatile("s_waitcnt vmcnt(6)" ::: "memory"); }
    __builtin_amdgcn_sched_barrier(0);
    __builtin_amdgcn_s_barrier();
    __builtin_amdgcn_sched_barrier(0);
    // phase 5: q0 of tile 2it+1 (buf 1)
    RA(65536, 0); RB0(65536, 0); SB(t2, 0);
    LGKM8();
    BAR_IN(); MM0(0, 0); BAR_OUT();
    // phase 6
    RB1(65536, 1); SA(t3, 0);
    BAR_IN(); MM1(0, 1); BAR_OUT();
    // phase 7
    RA(65536, 1); SB(t3, 32);
    BAR_IN(); MM0(1, 0); BAR_OUT();
    // phase 8
    SA(t3, 64);
    BAR_IN(); MM1(1, 1);
    __builtin_amdgcn_s_setprio(0);
    if (last) { asm volatile("s_waitcnt vmcnt(0)" ::: "memory"); }
    else      { asm volatile("s_waitcnt vmcnt(6)" ::: "memory"); }
    __builtin_amdgcn_sched_barrier(0);
    __builtin_amdgcn_s_barrier();
    __builtin_amdgcn_sched_barrier(0);
  }
#undef BAR_IN
#undef BAR_OUT
#undef LGKM8

  // epilogue. C/D layout: col=lane&15, row=(lane>>4)*4+reg  [m89-verified]
#pragma unroll
  for (int i = 0; i < 8; ++i) {
    const int row0 = tm * 256 + wm * 128 + i * 16 + ((lane >> 4) << 2);
#pragma unroll
    for (int jj = 0; jj < 4; ++jj) {
      const int col = tn * 256 + wn * 64 + jj * 16 + (lane & 15);
      if (SPLITK && ks) {  // partial: plain store to C4 plane
#pragma unroll
        for (int r = 0; r < 4; ++r)
          C4[(size_t)(row0 + r) * 1024 + (col & 1023)] = acc[i][jj][r];
      } else {
        const int pl = col >> 10;
        float* base = (FINAL || pl < 4) ? (C + (size_t)pl * (size_t)M * 1024) : C4;
#pragma unroll
        for (int r = 0; r < 4; ++r) {
          const size_t idx = (size_t)(row0 + r) * 1024 + (col & 1023);
          float v = acc[i][jj][r];
          if (BETA) v += base[idx];
          if (FINAL) v += xres[idx] + bias[col];
          base[idx] = v;
        }
      }
    }
  }
}

// split-K merge: out += partial
__global__ void add_kernel(float* __restrict__ out, const float* __restrict__ p) {
  size_t i = ((size_t)blockIdx.x * blockDim.x + threadIdx.x) * 4;
  if (i >= NELEM) return;
  float4 a = *(const float4*)(out + i);
  float4 b = *(const float4*)(p + i);
  a.x += b.x; a.y += b.y; a.z += b.z; a.w += b.w;
  *(float4*)(out + i) = a;
}

// ---------------- fused elementwise / scan passes (float4) ----------------

// P1+P2 fused: gating/sigmoid transforms in place + per-(b,chunk,d) sums
__global__ void prep_chunk_kernel(float* __restrict__ omega_go, const float* __restrict__ gate_lin,
                                  float* __restrict__ mag_io,
                                  const float* __restrict__ b_om, const float* __restrict__ b_gate,
                                  const float* __restrict__ b_mag, const float* __restrict__ isc,
                                  float* __restrict__ gsum, float* __restrict__ msum) {
  int tid = blockIdx.x * blockDim.x + threadIdx.x;
  if (tid >= B_ * CCH * (D_ / 4)) return;
  int d4 = tid & 255, c = (tid >> 8) & (CCH - 1), b = tid >> 14;
  int d = d4 * 4;
  size_t base = ((size_t)(b * S_) + c * LCH) * D_ + d;
  size_t cs = ((size_t)(b * CCH) + c) * D_ + d;
  float bo[4], bg[4], bm[4], is[4];
  *(float4*)bo = *(const float4*)(b_om + d);
  *(float4*)bg = *(const float4*)(b_gate + d);
  *(float4*)bm = *(const float4*)(b_mag + d);
  *(float4*)is = *(const float4*)(isc + d);
  float sg[4] = {0.f, 0.f, 0.f, 0.f}, sm[4] = {0.f, 0.f, 0.f, 0.f};
  for (int s = 0; s < LCH; ++s) {
    size_t i = base + (size_t)s * D_;
    float om[4], gl[4], mg[4];
    *(float4*)om = *(const float4*)(omega_go + i);
    *(float4*)gl = *(const float4*)(gate_lin + i);
    *(float4*)mg = *(const float4*)(mag_io + i);
#pragma unroll
    for (int j = 0; j < 4; ++j) {
      float g = 1.f / (1.f + __expf(-(gl[j] + bg[j])));
      float m5 = 5.f / (1.f + __expf(-(mg[j] + bm[j])));
      om[j] = g * ((om[j] + bo[j]) * fabsf(is[j]));
      mg[j] = m5;
      sg[j] += om[j];
      sm[j] += m5;
    }
    *(float4*)(omega_go + i) = *(float4*)om;
    *(float4*)(mag_io + i) = *(float4*)mg;
  }
  *(float4*)(gsum + cs) = *(float4*)sg;
  *(float4*)(msum + cs) = *(float4*)sm;
}

// P3/P5: in-place exclusive scan of chunk totals along c, per (b,d) chain
__global__ void scan_offsets_kernel(float* __restrict__ s1, float* __restrict__ s2) {
  int tid = blockIdx.x * blockDim.x + threadIdx.x;
  if (tid >= B_ * (D_ / 4)) return;
  int d = (tid & 255) * 4, b = tid >> 8;
  float a1[4] = {0.f, 0.f, 0.f, 0.f}, a2[4] = {0.f, 0.f, 0.f, 0.f};
  for (int c = 0; c < CCH; ++c) {
    size_t idx = ((size_t)(b * CCH) + c) * D_ + d;
    float v1[4], v2[4];
    *(float4*)v1 = *(const float4*)(s1 + idx);
    *(float4*)v2 = *(const float4*)(s2 + idx);
    *(float4*)(s1 + idx) = *(float4*)a1;
    *(float4*)(s2 + idx) = *(float4*)a2;
#pragma unroll
    for (int j = 0; j < 4; ++j) { a1[j] += v1[j]; a2[j] += v2[j]; }
  }
}

// P4: chunked scan -> phi, mag cumsum, local memory-term cumsums, ctx parts 0,1
__global__ void phase_scan_kernel(const float* __restrict__ x,
                                  float* __restrict__ goPhi, float* __restrict__ magC,
                                  float* __restrict__ trC, float* __restrict__ tiC,
                                  const float* __restrict__ goff, const float* __restrict__ moff,
                                  float* __restrict__ trsum, float* __restrict__ tisum,
                                  const float* __restrict__ b_phi, ushort* __restrict__ ctx) {
  int tid = blockIdx.x * blockDim.x + threadIdx.x;
  if (tid >= B_ * CCH * (D_ / 4)) return;
  int d4 = tid & 255, c = (tid >> 8) & (CCH - 1), b = tid >> 14;
  int d = d4 * 4;
  size_t base = ((size_t)(b * S_) + c * LCH) * D_ + d;
  size_t cs = ((size_t)(b * CCH) + c) * D_ + d;
  float pr[4], mr[4], bp[4];
  *(float4*)pr = *(const float4*)(goff + cs);
  *(float4*)mr = *(const float4*)(moff + cs);
  *(float4*)bp = *(const float4*)(b_phi + d);
  float tr[4] = {0.f, 0.f, 0.f, 0.f}, ti[4] = {0.f, 0.f, 0.f, 0.f};
  size_t crow = ((size_t)(b * S_ + c * LCH)) * 4096 + d;
  for (int s = 0; s < LCH; ++s) {
    size_t i = base + (size_t)s * D_;
    float go[4], p0[4], m[4], xv[4];
    *(float4*)go = *(const float4*)(goPhi + i);
    *(float4*)p0 = *(const float4*)(tiC + i);
    *(float4*)m  = *(const float4*)(magC + i);
    *(float4*)xv = *(const float4*)(x + i);
    ushort c4[4], s4[4];
#pragma unroll
    for (int j = 0; j < 4; ++j) {
      pr[j] += go[j];
      float ph = p0[j] + bp[j] + pr[j];
      float sp, cp;
      __sincosf(ph, &sp, &cp);
      mr[j] += m[j];
      float wr = m[j] * xv[j];
      tr[j] += wr * cp;
      ti[j] += wr * sp;
      go[j] = ph;
      c4[j] = f2bf(xv[j] * cp);
      s4[j] = f2bf(xv[j] * sp);
    }
    *(float4*)(goPhi + i) = *(float4*)go;
    *(float4*)(magC + i) = *(float4*)mr;
    *(float4*)(trC + i) = *(float4*)tr;
    *(float4*)(tiC + i) = *(float4*)ti;
    *(ushort4*)(ctx + crow) = *(ushort4*)c4;
    *(ushort4*)(ctx + crow + 1024) = *(ushort4*)s4;
    crow += 4096;
  }
  *(float4*)(trsum + cs) = *(float4*)tr;
  *(float4*)(tisum + cs) = *(float4*)ti;
}

// P6: memory normalization + complex retrieval -> ctx parts 2,3
__global__ void retrieve_kernel(const float* __restrict__ phi, const float* __restrict__ magC,
                                const float* __restrict__ trC, const float* __restrict__ tiC,
                                const float* __restrict__ qlin,
                                const float* __restrict__ troff, const float* __restrict__ tioff,
                                const float* __restrict__ b_q, ushort* __restrict__ ctx) {
  int tid = blockIdx.x * blockDim.x + threadIdx.x;
  if (tid >= (int)(NELEM / 4)) return;
  int d4 = tid & 255, m_ = tid >> 8;
  int d = d4 * 4;
  int srow = m_ & (S_ - 1), b = m_ >> 11;
  int c = srow >> 5;  // /LCH
  size_t i = (size_t)m_ * 1024 + d;
  size_t cs = ((size_t)(b * CCH) + c) * D_ + d;
  float ph[4], mc[4], trc[4], tic[4], ql[4], to[4], io[4], bq[4];
  *(float4*)ph  = *(const float4*)(phi + i);
  *(float4*)mc  = *(const float4*)(magC + i);
  *(float4*)trc = *(const float4*)(trC + i);
  *(float4*)tic = *(const float4*)(tiC + i);
  *(float4*)ql  = *(const float4*)(qlin + i);
  *(float4*)to  = *(const float4*)(troff + cs);
  *(float4*)io  = *(const float4*)(tioff + cs);
  *(float4*)bq  = *(const float4*)(b_q + d);
  ushort r2[4], r3[4];
#pragma unroll
  for (int j = 0; j < 4; ++j) {
    float rs = rsqrtf(mc[j] + 1e-8f);
    float mrr = (to[j] + trc[j]) * rs;
    float mii = (io[j] + tic[j]) * rs;
    float phq = ph[j] + ql[j] + bq[j];
    float sq, cq;
    __sincosf(phq, &sq, &cq);
    r2[j] = f2bf(mrr * cq + mii * sq);
    r3[j] = f2bf(mii * cq - mrr * sq);
  }
  size_t crow = (size_t)m_ * 4096 + d;
  *(ushort4*)(ctx + crow + 2048) = *(ushort4*)r2;
  *(ushort4*)(ctx + crow + 3072) = *(ushort4*)r3;
}

// ---------------- launcher ----------------
extern "C" void kernel_launch(void* const* d_in, const int* in_sizes, int n_in,
                              void* d_out, int out_size, void* d_ws, size_t ws_size,
                              hipStream_t stream) {
  const float* x      = (const float*)d_in[0];
  const float* W_om   = (const float*)d_in[1];
  const float* b_om   = (const float*)d_in[2];
  const float* W_mag  = (const float*)d_in[3];
  const float* b_mag  = (const float*)d_in[4];
  const float* W_phi  = (const float*)d_in[5];
  const float* b_phi  = (const float*)d_in[6];
  const float* W_gate = (const float*)d_in[7];
  const float* b_gate = (const float*)d_in[8];
  const float* W_q    = (const float*)d_in[9];
  const float* b_q    = (const float*)d_in[10];
  const float* isc    = (const float*)d_in[11];
  const float* W_out  = (const float*)d_in[12];
  const float* b_out  = (const float*)d_in[13];
  float* out = (float*)d_out;

  // ---- ws layout, 213,909,504 bytes total ----
  const size_t WS_NEEDED = 213909504ull;
  if (ws_size < WS_NEEDED) {
    hipMemsetAsync(d_out, 0, (size_t)out_size * sizeof(float), stream);
    return;
  }
  char* w = (char*)d_ws;
  float* planes    = (float*)w;                       // 4 x NELEM fp32
  float* omega_buf = planes;                          // omega_lin -> gated_omega -> phi
  float* gate_buf  = planes + NELEM;                  // gate_lin  -> trcum (local)
  float* mag_buf   = planes + 2 * NELEM;              // mag_lin -> magnitude -> mag cumsum
  float* phi0_buf  = planes + 3 * NELEM;              // phi0_lin -> ticum (local)
  float* q_buf     = out;                             // q_lin (d_out as scratch)
  char* ctxb = w + 4 * NELEM * 4;
  ushort* ctx   = (ushort*)ctxb;                      // [8192][4096] bf16
  ushort* x2    = (ushort*)ctxb;                      // [8192][2048] = [hi|lo]
  ushort* WT    = (ushort*)(ctxb + 33554432);         // hi: om|gate|mag|phi0|q, [n][1024]
  ushort* Wcomp = (ushort*)(ctxb + 44040192);         // [2048 n][2048 k] = [W_lo | W_hi]
  ushort* WoutT = (ushort*)(w + 201326592);           // [1024][4096]
  float* gsum  = (float*)(w + 209715200);
  float* msum  = (float*)(w + 210763776);
  float* trsum = (float*)(w + 211812352);
  float* tisum = (float*)(w + 212860928);

  const size_t DD = (size_t)D_ * D_;

  // conversions
  split_x_kernel<<<(int)(NELEM / 1024), 256, 0, stream>>>(x, x2);
  dim3 tg(16, 16);
  transpose_convert<1><<<tg, 256, 0, stream>>>(W_om,   WT + 0 * DD, 1024,
                                               Wcomp, Wcomp + 1024, 2048, D_, D_);
  transpose_convert<1><<<tg, 256, 0, stream>>>(W_gate, WT + 1 * DD, 1024,
                                               Wcomp + 1024 * 2048, Wcomp + 1024 * 2048 + 1024,
                                               2048, D_, D_);
  transpose_convert<0><<<tg, 256, 0, stream>>>(W_mag,  WT + 2 * DD, 1024, nullptr, nullptr, 0, D_, D_);
  transpose_convert<0><<<tg, 256, 0, stream>>>(W_phi,  WT + 3 * DD, 1024, nullptr, nullptr, 0, D_, D_);
  transpose_convert<0><<<tg, 256, 0, stream>>>(W_q,    WT + 4 * DD, 1024, nullptr, nullptr, 0, D_, D_);
  transpose_convert<0><<<dim3(64, 16), 256, 0, stream>>>(W_out, WoutT, 4096, nullptr, nullptr, 0,
                                                         4 * D_, D_);

  // GEMM1: 5 projections (hi*hi), q plane -> d_out scratch. N=5120, K=1024.
  gemm256<0, 0, 0><<<32 * 20, 512, 0, stream>>>(x2, 2048, WT, planes, q_buf, nullptr, nullptr,
                                                MROWS, 5 * D_, D_);
  // compensation: omega/gate += x_hi@W_lo + x_lo@W_hi. N=2048, K=2048.
  gemm256<1, 0, 0><<<32 * 8, 512, 0, stream>>>(x2, 2048, Wcomp, planes, nullptr, nullptr, nullptr,
                                               MROWS, 2 * D_, 2 * D_);

  // scans + fused elementwise
  prep_chunk_kernel<<<B_ * CCH * (D_ / 4) / 256, 256, 0, stream>>>(
      omega_buf, gate_buf, mag_buf, b_om, b_gate, b_mag, isc, gsum, msum);
  scan_offsets_kernel<<<(B_ * (D_ / 4) + 255) / 256, 256, 0, stream>>>(gsum, msum);
  phase_scan_kernel<<<B_ * CCH * (D_ / 4) / 256, 256, 0, stream>>>(
      x, omega_buf, mag_buf, gate_buf, phi0_buf, gsum, msum, trsum, tisum, b_phi, ctx);
  scan_offsets_kernel<<<(B_ * (D_ / 4) + 255) / 256, 256, 0, stream>>>(trsum, tisum);
  retrieve_kernel<<<(int)(NELEM / 4 / 256), 256, 0, stream>>>(
      omega_buf, mag_buf, gate_buf, phi0_buf, q_buf, trsum, tisum, b_q, ctx);

  // final: out = x + ctx @ W_out + b_out, split-K x2 (256 blocks, full GPU).
  // ks=0 half -> out (with x+bias), ks=1 half -> planes[0] (dead after retrieve).
  gemm256<0, 1, 1><<<2 * 32 * 4, 512, 0, stream>>>(ctx, 4096, WoutT, out, planes, x, b_out,
                                                   MROWS, D_, 4 * D_);
  add_kernel<<<(int)(NELEM / 1024), 256, 0, stream>>>(out, planes);
}

// Round 6
// 427.948 us; speedup vs baseline: 1.2337x; 1.1077x over previous
//
#include <hip/hip_runtime.h>
#include <hip/hip_bf16.h>

// Problem constants (B,S,D fixed by the reference)
#define B_ 4
#define S_ 2048
#define D_ 1024
#define CCH 64                    // chunks along S
#define LCH 32                    // chunk length; CCH*LCH == S_
#define NELEM ((size_t)B_*S_*D_)  // 8388608
#define MROWS (B_*S_)             // 8192

typedef __attribute__((ext_vector_type(4))) float f32x4;
typedef __attribute__((ext_vector_type(8))) short s16x8;  // 8 x bf16 fragment

__device__ __forceinline__ ushort f2bf(float v) {
  __hip_bfloat16 h = __float2bfloat16(v);
  return __builtin_bit_cast(ushort, h);
}
__device__ __forceinline__ float bf2f(ushort u) {
  return __bfloat162float(__builtin_bit_cast(__hip_bfloat16, u));
}

__device__ __forceinline__ void gload16(const ushort* src, char* ldsdst) {
  __builtin_amdgcn_global_load_lds(
      (const __attribute__((address_space(1))) void*)src,
      (__attribute__((address_space(3))) void*)ldsdst, 16, 0, 0);
}

// ---------------- conversions ----------------

// x -> x2 = [x_hi | x_lo] row-major [M][2048] (error-compensated split)
__global__ void split_x_kernel(const float* __restrict__ x, ushort* __restrict__ x2) {
  size_t i = ((size_t)blockIdx.x * blockDim.x + threadIdx.x) * 4;
  if (i >= NELEM) return;
  float4 v = *(const float4*)(x + i);
  float vv[4] = {v.x, v.y, v.z, v.w};
  ushort h[4], l[4];
#pragma unroll
  for (int j = 0; j < 4; ++j) {
    h[j] = f2bf(vv[j]);
    l[j] = f2bf(vv[j] - bf2f(h[j]));
  }
  size_t m = i >> 10, d = i & 1023;
  *(ushort4*)(x2 + m * 2048 + d) = make_ushort4(h[0], h[1], h[2], h[3]);
  *(ushort4*)(x2 + m * 2048 + 1024 + d) = make_ushort4(l[0], l[1], l[2], l[3]);
}

// W [Kd][Nd] f32 -> Th[n*sh+k] bf16 hi; if LO also Tl[n*sl+k] = lo, Th2[n*sl+k] = hi dup.
template <int LO>
__global__ void transpose_convert(const float* __restrict__ W, ushort* __restrict__ Th, int sh,
                                  ushort* __restrict__ Tl, ushort* __restrict__ Th2, int sl,
                                  int Kd, int Nd) {
  __shared__ float tile[64][65];  // +1 pad: conflict-free column reads
  const int k0 = blockIdx.x * 64, n0 = blockIdx.y * 64;
  const int tx = threadIdx.x & 63, ty = threadIdx.x >> 6;  // 64 x 4
#pragma unroll
  for (int i = 0; i < 16; ++i)
    tile[ty * 16 + i][tx] = W[(size_t)(k0 + ty * 16 + i) * Nd + n0 + tx];
  __syncthreads();
#pragma unroll
  for (int i = 0; i < 16; ++i) {
    const int nn = ty * 16 + i;
    float v = tile[tx][nn];
    ushort h = f2bf(v);
    Th[(size_t)(n0 + nn) * sh + k0 + tx] = h;
    if (LO) {
      size_t o = (size_t)(n0 + nn) * sl + k0 + tx;
      Tl[o] = f2bf(v - bf2f(h));
      Th2[o] = h;
    }
  }
}

// ---------------- 256x256 bf16 MFMA GEMM, BK=32, 1 barrier/K-tile ----------------
// 8 waves (2m x 4n), wave tile 128x64. LDS: 2 buffers x (A 256x32 + B 256x32) = 64 KB.
// Depth-1 prefetch: STAGE(t+1) issued at loop top, vmcnt(0) lands it under compute.
// Granule swizzle: phys = logical ^ (row&3) ^ ((row>>2)&3)  (2-way = free).
// MERGED: bid<256 -> heavy (omega|gate, K=3072, A k-dup tiles>=64, B=W3);
//         else light (mag|phi0|q, K=1024, B=Bw2). C plane per col>>10, plane4->C4.
// FINAL+SPLITK: grid 256, K halves; ks=1 writes plain partial to C4.
template <int MERGED, int FINAL, int SPLITK>
__global__ __launch_bounds__(512, 2) void gemm256(
    const ushort* __restrict__ A, int lda,
    const ushort* __restrict__ Bw, const ushort* __restrict__ Bw2,
    float* __restrict__ C, float* __restrict__ C4,
    const float* __restrict__ xres, const float* __restrict__ bias,
    int M, int K) {
  __shared__ __align__(16) char ldsc[2 * 32768];
  int bid = blockIdx.x, ks = 0, tm, tn, Kb, ldb, nB;
  const ushort* Bbase = Bw;
  if (MERGED) {
    if (bid < 256) { tm = bid & 31; tn = bid >> 5; Kb = 3072; ldb = 3072; nB = tn << 8; }
    else {
      bid -= 256; tm = bid & 31; tn = 8 + (bid >> 5);
      Kb = 1024; ldb = 1024; Bbase = Bw2; nB = (tn - 8) << 8;
    }
  } else {
    if (SPLITK && bid >= 128) { ks = 1; bid -= 128; }
    tm = bid & 31; tn = bid >> 5;
    Kb = SPLITK ? (K >> 1) : K; ldb = K; nB = tn << 8;
    A += (size_t)ks * Kb;
    Bbase = Bw + (size_t)ks * Kb;
  }
  const int NT = Kb >> 5;
  const int t = threadIdx.x, lane = t & 63, wid = t >> 6;
  const int wm = wid >> 2, wn = wid & 3;

  f32x4 acc[8][4];
#pragma unroll
  for (int i = 0; i < 8; ++i)
#pragma unroll
    for (int j = 0; j < 4; ++j) acc[i][j] = (f32x4){0.f, 0.f, 0.f, 0.f};

  // ---- staging (pre-swizzled global source, linear LDS dest) ----
  const int lrow = t >> 2;                                       // 0..127
  const int gl = ((t & 3) ^ (lrow & 3) ^ ((lrow >> 2) & 3)) << 3;  // elems
  const ushort* srcA = A + (size_t)(tm * 256 + lrow) * lda + gl;
  const ushort* srcB = Bbase + (size_t)(nB + lrow) * ldb + gl;
  char* dstA = ldsc + (size_t)t * 16;
  char* dstB = ldsc + 16384 + (size_t)t * 16;

  auto STAGE = [&](int tile) {
    if (tile >= NT) return;
    char* ba = dstA + (tile & 1) * 32768;
    char* bb = dstB + (tile & 1) * 32768;
    const int ta = (MERGED && Kb == 3072 && tile >= 64) ? tile - 64 : tile;  // A hi-dup
    const ushort* sa = srcA + ta * 32;
    const ushort* sb = srcB + tile * 32;
    gload16(sa, ba);
    gload16(sa + (size_t)128 * lda, ba + 8192);
    gload16(sb, bb);
    gload16(sb + (size_t)128 * ldb, bb + 8192);
  };

  // ---- fragment reads (swizzled granule) ----
  const int lane15 = lane & 15;
  const int swz = (((lane >> 4) ^ (lane15 & 3) ^ ((lane15 >> 2) & 3)) << 4);
  const char* aB = ldsc + (wm * 128 + lane15) * 64 + swz;
  const char* bB = ldsc + 16384 + (wn * 64 + lane15) * 64 + swz;

  STAGE(0);
  asm volatile("s_waitcnt vmcnt(0)" ::: "memory");
  __builtin_amdgcn_sched_barrier(0);
  __builtin_amdgcn_s_barrier();

#pragma unroll 1
  for (int tt = 0; tt < NT; ++tt) {
    STAGE(tt + 1);
    const char* ab = aB + (tt & 1) * 32768;
    const char* bb = bB + (tt & 1) * 32768;
    s16x8 af[4], bf_[4], af2[4];
#pragma unroll
    for (int f = 0; f < 4; ++f) af[f] = *(const s16x8*)(ab + f * 1024);
#pragma unroll
    for (int c = 0; c < 4; ++c) bf_[c] = *(const s16x8*)(bb + c * 1024);
#pragma unroll
    for (int f = 0; f < 4; ++f) af2[f] = *(const s16x8*)(ab + 4096 + f * 1024);
    asm volatile("s_waitcnt lgkmcnt(4)" ::: "memory");  // af+bf landed (af2 in flight)
    __builtin_amdgcn_sched_barrier(0);
    __builtin_amdgcn_s_setprio(1);
#pragma unroll
    for (int f = 0; f < 4; ++f)
#pragma unroll
      for (int c = 0; c < 4; ++c)
        acc[f][c] = __builtin_amdgcn_mfma_f32_16x16x32_bf16(af[f], bf_[c], acc[f][c], 0, 0, 0);
    __builtin_amdgcn_s_setprio(0);
    asm volatile("s_waitcnt lgkmcnt(0)" ::: "memory");
    __builtin_amdgcn_sched_barrier(0);
    __builtin_amdgcn_s_setprio(1);
#pragma unroll
    for (int f = 0; f < 4; ++f)
#pragma unroll
      for (int c = 0; c < 4; ++c)
        acc[4 + f][c] = __builtin_amdgcn_mfma_f32_16x16x32_bf16(af2[f], bf_[c], acc[4 + f][c], 0, 0, 0);
    __builtin_amdgcn_s_setprio(0);
    asm volatile("s_waitcnt vmcnt(0)" ::: "memory");  // tile tt+1 fully landed
    __builtin_amdgcn_sched_barrier(0);
    __builtin_amdgcn_s_barrier();
  }

  // epilogue. C/D layout: col=lane&15, row=(lane>>4)*4+reg  [m89-verified]
#pragma unroll
  for (int i = 0; i < 8; ++i) {
    const int row0 = tm * 256 + wm * 128 + i * 16 + ((lane >> 4) << 2);
#pragma unroll
    for (int jj = 0; jj < 4; ++jj) {
      const int col = tn * 256 + wn * 64 + jj * 16 + lane15;
      if (SPLITK && ks) {  // partial: plain store to C4 plane
#pragma unroll
        for (int r = 0; r < 4; ++r)
          C4[(size_t)(row0 + r) * 1024 + (col & 1023)] = acc[i][jj][r];
      } else {
        const int pl = col >> 10;
        float* base = (FINAL || pl < 4) ? (C + (size_t)pl * (size_t)M * 1024) : C4;
#pragma unroll
        for (int r = 0; r < 4; ++r) {
          const size_t idx = (size_t)(row0 + r) * 1024 + (col & 1023);
          float v = acc[i][jj][r];
          if (FINAL) v += xres[idx] + bias[col];
          base[idx] = v;
        }
      }
    }
  }
}

// split-K merge: out += partial
__global__ void add_kernel(float* __restrict__ out, const float* __restrict__ p) {
  size_t i = ((size_t)blockIdx.x * blockDim.x + threadIdx.x) * 4;
  if (i >= NELEM) return;
  float4 a = *(const float4*)(out + i);
  float4 b = *(const float4*)(p + i);
  a.x += b.x; a.y += b.y; a.z += b.z; a.w += b.w;
  *(float4*)(out + i) = a;
}

// ---------------- fused elementwise / scan passes (float4) ----------------

// P1+P2: gating/sigmoid transforms in place + per-(b,chunk,d) sums
__global__ void prep_chunk_kernel(float* __restrict__ omega_go, const float* __restrict__ gate_lin,
                                  float* __restrict__ mag_io,
                                  const float* __restrict__ b_om, const float* __restrict__ b_gate,
                                  const float* __restrict__ b_mag, const float* __restrict__ isc,
                                  float* __restrict__ gsum, float* __restrict__ msum) {
  int tid = blockIdx.x * blockDim.x + threadIdx.x;
  if (tid >= B_ * CCH * (D_ / 4)) return;
  int d4 = tid & 255, c = (tid >> 8) & (CCH - 1), b = tid >> 14;
  int d = d4 * 4;
  size_t base = ((size_t)(b * S_) + c * LCH) * D_ + d;
  size_t cs = ((size_t)(b * CCH) + c) * D_ + d;
  float bo[4], bg[4], bm[4], is[4];
  *(float4*)bo = *(const float4*)(b_om + d);
  *(float4*)bg = *(const float4*)(b_gate + d);
  *(float4*)bm = *(const float4*)(b_mag + d);
  *(float4*)is = *(const float4*)(isc + d);
  float sg[4] = {0.f, 0.f, 0.f, 0.f}, sm[4] = {0.f, 0.f, 0.f, 0.f};
  for (int s = 0; s < LCH; ++s) {
    size_t i = base + (size_t)s * D_;
    float om[4], gl[4], mg[4];
    *(float4*)om = *(const float4*)(omega_go + i);
    *(float4*)gl = *(const float4*)(gate_lin + i);
    *(float4*)mg = *(const float4*)(mag_io + i);
#pragma unroll
    for (int j = 0; j < 4; ++j) {
      float g = 1.f / (1.f + __expf(-(gl[j] + bg[j])));
      float m5 = 5.f / (1.f + __expf(-(mg[j] + bm[j])));
      om[j] = g * ((om[j] + bo[j]) * fabsf(is[j]));
      mg[j] = m5;
      sg[j] += om[j];
      sm[j] += m5;
    }
    *(float4*)(omega_go + i) = *(float4*)om;
    *(float4*)(mag_io + i) = *(float4*)mg;
  }
  *(float4*)(gsum + cs) = *(float4*)sg;
  *(float4*)(msum + cs) = *(float4*)sm;
}

// P3/P5: exclusive scan of chunk totals along c — wave-parallel (lane = chunk)
__global__ void scan_offsets_kernel(float* __restrict__ s1, float* __restrict__ s2) {
  int gw = (blockIdx.x * blockDim.x + threadIdx.x) >> 6;
  int lane = threadIdx.x & 63;
  if (gw >= B_ * D_) return;
  int d = gw & (D_ - 1), b = gw >> 10;
  size_t idx = ((size_t)(b * CCH) + lane) * D_ + d;
  float v1 = s1[idx], v2 = s2[idx];
#pragma unroll
  for (int off = 1; off < 64; off <<= 1) {
    float u1 = __shfl_up(v1, off);
    float u2 = __shfl_up(v2, off);
    if (lane >= off) { v1 += u1; v2 += u2; }
  }
  float e1 = __shfl_up(v1, 1), e2 = __shfl_up(v2, 1);
  if (lane == 0) { e1 = 0.f; e2 = 0.f; }
  s1[idx] = e1;
  s2[idx] = e2;
}

// P4 (slim): chunked scan -> ctx parts 0,1 + tr/ti chunk totals. Planes untouched.
__global__ void phase_scan_kernel(const float* __restrict__ x, const float* __restrict__ go,
                                  const float* __restrict__ mag, const float* __restrict__ p0,
                                  const float* __restrict__ goff,
                                  float* __restrict__ trsum, float* __restrict__ tisum,
                                  const float* __restrict__ b_phi, ushort* __restrict__ ctx) {
  int tid = blockIdx.x * blockDim.x + threadIdx.x;
  if (tid >= B_ * CCH * (D_ / 4)) return;
  int d4 = tid & 255, c = (tid >> 8) & (CCH - 1), b = tid >> 14;
  int d = d4 * 4;
  size_t base = ((size_t)(b * S_) + c * LCH) * D_ + d;
  size_t cs = ((size_t)(b * CCH) + c) * D_ + d;
  float pr[4], bp[4];
  *(float4*)pr = *(const float4*)(goff + cs);
  *(float4*)bp = *(const float4*)(b_phi + d);
  float tr[4] = {0.f, 0.f, 0.f, 0.f}, ti[4] = {0.f, 0.f, 0.f, 0.f};
  size_t crow = ((size_t)(b * S_ + c * LCH)) * 4096 + d;
  for (int s = 0; s < LCH; ++s) {
    size_t i = base + (size_t)s * D_;
    float g[4], ph0[4], m[4], xv[4];
    *(float4*)g   = *(const float4*)(go + i);
    *(float4*)ph0 = *(const float4*)(p0 + i);
    *(float4*)m   = *(const float4*)(mag + i);
    *(float4*)xv  = *(const float4*)(x + i);
    ushort c4[4], s4[4];
#pragma unroll
    for (int j = 0; j < 4; ++j) {
      pr[j] += g[j];
      float ph = ph0[j] + bp[j] + pr[j];
      float sp, cp;
      __sincosf(ph, &sp, &cp);
      float wr = m[j] * xv[j];
      tr[j] += wr * cp;
      ti[j] += wr * sp;
      c4[j] = f2bf(xv[j] * cp);
      s4[j] = f2bf(xv[j] * sp);
    }
    *(ushort4*)(ctx + crow) = *(ushort4*)c4;
    *(ushort4*)(ctx + crow + 1024) = *(ushort4*)s4;
    crow += 4096;
  }
  *(float4*)(trsum + cs) = *(float4*)tr;
  *(float4*)(tisum + cs) = *(float4*)ti;
}

// P6 (recompute): re-run the chunk chains, normalize + retrieve -> ctx parts 2,3
__global__ void retrieve_kernel(const float* __restrict__ x, const float* __restrict__ go,
                                const float* __restrict__ mag, const float* __restrict__ p0,
                                const float* __restrict__ q,
                                const float* __restrict__ goff, const float* __restrict__ moff,
                                const float* __restrict__ troff, const float* __restrict__ tioff,
                                const float* __restrict__ b_phi, const float* __restrict__ b_q,
                                ushort* __restrict__ ctx) {
  int tid = blockIdx.x * blockDim.x + threadIdx.x;
  if (tid >= B_ * CCH * (D_ / 4)) return;
  int d4 = tid & 255, c = (tid >> 8) & (CCH - 1), b = tid >> 14;
  int d = d4 * 4;
  size_t base = ((size_t)(b * S_) + c * LCH) * D_ + d;
  size_t cs = ((size_t)(b * CCH) + c) * D_ + d;
  float pr[4], mr[4], tr[4], ti[4], bp[4], bq[4];
  *(float4*)pr = *(const float4*)(goff + cs);
  *(float4*)mr = *(const float4*)(moff + cs);
  *(float4*)tr = *(const float4*)(troff + cs);
  *(float4*)ti = *(const float4*)(tioff + cs);
  *(float4*)bp = *(const float4*)(b_phi + d);
  *(float4*)bq = *(const float4*)(b_q + d);
  size_t crow = ((size_t)(b * S_ + c * LCH)) * 4096 + d;
  for (int s = 0; s < LCH; ++s) {
    size_t i = base + (size_t)s * D_;
    float g[4], ph0[4], m[4], xv[4], qv[4];
    *(float4*)g   = *(const float4*)(go + i);
    *(float4*)ph0 = *(const float4*)(p0 + i);
    *(float4*)m   = *(const float4*)(mag + i);
    *(float4*)xv  = *(const float4*)(x + i);
    *(float4*)qv  = *(const float4*)(q + i);
    ushort r2[4], r3[4];
#pragma unroll
    for (int j = 0; j < 4; ++j) {
      pr[j] += g[j];
      float ph = ph0[j] + bp[j] + pr[j];
      float sp, cp;
      __sincosf(ph, &sp, &cp);
      mr[j] += m[j];
      float wr = m[j] * xv[j];
      tr[j] += wr * cp;
      ti[j] += wr * sp;
      float rs = rsqrtf(mr[j] + 1e-8f);
      float mreal = tr[j] * rs, mimag = ti[j] * rs;
      float phq = ph + qv[j] + bq[j];
      float sq, cq;
      __sincosf(phq, &sq, &cq);
      r2[j] = f2bf(mreal * cq + mimag * sq);
      r3[j] = f2bf(mimag * cq - mreal * sq);
    }
    *(ushort4*)(ctx + crow + 2048) = *(ushort4*)r2;
    *(ushort4*)(ctx + crow + 3072) = *(ushort4*)r3;
    crow += 4096;
  }
}

// ---------------- launcher ----------------
extern "C" void kernel_launch(void* const* d_in, const int* in_sizes, int n_in,
                              void* d_out, int out_size, void* d_ws, size_t ws_size,
                              hipStream_t stream) {
  const float* x      = (const float*)d_in[0];
  const float* W_om   = (const float*)d_in[1];
  const float* b_om   = (const float*)d_in[2];
  const float* W_mag  = (const float*)d_in[3];
  const float* b_mag  = (const float*)d_in[4];
  const float* W_phi  = (const float*)d_in[5];
  const float* b_phi  = (const float*)d_in[6];
  const float* W_gate = (const float*)d_in[7];
  const float* b_gate = (const float*)d_in[8];
  const float* W_q    = (const float*)d_in[9];
  const float* b_q    = (const float*)d_in[10];
  const float* isc    = (const float*)d_in[11];
  const float* W_out  = (const float*)d_in[12];
  const float* b_out  = (const float*)d_in[13];
  float* out = (float*)d_out;

  // ---- ws layout, 213,909,504 bytes ----
  // [0)           4 fp32 planes: omega|gate|mag|phi0 (stay clean until final splitK partial)
  // [134,217,728) ctx bf16 [8192][4096]; overlapped (dead before ctx written):
  //               x2 (32MB) | W3 [2048][3072] (12MB) | WT356 [3072][1024] (6MB)
  // [201,326,592) WoutT [1024][4096]
  // [209,715,200) gsum|msum|trsum|tisum (4 x 1MB)
  // q_lin lives in d_out (overwritten by the final GEMM afterwards).
  const size_t WS_NEEDED = 213909504ull;
  if (ws_size < WS_NEEDED) {
    hipMemsetAsync(d_out, 0, (size_t)out_size * sizeof(float), stream);
    return;
  }
  char* w = (char*)d_ws;
  float* planes    = (float*)w;
  float* omega_buf = planes;
  float* gate_buf  = planes + NELEM;
  float* mag_buf   = planes + 2 * NELEM;
  float* phi0_buf  = planes + 3 * NELEM;
  float* q_buf     = out;
  char* ctxb = w + 4 * NELEM * 4;
  ushort* ctx   = (ushort*)ctxb;
  ushort* x2    = (ushort*)ctxb;                      // [8192][2048] = [hi|lo]
  ushort* W3    = (ushort*)(ctxb + 33554432);         // [2048][3072] = [Wh|Wh|Wl] om,gate
  ushort* WT356 = (ushort*)(ctxb + 46137344);         // [3072][1024] hi: mag|phi0|q
  ushort* WoutT = (ushort*)(w + 201326592);           // [1024][4096]
  float* gsum  = (float*)(w + 209715200);
  float* msum  = (float*)(w + 210763776);
  float* trsum = (float*)(w + 211812352);
  float* tisum = (float*)(w + 212860928);

  const size_t DD = (size_t)D_ * D_;
  ushort* W3g = W3 + (size_t)1024 * 3072;

  // conversions
  split_x_kernel<<<(int)(NELEM / 1024), 256, 0, stream>>>(x, x2);
  dim3 tg(16, 16);
  transpose_convert<1><<<tg, 256, 0, stream>>>(W_om,   W3, 3072, W3 + 2048, W3 + 1024, 3072, D_, D_);
  transpose_convert<1><<<tg, 256, 0, stream>>>(W_gate, W3g, 3072, W3g + 2048, W3g + 1024, 3072, D_, D_);
  transpose_convert<0><<<tg, 256, 0, stream>>>(W_mag,  WT356 + 0 * DD, 1024, nullptr, nullptr, 0, D_, D_);
  transpose_convert<0><<<tg, 256, 0, stream>>>(W_phi,  WT356 + 1 * DD, 1024, nullptr, nullptr, 0, D_, D_);
  transpose_convert<0><<<tg, 256, 0, stream>>>(W_q,    WT356 + 2 * DD, 1024, nullptr, nullptr, 0, D_, D_);
  transpose_convert<0><<<dim3(64, 16), 256, 0, stream>>>(W_out, WoutT, 4096, nullptr, nullptr, 0,
                                                         4 * D_, D_);

  // merged GEMM: 256 heavy blocks (omega|gate, K=3072 hi/lo-compensated) +
  // 384 light blocks (mag|phi0|q, K=1024). q plane -> d_out scratch.
  gemm256<1, 0, 0><<<640, 512, 0, stream>>>(x2, 2048, W3, WT356, planes, q_buf,
                                            nullptr, nullptr, MROWS, 1024);

  // scans + fused elementwise
  prep_chunk_kernel<<<B_ * CCH * (D_ / 4) / 256, 256, 0, stream>>>(
      omega_buf, gate_buf, mag_buf, b_om, b_gate, b_mag, isc, gsum, msum);
  scan_offsets_kernel<<<B_ * D_ * 64 / 256, 256, 0, stream>>>(gsum, msum);
  phase_scan_kernel<<<B_ * CCH * (D_ / 4) / 256, 256, 0, stream>>>(
      x, omega_buf, mag_buf, phi0_buf, gsum, trsum, tisum, b_phi, ctx);
  scan_offsets_kernel<<<B_ * D_ * 64 / 256, 256, 0, stream>>>(trsum, tisum);
  retrieve_kernel<<<B_ * CCH * (D_ / 4) / 256, 256, 0, stream>>>(
      x, omega_buf, mag_buf, phi0_buf, q_buf, gsum, msum, trsum, tisum, b_phi, b_q, ctx);

  // final: out = x + ctx @ W_out + b_out, split-K x2 (256 blocks, full GPU).
  gemm256<0, 1, 1><<<256, 512, 0, stream>>>(ctx, 4096, WoutT, nullptr, out, planes,
                                            x, b_out, MROWS, 4 * D_);
  add_kernel<<<(int)(NELEM / 1024), 256, 0, stream>>>(out, planes);
}

// Round 7
// 415.157 us; speedup vs baseline: 1.2718x; 1.0308x over previous
//
#include <hip/hip_runtime.h>
#include <hip/hip_bf16.h>

// Problem constants (B,S,D fixed by the reference)
#define B_ 4
#define S_ 2048
#define D_ 1024
#define CCH 64                    // chunks along S
#define LCH 32                    // chunk length; CCH*LCH == S_
#define NELEM ((size_t)B_*S_*D_)  // 8388608
#define MROWS (B_*S_)             // 8192

typedef __attribute__((ext_vector_type(4))) float f32x4;
typedef __attribute__((ext_vector_type(8))) short s16x8;  // 8 x bf16 fragment

__device__ __forceinline__ ushort f2bf(float v) {
  __hip_bfloat16 h = __float2bfloat16(v);
  return __builtin_bit_cast(ushort, h);
}
__device__ __forceinline__ float bf2f(ushort u) {
  return __bfloat162float(__builtin_bit_cast(__hip_bfloat16, u));
}

__device__ __forceinline__ void gload16(const ushort* src, char* ldsdst) {
  __builtin_amdgcn_global_load_lds(
      (const __attribute__((address_space(1))) void*)src,
      (__attribute__((address_space(3))) void*)ldsdst, 16, 0, 0);
}

// ---------------- conversions ----------------

// x -> x2 = [x_hi | x_lo] row-major [M][2048] (error-compensated split)
__global__ void split_x_kernel(const float* __restrict__ x, ushort* __restrict__ x2) {
  size_t i = ((size_t)blockIdx.x * blockDim.x + threadIdx.x) * 4;
  if (i >= NELEM) return;
  float4 v = *(const float4*)(x + i);
  float vv[4] = {v.x, v.y, v.z, v.w};
  ushort h[4], l[4];
#pragma unroll
  for (int j = 0; j < 4; ++j) {
    h[j] = f2bf(vv[j]);
    l[j] = f2bf(vv[j] - bf2f(h[j]));
  }
  size_t m = i >> 10, d = i & 1023;
  *(ushort4*)(x2 + m * 2048 + d) = make_ushort4(h[0], h[1], h[2], h[3]);
  *(ushort4*)(x2 + m * 2048 + 1024 + d) = make_ushort4(l[0], l[1], l[2], l[3]);
}

// W [Kd][Nd] f32 -> Th[n*sh+k] bf16 hi; if LO also Tl[n*sl+k] = lo, Th2[n*sl+k] = hi dup.
template <int LO>
__global__ void transpose_convert(const float* __restrict__ W, ushort* __restrict__ Th, int sh,
                                  ushort* __restrict__ Tl, ushort* __restrict__ Th2, int sl,
                                  int Kd, int Nd) {
  __shared__ float tile[64][65];  // +1 pad: conflict-free column reads
  const int k0 = blockIdx.x * 64, n0 = blockIdx.y * 64;
  const int tx = threadIdx.x & 63, ty = threadIdx.x >> 6;  // 64 x 4
#pragma unroll
  for (int i = 0; i < 16; ++i)
    tile[ty * 16 + i][tx] = W[(size_t)(k0 + ty * 16 + i) * Nd + n0 + tx];
  __syncthreads();
#pragma unroll
  for (int i = 0; i < 16; ++i) {
    const int nn = ty * 16 + i;
    float v = tile[tx][nn];
    ushort h = f2bf(v);
    Th[(size_t)(n0 + nn) * sh + k0 + tx] = h;
    if (LO) {
      size_t o = (size_t)(n0 + nn) * sl + k0 + tx;
      Tl[o] = f2bf(v - bf2f(h));
      Th2[o] = h;
    }
  }
}

// ---------------- 256x256 bf16 MFMA GEMM, BK=32, 1 barrier/K-tile ----------------
// 8 waves (2m x 4n), wave tile 128x64. LDS: 2 buffers x (A 256x32 + B 256x32) = 64 KB.
// Depth-1 prefetch: STAGE(t+1) at loop top; vmcnt(0)+barrier once per tile.
// LDS layout: row-pairs packed in 128B lines: line=row>>1, g8=(row&1)*4+kgran,
// phys=g8^(line&7) -> 8 granule positions, 2 lanes/position per quarter (free).
// MERGED: bid<256 -> heavy (omega|gate, K=3072, A k-dup tiles>=64, B=W3);
//         else light (mag|phi0|q, K=1024, B=Bw2). C plane per col>>10, plane4->C4.
// FINAL+SPLITK: grid 256, K halves; ks=1 writes plain partial to C4.
template <int MERGED, int FINAL, int SPLITK>
__global__ __launch_bounds__(512, 2) void gemm256(
    const ushort* __restrict__ A, int lda,
    const ushort* __restrict__ Bw, const ushort* __restrict__ Bw2,
    float* __restrict__ C, float* __restrict__ C4,
    const float* __restrict__ xres, const float* __restrict__ bias,
    int M, int K) {
  __shared__ __align__(16) char ldsc[2 * 32768];
  int bid = blockIdx.x, ks = 0, tm, tn, Kb, ldb, nB;
  const ushort* Bbase = Bw;
  if (MERGED) {
    if (bid < 256) { tm = bid & 31; tn = bid >> 5; Kb = 3072; ldb = 3072; nB = tn << 8; }
    else {
      bid -= 256; tm = bid & 31; tn = 8 + (bid >> 5);
      Kb = 1024; ldb = 1024; Bbase = Bw2; nB = (tn - 8) << 8;
    }
  } else {
    if (SPLITK && bid >= 128) { ks = 1; bid -= 128; }
    tm = bid & 31; tn = bid >> 5;
    Kb = SPLITK ? (K >> 1) : K; ldb = K; nB = tn << 8;
    A += (size_t)ks * Kb;
    Bbase = Bw + (size_t)ks * Kb;
  }
  const int NT = Kb >> 5;
  const int t = threadIdx.x, lane = t & 63, wid = t >> 6;
  const int wm = wid >> 2, wn = wid & 3;

  f32x4 acc[8][4];
#pragma unroll
  for (int i = 0; i < 8; ++i)
#pragma unroll
    for (int j = 0; j < 4; ++j) acc[i][j] = (f32x4){0.f, 0.f, 0.f, 0.f};

  // ---- staging: linear LDS dest t*16; inverse-swizzled global source ----
  // dest granule q=t: line=q>>3, p=q&7 -> g8 = p^(line&7), row=line*2+(g8>>2),
  // k = (g8&3)*8. Second gload at +8192B: line+=64 (line&7 unchanged), row+=128.
  const int line1 = t >> 3;
  const int g8s = (t & 7) ^ (line1 & 7);
  const int rowS = line1 * 2 + (g8s >> 2);
  const int kgS = (g8s & 3) << 3;
  const ushort* srcA = A + (size_t)(tm * 256 + rowS) * lda + kgS;
  const ushort* srcB = Bbase + (size_t)(nB + rowS) * ldb + kgS;
  char* dstA = ldsc + (size_t)t * 16;
  char* dstB = ldsc + 16384 + (size_t)t * 16;

  auto STAGE = [&](int tile) {
    if (tile >= NT) return;
    char* ba = dstA + (tile & 1) * 32768;
    char* bb = dstB + (tile & 1) * 32768;
    const int ta = (MERGED && Kb == 3072 && tile >= 64) ? tile - 64 : tile;  // A hi-dup
    const ushort* sa = srcA + ta * 32;
    const ushort* sb = srcB + tile * 32;
    gload16(sa, ba);
    gload16(sa + (size_t)128 * lda, ba + 8192);
    gload16(sb, bb);
    gload16(sb + (size_t)128 * ldb, bb + 8192);
  };

  // ---- fragment reads: row=base+lane15, kgran=lane>>4 ----
  // byte = (row>>1)*128 + ((((row&1)*4 + kgran) ^ ((row>>1)&7))<<4); f*16 rows = f*1024B.
  const int lane15 = lane & 15;
  const int hl = lane15 >> 1;  // half-line 0..7 (line&7 within any 8-line-aligned block)
  const int swz = ((((lane15 & 1) << 2) + (lane >> 4)) ^ hl) << 4;
  const char* aB = ldsc + wm * 8192 + hl * 128 + swz;
  const char* bB = ldsc + 16384 + wn * 4096 + hl * 128 + swz;

  STAGE(0);
  asm volatile("s_waitcnt vmcnt(0)" ::: "memory");
  __builtin_amdgcn_sched_barrier(0);
  __builtin_amdgcn_s_barrier();

#pragma unroll 1
  for (int tt = 0; tt < NT; ++tt) {
    STAGE(tt + 1);
    const char* ab = aB + (tt & 1) * 32768;
    const char* bb = bB + (tt & 1) * 32768;
    s16x8 af[4], bf_[4], af2[4];
#pragma unroll
    for (int f = 0; f < 4; ++f) af[f] = *(const s16x8*)(ab + f * 1024);
#pragma unroll
    for (int c = 0; c < 4; ++c) bf_[c] = *(const s16x8*)(bb + c * 1024);
#pragma unroll
    for (int f = 0; f < 4; ++f) af2[f] = *(const s16x8*)(ab + 4096 + f * 1024);
    asm volatile("s_waitcnt lgkmcnt(4)" ::: "memory");  // af+bf landed (af2 in flight)
    __builtin_amdgcn_sched_barrier(0);
    __builtin_amdgcn_s_setprio(1);
#pragma unroll
    for (int f = 0; f < 4; ++f)
#pragma unroll
      for (int c = 0; c < 4; ++c)
        acc[f][c] = __builtin_amdgcn_mfma_f32_16x16x32_bf16(af[f], bf_[c], acc[f][c], 0, 0, 0);
    __builtin_amdgcn_s_setprio(0);
    asm volatile("s_waitcnt lgkmcnt(0)" ::: "memory");
    __builtin_amdgcn_sched_barrier(0);
    __builtin_amdgcn_s_setprio(1);
#pragma unroll
    for (int f = 0; f < 4; ++f)
#pragma unroll
      for (int c = 0; c < 4; ++c)
        acc[4 + f][c] = __builtin_amdgcn_mfma_f32_16x16x32_bf16(af2[f], bf_[c], acc[4 + f][c], 0, 0, 0);
    __builtin_amdgcn_s_setprio(0);
    asm volatile("s_waitcnt vmcnt(0)" ::: "memory");  // tile tt+1 fully landed
    __builtin_amdgcn_sched_barrier(0);
    __builtin_amdgcn_s_barrier();
  }

  // epilogue. C/D layout: col=lane&15, row=(lane>>4)*4+reg  [m89-verified]
#pragma unroll
  for (int i = 0; i < 8; ++i) {
    const int row0 = tm * 256 + wm * 128 + i * 16 + ((lane >> 4) << 2);
#pragma unroll
    for (int jj = 0; jj < 4; ++jj) {
      const int col = tn * 256 + wn * 64 + jj * 16 + lane15;
      if (SPLITK && ks) {  // partial: plain store to C4 plane
#pragma unroll
        for (int r = 0; r < 4; ++r)
          C4[(size_t)(row0 + r) * 1024 + (col & 1023)] = acc[i][jj][r];
      } else {
        const int pl = col >> 10;
        float* base = (FINAL || pl < 4) ? (C + (size_t)pl * (size_t)M * 1024) : C4;
#pragma unroll
        for (int r = 0; r < 4; ++r) {
          const size_t idx = (size_t)(row0 + r) * 1024 + (col & 1023);
          float v = acc[i][jj][r];
          if (FINAL) v += xres[idx] + bias[col];
          base[idx] = v;
        }
      }
    }
  }
}

// split-K merge: out += partial
__global__ void add_kernel(float* __restrict__ out, const float* __restrict__ p) {
  size_t i = ((size_t)blockIdx.x * blockDim.x + threadIdx.x) * 4;
  if (i >= NELEM) return;
  float4 a = *(const float4*)(out + i);
  float4 b = *(const float4*)(p + i);
  a.x += b.x; a.y += b.y; a.z += b.z; a.w += b.w;
  *(float4*)(out + i) = a;
}

// ---------------- fused elementwise / scan passes (float4) ----------------

// P1+P2: gating/sigmoid transforms in place + per-(b,chunk,d) sums
__global__ void prep_chunk_kernel(float* __restrict__ omega_go, const float* __restrict__ gate_lin,
                                  float* __restrict__ mag_io,
                                  const float* __restrict__ b_om, const float* __restrict__ b_gate,
                                  const float* __restrict__ b_mag, const float* __restrict__ isc,
                                  float* __restrict__ gsum, float* __restrict__ msum) {
  int tid = blockIdx.x * blockDim.x + threadIdx.x;
  if (tid >= B_ * CCH * (D_ / 4)) return;
  int d4 = tid & 255, c = (tid >> 8) & (CCH - 1), b = tid >> 14;
  int d = d4 * 4;
  size_t base = ((size_t)(b * S_) + c * LCH) * D_ + d;
  size_t cs = ((size_t)(b * CCH) + c) * D_ + d;
  float bo[4], bg[4], bm[4], is[4];
  *(float4*)bo = *(const float4*)(b_om + d);
  *(float4*)bg = *(const float4*)(b_gate + d);
  *(float4*)bm = *(const float4*)(b_mag + d);
  *(float4*)is = *(const float4*)(isc + d);
  float sg[4] = {0.f, 0.f, 0.f, 0.f}, sm[4] = {0.f, 0.f, 0.f, 0.f};
  for (int s = 0; s < LCH; ++s) {
    size_t i = base + (size_t)s * D_;
    float om[4], gl[4], mg[4];
    *(float4*)om = *(const float4*)(omega_go + i);
    *(float4*)gl = *(const float4*)(gate_lin + i);
    *(float4*)mg = *(const float4*)(mag_io + i);
#pragma unroll
    for (int j = 0; j < 4; ++j) {
      float g = 1.f / (1.f + __expf(-(gl[j] + bg[j])));
      float m5 = 5.f / (1.f + __expf(-(mg[j] + bm[j])));
      om[j] = g * ((om[j] + bo[j]) * fabsf(is[j]));
      mg[j] = m5;
      sg[j] += om[j];
      sm[j] += m5;
    }
    *(float4*)(omega_go + i) = *(float4*)om;
    *(float4*)(mag_io + i) = *(float4*)mg;
  }
  *(float4*)(gsum + cs) = *(float4*)sg;
  *(float4*)(msum + cs) = *(float4*)sm;
}

// P3/P5: exclusive scan of chunk totals along c — wave-parallel (lane = chunk)
__global__ void scan_offsets_kernel(float* __restrict__ s1, float* __restrict__ s2) {
  int gw = (blockIdx.x * blockDim.x + threadIdx.x) >> 6;
  int lane = threadIdx.x & 63;
  if (gw >= B_ * D_) return;
  int d = gw & (D_ - 1), b = gw >> 10;
  size_t idx = ((size_t)(b * CCH) + lane) * D_ + d;
  float v1 = s1[idx], v2 = s2[idx];
#pragma unroll
  for (int off = 1; off < 64; off <<= 1) {
    float u1 = __shfl_up(v1, off);
    float u2 = __shfl_up(v2, off);
    if (lane >= off) { v1 += u1; v2 += u2; }
  }
  float e1 = __shfl_up(v1, 1), e2 = __shfl_up(v2, 1);
  if (lane == 0) { e1 = 0.f; e2 = 0.f; }
  s1[idx] = e1;
  s2[idx] = e2;
}

// P4 (slim): chunked scan -> ctx parts 0,1 + tr/ti chunk totals. Planes untouched.
__global__ void phase_scan_kernel(const float* __restrict__ x, const float* __restrict__ go,
                                  const float* __restrict__ mag, const float* __restrict__ p0,
                                  const float* __restrict__ goff,
                                  float* __restrict__ trsum, float* __restrict__ tisum,
                                  const float* __restrict__ b_phi, ushort* __restrict__ ctx) {
  int tid = blockIdx.x * blockDim.x + threadIdx.x;
  if (tid >= B_ * CCH * (D_ / 4)) return;
  int d4 = tid & 255, c = (tid >> 8) & (CCH - 1), b = tid >> 14;
  int d = d4 * 4;
  size_t base = ((size_t)(b * S_) + c * LCH) * D_ + d;
  size_t cs = ((size_t)(b * CCH) + c) * D_ + d;
  float pr[4], bp[4];
  *(float4*)pr = *(const float4*)(goff + cs);
  *(float4*)bp = *(const float4*)(b_phi + d);
  float tr[4] = {0.f, 0.f, 0.f, 0.f}, ti[4] = {0.f, 0.f, 0.f, 0.f};
  size_t crow = ((size_t)(b * S_ + c * LCH)) * 4096 + d;
  for (int s = 0; s < LCH; ++s) {
    size_t i = base + (size_t)s * D_;
    float g[4], ph0[4], m[4], xv[4];
    *(float4*)g   = *(const float4*)(go + i);
    *(float4*)ph0 = *(const float4*)(p0 + i);
    *(float4*)m   = *(const float4*)(mag + i);
    *(float4*)xv  = *(const float4*)(x + i);
    ushort c4[4], s4[4];
#pragma unroll
    for (int j = 0; j < 4; ++j) {
      pr[j] += g[j];
      float ph = ph0[j] + bp[j] + pr[j];
      float sp, cp;
      __sincosf(ph, &sp, &cp);
      float wr = m[j] * xv[j];
      tr[j] += wr * cp;
      ti[j] += wr * sp;
      c4[j] = f2bf(xv[j] * cp);
      s4[j] = f2bf(xv[j] * sp);
    }
    *(ushort4*)(ctx + crow) = *(ushort4*)c4;
    *(ushort4*)(ctx + crow + 1024) = *(ushort4*)s4;
    crow += 4096;
  }
  *(float4*)(trsum + cs) = *(float4*)tr;
  *(float4*)(tisum + cs) = *(float4*)ti;
}

// P6 (recompute): re-run the chunk chains, normalize + retrieve -> ctx parts 2,3
__global__ void retrieve_kernel(const float* __restrict__ x, const float* __restrict__ go,
                                const float* __restrict__ mag, const float* __restrict__ p0,
                                const float* __restrict__ q,
                                const float* __restrict__ goff, const float* __restrict__ moff,
                                const float* __restrict__ troff, const float* __restrict__ tioff,
                                const float* __restrict__ b_phi, const float* __restrict__ b_q,
                                ushort* __restrict__ ctx) {
  int tid = blockIdx.x * blockDim.x + threadIdx.x;
  if (tid >= B_ * CCH * (D_ / 4)) return;
  int d4 = tid & 255, c = (tid >> 8) & (CCH - 1), b = tid >> 14;
  int d = d4 * 4;
  size_t base = ((size_t)(b * S_) + c * LCH) * D_ + d;
  size_t cs = ((size_t)(b * CCH) + c) * D_ + d;
  float pr[4], mr[4], tr[4], ti[4], bp[4], bq[4];
  *(float4*)pr = *(const float4*)(goff + cs);
  *(float4*)mr = *(const float4*)(moff + cs);
  *(float4*)tr = *(const float4*)(troff + cs);
  *(float4*)ti = *(const float4*)(tioff + cs);
  *(float4*)bp = *(const float4*)(b_phi + d);
  *(float4*)bq = *(const float4*)(b_q + d);
  size_t crow = ((size_t)(b * S_ + c * LCH)) * 4096 + d;
  for (int s = 0; s < LCH; ++s) {
    size_t i = base + (size_t)s * D_;
    float g[4], ph0[4], m[4], xv[4], qv[4];
    *(float4*)g   = *(const float4*)(go + i);
    *(float4*)ph0 = *(const float4*)(p0 + i);
    *(float4*)m   = *(const float4*)(mag + i);
    *(float4*)xv  = *(const float4*)(x + i);
    *(float4*)qv  = *(const float4*)(q + i);
    ushort r2[4], r3[4];
#pragma unroll
    for (int j = 0; j < 4; ++j) {
      pr[j] += g[j];
      float ph = ph0[j] + bp[j] + pr[j];
      float sp, cp;
      __sincosf(ph, &sp, &cp);
      mr[j] += m[j];
      float wr = m[j] * xv[j];
      tr[j] += wr * cp;
      ti[j] += wr * sp;
      float rs = rsqrtf(mr[j] + 1e-8f);
      float mreal = tr[j] * rs, mimag = ti[j] * rs;
      float phq = ph + qv[j] + bq[j];
      float sq, cq;
      __sincosf(phq, &sq, &cq);
      r2[j] = f2bf(mreal * cq + mimag * sq);
      r3[j] = f2bf(mimag * cq - mreal * sq);
    }
    *(ushort4*)(ctx + crow + 2048) = *(ushort4*)r2;
    *(ushort4*)(ctx + crow + 3072) = *(ushort4*)r3;
    crow += 4096;
  }
}

// ---------------- launcher ----------------
extern "C" void kernel_launch(void* const* d_in, const int* in_sizes, int n_in,
                              void* d_out, int out_size, void* d_ws, size_t ws_size,
                              hipStream_t stream) {
  const float* x      = (const float*)d_in[0];
  const float* W_om   = (const float*)d_in[1];
  const float* b_om   = (const float*)d_in[2];
  const float* W_mag  = (const float*)d_in[3];
  const float* b_mag  = (const float*)d_in[4];
  const float* W_phi  = (const float*)d_in[5];
  const float* b_phi  = (const float*)d_in[6];
  const float* W_gate = (const float*)d_in[7];
  const float* b_gate = (const float*)d_in[8];
  const float* W_q    = (const float*)d_in[9];
  const float* b_q    = (const float*)d_in[10];
  const float* isc    = (const float*)d_in[11];
  const float* W_out  = (const float*)d_in[12];
  const float* b_out  = (const float*)d_in[13];
  float* out = (float*)d_out;

  // ---- ws layout, 213,909,504 bytes ----
  // [0)           4 fp32 planes: omega|gate|mag|phi0
  // [134,217,728) ctx bf16 [8192][4096]; overlapped (dead before ctx written):
  //               x2 (32MB) | W3 [2048][3072] (12MB) | WT356 [3072][1024] (6MB)
  // [201,326,592) WoutT [1024][4096]
  // [209,715,200) gsum|msum|trsum|tisum (4 x 1MB)
  // q_lin lives in d_out (overwritten by the final GEMM afterwards).
  const size_t WS_NEEDED = 213909504ull;
  if (ws_size < WS_NEEDED) {
    hipMemsetAsync(d_out, 0, (size_t)out_size * sizeof(float), stream);
    return;
  }
  char* w = (char*)d_ws;
  float* planes    = (float*)w;
  float* omega_buf = planes;
  float* gate_buf  = planes + NELEM;
  float* mag_buf   = planes + 2 * NELEM;
  float* phi0_buf  = planes + 3 * NELEM;
  float* q_buf     = out;
  char* ctxb = w + 4 * NELEM * 4;
  ushort* ctx   = (ushort*)ctxb;
  ushort* x2    = (ushort*)ctxb;                      // [8192][2048] = [hi|lo]
  ushort* W3    = (ushort*)(ctxb + 33554432);         // [2048][3072] = [Wh|Wh|Wl] om,gate
  ushort* WT356 = (ushort*)(ctxb + 46137344);         // [3072][1024] hi: mag|phi0|q
  ushort* WoutT = (ushort*)(w + 201326592);           // [1024][4096]
  float* gsum  = (float*)(w + 209715200);
  float* msum  = (float*)(w + 210763776);
  float* trsum = (float*)(w + 211812352);
  float* tisum = (float*)(w + 212860928);

  const size_t DD = (size_t)D_ * D_;
  ushort* W3g = W3 + (size_t)1024 * 3072;

  // conversions
  split_x_kernel<<<(int)(NELEM / 1024), 256, 0, stream>>>(x, x2);
  dim3 tg(16, 16);
  transpose_convert<1><<<tg, 256, 0, stream>>>(W_om,   W3, 3072, W3 + 2048, W3 + 1024, 3072, D_, D_);
  transpose_convert<1><<<tg, 256, 0, stream>>>(W_gate, W3g, 3072, W3g + 2048, W3g + 1024, 3072, D_, D_);
  transpose_convert<0><<<tg, 256, 0, stream>>>(W_mag,  WT356 + 0 * DD, 1024, nullptr, nullptr, 0, D_, D_);
  transpose_convert<0><<<tg, 256, 0, stream>>>(W_phi,  WT356 + 1 * DD, 1024, nullptr, nullptr, 0, D_, D_);
  transpose_convert<0><<<tg, 256, 0, stream>>>(W_q,    WT356 + 2 * DD, 1024, nullptr, nullptr, 0, D_, D_);
  transpose_convert<0><<<dim3(64, 16), 256, 0, stream>>>(W_out, WoutT, 4096, nullptr, nullptr, 0,
                                                         4 * D_, D_);

  // merged GEMM: 256 heavy blocks (omega|gate, K=3072 hi/lo-compensated) +
  // 384 light blocks (mag|phi0|q, K=1024). q plane -> d_out scratch.
  gemm256<1, 0, 0><<<640, 512, 0, stream>>>(x2, 2048, W3, WT356, planes, q_buf,
                                            nullptr, nullptr, MROWS, 1024);

  // scans + fused elementwise
  prep_chunk_kernel<<<B_ * CCH * (D_ / 4) / 256, 256, 0, stream>>>(
      omega_buf, gate_buf, mag_buf, b_om, b_gate, b_mag, isc, gsum, msum);
  scan_offsets_kernel<<<B_ * D_ * 64 / 256, 256, 0, stream>>>(gsum, msum);
  phase_scan_kernel<<<B_ * CCH * (D_ / 4) / 256, 256, 0, stream>>>(
      x, omega_buf, mag_buf, phi0_buf, gsum, trsum, tisum, b_phi, ctx);
  scan_offsets_kernel<<<B_ * D_ * 64 / 256, 256, 0, stream>>>(trsum, tisum);
  retrieve_kernel<<<B_ * CCH * (D_ / 4) / 256, 256, 0, stream>>>(
      x, omega_buf, mag_buf, phi0_buf, q_buf, gsum, msum, trsum, tisum, b_phi, b_q, ctx);

  // final: out = x + ctx @ W_out + b_out, split-K x2 (256 blocks, full GPU).
  gemm256<0, 1, 1><<<256, 512, 0, stream>>>(ctx, 4096, WoutT, nullptr, out, planes,
                                            x, b_out, MROWS, 4 * D_);
  add_kernel<<<(int)(NELEM / 1024), 256, 0, stream>>>(out, planes);
}

// Round 9
// 361.450 us; speedup vs baseline: 1.4607x; 1.1486x over previous
//
#include <hip/hip_runtime.h>
#include <hip/hip_bf16.h>
#include <hip/hip_fp16.h>

// Problem constants (B,S,D fixed by the reference)
#define B_ 4
#define S_ 2048
#define D_ 1024
#define CCH 64                    // chunks along S
#define LCH 32                    // chunk length; CCH*LCH == S_
#define NELEM ((size_t)B_*S_*D_)  // 8388608
#define MROWS (B_*S_)             // 8192

typedef __attribute__((ext_vector_type(4))) float f32x4;
typedef __attribute__((ext_vector_type(8))) _Float16 f16x8;  // 8 x fp16 fragment

__device__ __forceinline__ ushort f2h(float v) {
  __half h = __float2half(v);
  return __builtin_bit_cast(ushort, h);
}

__device__ __forceinline__ void gload16(const ushort* src, char* ldsdst) {
  __builtin_amdgcn_global_load_lds(
      (const __attribute__((address_space(1))) void*)src,
      (__attribute__((address_space(3))) void*)ldsdst, 16, 0, 0);
}

// ---------------- conversions ----------------

// x -> fp16 [M][1024]
__global__ void xhalf_kernel(const float* __restrict__ x, ushort* __restrict__ xh) {
  size_t i = ((size_t)blockIdx.x * blockDim.x + threadIdx.x) * 8;
  if (i >= NELEM) return;
  float4 a = *(const float4*)(x + i);
  float4 b = *(const float4*)(x + i + 4);
  ushort h[8] = {f2h(a.x), f2h(a.y), f2h(a.z), f2h(a.w),
                 f2h(b.x), f2h(b.y), f2h(b.z), f2h(b.w)};
  *(ushort4*)(xh + i) = *(ushort4*)h;
  *(ushort4*)(xh + i + 4) = *(ushort4*)(h + 4);
}

// W [Kd][Nd] f32 -> Th[n*sh+k] fp16 (transposed). LDS-tiled, coalesced both sides.
__global__ void transpose_convert(const float* __restrict__ W, ushort* __restrict__ Th, int sh,
                                  int Kd, int Nd) {
  __shared__ float tile[64][65];  // +1 pad: conflict-free column reads
  const int k0 = blockIdx.x * 64, n0 = blockIdx.y * 64;
  const int tx = threadIdx.x & 63, ty = threadIdx.x >> 6;  // 64 x 4
#pragma unroll
  for (int i = 0; i < 16; ++i)
    tile[ty * 16 + i][tx] = W[(size_t)(k0 + ty * 16 + i) * Nd + n0 + tx];
  __syncthreads();
#pragma unroll
  for (int i = 0; i < 16; ++i) {
    const int nn = ty * 16 + i;
    Th[(size_t)(n0 + nn) * sh + k0 + tx] = f2h(tile[tx][nn]);
  }
}

// ---------------- 256x256 fp16 MFMA GEMM, BK=32, 1 barrier/K-tile ----------------
// 8 waves (2m x 4n), wave tile 128x64. LDS: 2 buffers x (A 256x32 + B 256x32) = 64 KB.
// Depth-1 prefetch: STAGE(t+1) at loop top; vmcnt(0)+barrier once per tile.
// LDS layout: row-pairs packed in 128B lines: line=row>>1, g8=(row&1)*4+kgran,
// phys=g8^(line&7) -> 8 granule positions, conflict-free (verified r7: conflicts=0).
// C plane stacking (!FINAL): col>>10 selects fp32 plane in C; plane 4 -> C4.
// FINAL+SPLITK: grid 256, K halves; ks=1 writes plain partial to C4.
template <int FINAL, int SPLITK>
__global__ __launch_bounds__(512, 2) void gemm256(
    const ushort* __restrict__ A, int lda, const ushort* __restrict__ Bw,
    float* __restrict__ C, float* __restrict__ C4,
    const float* __restrict__ xres, const float* __restrict__ bias,
    int M, int K) {
  __shared__ __align__(16) char ldsc[2 * 32768];
  int bid = blockIdx.x, ks = 0;
  if (SPLITK && bid >= 128) { ks = 1; bid -= 128; }
  const int tm = bid & 31, tn = bid >> 5;
  const int Kb = SPLITK ? (K >> 1) : K;
  const int ldb = K;
  const int nB = tn << 8;
  if (SPLITK) { A += (size_t)ks * Kb; Bw += (size_t)ks * Kb; }
  const int NT = Kb >> 5;
  const int t = threadIdx.x, lane = t & 63, wid = t >> 6;
  const int wm = wid >> 2, wn = wid & 3;

  f32x4 acc[8][4];
#pragma unroll
  for (int i = 0; i < 8; ++i)
#pragma unroll
    for (int j = 0; j < 4; ++j) acc[i][j] = (f32x4){0.f, 0.f, 0.f, 0.f};

  // ---- staging: linear LDS dest t*16; inverse-swizzled global source ----
  const int line1 = t >> 3;
  const int g8s = (t & 7) ^ (line1 & 7);
  const int rowS = line1 * 2 + (g8s >> 2);
  const int kgS = (g8s & 3) << 3;
  const ushort* srcA = A + (size_t)(tm * 256 + rowS) * lda + kgS;
  const ushort* srcB = Bw + (size_t)(nB + rowS) * ldb + kgS;
  char* dstA = ldsc + (size_t)t * 16;
  char* dstB = ldsc + 16384 + (size_t)t * 16;

  auto STAGE = [&](int tile) {
    if (tile >= NT) return;
    char* ba = dstA + (tile & 1) * 32768;
    char* bb = dstB + (tile & 1) * 32768;
    const ushort* sa = srcA + tile * 32;
    const ushort* sb = srcB + tile * 32;
    gload16(sa, ba);
    gload16(sa + (size_t)128 * lda, ba + 8192);
    gload16(sb, bb);
    gload16(sb + (size_t)128 * ldb, bb + 8192);
  };

  // ---- fragment reads: row=base+lane15, kgran=lane>>4 ----
  const int lane15 = lane & 15;
  const int hl = lane15 >> 1;
  const int swz = ((((lane15 & 1) << 2) + (lane >> 4)) ^ hl) << 4;
  const char* aB = ldsc + wm * 8192 + hl * 128 + swz;
  const char* bB = ldsc + 16384 + wn * 4096 + hl * 128 + swz;

  STAGE(0);
  asm volatile("s_waitcnt vmcnt(0)" ::: "memory");
  __builtin_amdgcn_sched_barrier(0);
  __builtin_amdgcn_s_barrier();

#pragma unroll 1
  for (int tt = 0; tt < NT; ++tt) {
    STAGE(tt + 1);
    const char* ab = aB + (tt & 1) * 32768;
    const char* bb = bB + (tt & 1) * 32768;
    f16x8 af[4], bf_[4], af2[4];
#pragma unroll
    for (int f = 0; f < 4; ++f) af[f] = *(const f16x8*)(ab + f * 1024);
#pragma unroll
    for (int c = 0; c < 4; ++c) bf_[c] = *(const f16x8*)(bb + c * 1024);
#pragma unroll
    for (int f = 0; f < 4; ++f) af2[f] = *(const f16x8*)(ab + 4096 + f * 1024);
    asm volatile("s_waitcnt lgkmcnt(4)" ::: "memory");  // af+bf landed (af2 in flight)
    __builtin_amdgcn_sched_barrier(0);
    __builtin_amdgcn_s_setprio(1);
#pragma unroll
    for (int f = 0; f < 4; ++f)
#pragma unroll
      for (int c = 0; c < 4; ++c)
        acc[f][c] = __builtin_amdgcn_mfma_f32_16x16x32_f16(af[f], bf_[c], acc[f][c], 0, 0, 0);
    __builtin_amdgcn_s_setprio(0);
    asm volatile("s_waitcnt lgkmcnt(0)" ::: "memory");
    __builtin_amdgcn_sched_barrier(0);
    __builtin_amdgcn_s_setprio(1);
#pragma unroll
    for (int f = 0; f < 4; ++f)
#pragma unroll
      for (int c = 0; c < 4; ++c)
        acc[4 + f][c] = __builtin_amdgcn_mfma_f32_16x16x32_f16(af2[f], bf_[c], acc[4 + f][c], 0, 0, 0);
    __builtin_amdgcn_s_setprio(0);
    asm volatile("s_waitcnt vmcnt(0)" ::: "memory");  // tile tt+1 fully landed
    __builtin_amdgcn_sched_barrier(0);
    __builtin_amdgcn_s_barrier();
  }

  // epilogue. C/D layout: col=lane&15, row=(lane>>4)*4+reg  [m89-verified]
#pragma unroll
  for (int i = 0; i < 8; ++i) {
    const int row0 = tm * 256 + wm * 128 + i * 16 + ((lane >> 4) << 2);
#pragma unroll
    for (int jj = 0; jj < 4; ++jj) {
      const int col = tn * 256 + wn * 64 + jj * 16 + lane15;
      if (SPLITK && ks) {  // partial: plain store to C4 plane
#pragma unroll
        for (int r = 0; r < 4; ++r)
          C4[(size_t)(row0 + r) * 1024 + (col & 1023)] = acc[i][jj][r];
      } else {
        const int pl = col >> 10;
        float* base = (FINAL || pl < 4) ? (C + (size_t)pl * (size_t)M * 1024) : C4;
#pragma unroll
        for (int r = 0; r < 4; ++r) {
          const size_t idx = (size_t)(row0 + r) * 1024 + (col & 1023);
          float v = acc[i][jj][r];
          if (FINAL) v += xres[idx] + bias[col];
          base[idx] = v;
        }
      }
    }
  }
}

// split-K merge: out += partial
__global__ void add_kernel(float* __restrict__ out, const float* __restrict__ p) {
  size_t i = ((size_t)blockIdx.x * blockDim.x + threadIdx.x) * 4;
  if (i >= NELEM) return;
  float4 a = *(const float4*)(out + i);
  float4 b = *(const float4*)(p + i);
  a.x += b.x; a.y += b.y; a.z += b.z; a.w += b.w;
  *(float4*)(out + i) = a;
}

// ---------------- fused elementwise / scan passes (float4) ----------------

// P1+P2: gating/sigmoid transforms in place + per-(b,chunk,d) sums
__global__ void prep_chunk_kernel(float* __restrict__ omega_go, const float* __restrict__ gate_lin,
                                  float* __restrict__ mag_io,
                                  const float* __restrict__ b_om, const float* __restrict__ b_gate,
                                  const float* __restrict__ b_mag, const float* __restrict__ isc,
                                  float* __restrict__ gsum, float* __restrict__ msum) {
  int tid = blockIdx.x * blockDim.x + threadIdx.x;
  if (tid >= B_ * CCH * (D_ / 4)) return;
  int d4 = tid & 255, c = (tid >> 8) & (CCH - 1), b = tid >> 14;
  int d = d4 * 4;
  size_t base = ((size_t)(b * S_) + c * LCH) * D_ + d;
  size_t cs = ((size_t)(b * CCH) + c) * D_ + d;
  float bo[4], bg[4], bm[4], is[4];
  *(float4*)bo = *(const float4*)(b_om + d);
  *(float4*)bg = *(const float4*)(b_gate + d);
  *(float4*)bm = *(const float4*)(b_mag + d);
  *(float4*)is = *(const float4*)(isc + d);
  float sg[4] = {0.f, 0.f, 0.f, 0.f}, sm[4] = {0.f, 0.f, 0.f, 0.f};
  for (int s = 0; s < LCH; ++s) {
    size_t i = base + (size_t)s * D_;
    float om[4], gl[4], mg[4];
    *(float4*)om = *(const float4*)(omega_go + i);
    *(float4*)gl = *(const float4*)(gate_lin + i);
    *(float4*)mg = *(const float4*)(mag_io + i);
#pragma unroll
    for (int j = 0; j < 4; ++j) {
      float g = 1.f / (1.f + __expf(-(gl[j] + bg[j])));
      float m5 = 5.f / (1.f + __expf(-(mg[j] + bm[j])));
      om[j] = g * ((om[j] + bo[j]) * fabsf(is[j]));
      mg[j] = m5;
      sg[j] += om[j];
      sm[j] += m5;
    }
    *(float4*)(omega_go + i) = *(float4*)om;
    *(float4*)(mag_io + i) = *(float4*)mg;
  }
  *(float4*)(gsum + cs) = *(float4*)sg;
  *(float4*)(msum + cs) = *(float4*)sm;
}

// P3/P5: exclusive scan of chunk totals along c — wave-parallel (lane = chunk)
__global__ void scan_offsets_kernel(float* __restrict__ s1, float* __restrict__ s2) {
  int gw = (blockIdx.x * blockDim.x + threadIdx.x) >> 6;
  int lane = threadIdx.x & 63;
  if (gw >= B_ * D_) return;
  int d = gw & (D_ - 1), b = gw >> 10;
  size_t idx = ((size_t)(b * CCH) + lane) * D_ + d;
  float v1 = s1[idx], v2 = s2[idx];
#pragma unroll
  for (int off = 1; off < 64; off <<= 1) {
    float u1 = __shfl_up(v1, off);
    float u2 = __shfl_up(v2, off);
    if (lane >= off) { v1 += u1; v2 += u2; }
  }
  float e1 = __shfl_up(v1, 1), e2 = __shfl_up(v2, 1);
  if (lane == 0) { e1 = 0.f; e2 = 0.f; }
  s1[idx] = e1;
  s2[idx] = e2;
}

// P4 (slim): chunked scan -> ctx parts 0,1 + tr/ti chunk totals. Planes untouched.
__global__ void phase_scan_kernel(const float* __restrict__ x, const float* __restrict__ go,
                                  const float* __restrict__ mag, const float* __restrict__ p0,
                                  const float* __restrict__ goff,
                                  float* __restrict__ trsum, float* __restrict__ tisum,
                                  const float* __restrict__ b_phi, ushort* __restrict__ ctx) {
  int tid = blockIdx.x * blockDim.x + threadIdx.x;
  if (tid >= B_ * CCH * (D_ / 4)) return;
  int d4 = tid & 255, c = (tid >> 8) & (CCH - 1), b = tid >> 14;
  int d = d4 * 4;
  size_t base = ((size_t)(b * S_) + c * LCH) * D_ + d;
  size_t cs = ((size_t)(b * CCH) + c) * D_ + d;
  float pr[4], bp[4];
  *(float4*)pr = *(const float4*)(goff + cs);
  *(float4*)bp = *(const float4*)(b_phi + d);
  float tr[4] = {0.f, 0.f, 0.f, 0.f}, ti[4] = {0.f, 0.f, 0.f, 0.f};
  size_t crow = ((size_t)(b * S_ + c * LCH)) * 4096 + d;
  for (int s = 0; s < LCH; ++s) {
    size_t i = base + (size_t)s * D_;
    float g[4], ph0[4], m[4], xv[4];
    *(float4*)g   = *(const float4*)(go + i);
    *(float4*)ph0 = *(const float4*)(p0 + i);
    *(float4*)m   = *(const float4*)(mag + i);
    *(float4*)xv  = *(const float4*)(x + i);
    ushort c4[4], s4[4];
#pragma unroll
    for (int j = 0; j < 4; ++j) {
      pr[j] += g[j];
      float ph = ph0[j] + bp[j] + pr[j];
      float sp, cp;
      __sincosf(ph, &sp, &cp);
      float wr = m[j] * xv[j];
      tr[j] += wr * cp;
      ti[j] += wr * sp;
      c4[j] = f2h(xv[j] * cp);
      s4[j] = f2h(xv[j] * sp);
    }
    *(ushort4*)(ctx + crow) = *(ushort4*)c4;
    *(ushort4*)(ctx + crow + 1024) = *(ushort4*)s4;
    crow += 4096;
  }
  *(float4*)(trsum + cs) = *(float4*)tr;
  *(float4*)(tisum + cs) = *(float4*)ti;
}

// P6 (recompute): re-run the chunk chains, normalize + retrieve -> ctx parts 2,3
__global__ void retrieve_kernel(const float* __restrict__ x, const float* __restrict__ go,
                                const float* __restrict__ mag, const float* __restrict__ p0,
                                const float* __restrict__ q,
                                const float* __restrict__ goff, const float* __restrict__ moff,
                                const float* __restrict__ troff, const float* __restrict__ tioff,
                                const float* __restrict__ b_phi, const float* __restrict__ b_q,
                                ushort* __restrict__ ctx) {
  int tid = blockIdx.x * blockDim.x + threadIdx.x;
  if (tid >= B_ * CCH * (D_ / 4)) return;
  int d4 = tid & 255, c = (tid >> 8) & (CCH - 1), b = tid >> 14;
  int d = d4 * 4;
  size_t base = ((size_t)(b * S_) + c * LCH) * D_ + d;
  size_t cs = ((size_t)(b * CCH) + c) * D_ + d;
  float pr[4], mr[4], tr[4], ti[4], bp[4], bq[4];
  *(float4*)pr = *(const float4*)(goff + cs);
  *(float4*)mr = *(const float4*)(moff + cs);
  *(float4*)tr = *(const float4*)(troff + cs);
  *(float4*)ti = *(const float4*)(tioff + cs);
  *(float4*)bp = *(const float4*)(b_phi + d);
  *(float4*)bq = *(const float4*)(b_q + d);
  size_t crow = ((size_t)(b * S_ + c * LCH)) * 4096 + d;
  for (int s = 0; s < LCH; ++s) {
    size_t i = base + (size_t)s * D_;
    float g[4], ph0[4], m[4], xv[4], qv[4];
    *(float4*)g   = *(const float4*)(go + i);
    *(float4*)ph0 = *(const float4*)(p0 + i);
    *(float4*)m   = *(const float4*)(mag + i);
    *(float4*)xv  = *(const float4*)(x + i);
    *(float4*)qv  = *(const float4*)(q + i);
    ushort r2[4], r3[4];
#pragma unroll
    for (int j = 0; j < 4; ++j) {
      pr[j] += g[j];
      float ph = ph0[j] + bp[j] + pr[j];
      float sp, cp;
      __sincosf(ph, &sp, &cp);
      mr[j] += m[j];
      float wr = m[j] * xv[j];
      tr[j] += wr * cp;
      ti[j] += wr * sp;
      float rs = rsqrtf(mr[j] + 1e-8f);
      float mreal = tr[j] * rs, mimag = ti[j] * rs;
      float phq = ph + qv[j] + bq[j];
      float sq, cq;
      __sincosf(phq, &sq, &cq);
      r2[j] = f2h(mreal * cq + mimag * sq);
      r3[j] = f2h(mimag * cq - mreal * sq);
    }
    *(ushort4*)(ctx + crow + 2048) = *(ushort4*)r2;
    *(ushort4*)(ctx + crow + 3072) = *(ushort4*)r3;
    crow += 4096;
  }
}

// ---------------- launcher ----------------
extern "C" void kernel_launch(void* const* d_in, const int* in_sizes, int n_in,
                              void* d_out, int out_size, void* d_ws, size_t ws_size,
                              hipStream_t stream) {
  const float* x      = (const float*)d_in[0];
  const float* W_om   = (const float*)d_in[1];
  const float* b_om   = (const float*)d_in[2];
  const float* W_mag  = (const float*)d_in[3];
  const float* b_mag  = (const float*)d_in[4];
  const float* W_phi  = (const float*)d_in[5];
  const float* b_phi  = (const float*)d_in[6];
  const float* W_gate = (const float*)d_in[7];
  const float* b_gate = (const float*)d_in[8];
  const float* W_q    = (const float*)d_in[9];
  const float* b_q    = (const float*)d_in[10];
  const float* isc    = (const float*)d_in[11];
  const float* W_out  = (const float*)d_in[12];
  const float* b_out  = (const float*)d_in[13];
  float* out = (float*)d_out;

  // ---- ws layout, 213,909,504 bytes ----
  // [0)           4 fp32 planes: omega|gate|mag|phi0
  // [134,217,728) ctx fp16 [8192][4096]; overlapped (dead before ctx written):
  //               x_h fp16 (16MB) | W5T [5120][1024] fp16 (10MB)
  // [201,326,592) WoutT [1024][4096] fp16
  // [209,715,200) gsum|msum|trsum|tisum (4 x 1MB)
  // q_lin lives in d_out (overwritten by the final GEMM afterwards).
  const size_t WS_NEEDED = 213909504ull;
  if (ws_size < WS_NEEDED) {
    (void)hipMemsetAsync(d_out, 0, (size_t)out_size * sizeof(float), stream);
    return;
  }
  char* w = (char*)d_ws;
  float* planes    = (float*)w;
  float* omega_buf = planes;
  float* gate_buf  = planes + NELEM;
  float* mag_buf   = planes + 2 * NELEM;
  float* phi0_buf  = planes + 3 * NELEM;
  float* q_buf     = out;
  char* ctxb = w + 4 * NELEM * 4;
  ushort* ctx   = (ushort*)ctxb;
  ushort* x_h   = (ushort*)ctxb;                      // [8192][1024] fp16
  ushort* W5T   = (ushort*)(ctxb + 16777216);         // [5120][1024]: om|gate|mag|phi0|q
  ushort* WoutT = (ushort*)(w + 201326592);           // [1024][4096]
  float* gsum  = (float*)(w + 209715200);
  float* msum  = (float*)(w + 210763776);
  float* trsum = (float*)(w + 211812352);
  float* tisum = (float*)(w + 212860928);

  const size_t DD = (size_t)D_ * D_;

  // conversions
  xhalf_kernel<<<(int)(NELEM / 2048), 256, 0, stream>>>(x, x_h);
  dim3 tg(16, 16);
  transpose_convert<<<tg, 256, 0, stream>>>(W_om,   W5T + 0 * DD, 1024, D_, D_);
  transpose_convert<<<tg, 256, 0, stream>>>(W_gate, W5T + 1 * DD, 1024, D_, D_);
  transpose_convert<<<tg, 256, 0, stream>>>(W_mag,  W5T + 2 * DD, 1024, D_, D_);
  transpose_convert<<<tg, 256, 0, stream>>>(W_phi,  W5T + 3 * DD, 1024, D_, D_);
  transpose_convert<<<tg, 256, 0, stream>>>(W_q,    W5T + 4 * DD, 1024, D_, D_);
  transpose_convert<<<dim3(64, 16), 256, 0, stream>>>(W_out, WoutT, 4096, 4 * D_, D_);

  // GEMM1: 5 projections, N=5120, K=1024, fp16. q plane -> d_out scratch.
  gemm256<0, 0><<<640, 512, 0, stream>>>(x_h, 1024, W5T, planes, q_buf,
                                         nullptr, nullptr, MROWS, 1024);

  // scans + fused elementwise
  prep_chunk_kernel<<<B_ * CCH * (D_ / 4) / 256, 256, 0, stream>>>(
      omega_buf, gate_buf, mag_buf, b_om, b_gate, b_mag, isc, gsum, msum);
  scan_offsets_kernel<<<B_ * D_ * 64 / 256, 256, 0, stream>>>(gsum, msum);
  phase_scan_kernel<<<B_ * CCH * (D_ / 4) / 256, 256, 0, stream>>>(
      x, omega_buf, mag_buf, phi0_buf, gsum, trsum, tisum, b_phi, ctx);
  scan_offsets_kernel<<<B_ * D_ * 64 / 256, 256, 0, stream>>>(trsum, tisum);
  retrieve_kernel<<<B_ * CCH * (D_ / 4) / 256, 256, 0, stream>>>(
      x, omega_buf, mag_buf, phi0_buf, q_buf, gsum, msum, trsum, tisum, b_phi, b_q, ctx);

  // final: out = x + ctx @ W_out + b_out, split-K x2 (256 blocks, full GPU).
  gemm256<1, 1><<<256, 512, 0, stream>>>(ctx, 4096, WoutT, out, planes,
                                         x, b_out, MROWS, 4 * D_);
  add_kernel<<<(int)(NELEM / 1024), 256, 0, stream>>>(out, planes);
}

// Round 10
// 333.446 us; speedup vs baseline: 1.5834x; 1.0840x over previous
//
#include <hip/hip_runtime.h>
#include <hip/hip_fp16.h>

// Problem constants (B,S,D fixed by the reference)
#define B_ 4
#define S_ 2048
#define D_ 1024
#define CCH 64                    // chunks along S
#define LCH 32                    // chunk length; CCH*LCH == S_
#define NELEM ((size_t)B_*S_*D_)  // 8388608
#define MROWS (B_*S_)             // 8192

typedef __attribute__((ext_vector_type(16))) float f32x16;
typedef __attribute__((ext_vector_type(8))) _Float16 f16x8;  // 8 x fp16 fragment

__device__ __forceinline__ ushort f2h(float v) {
  __half h = __float2half(v);
  return __builtin_bit_cast(ushort, h);
}
__device__ __forceinline__ float h2f(ushort u) {
  return __half2float(__builtin_bit_cast(__half, u));
}

__device__ __forceinline__ void gload16(const ushort* src, char* ldsdst) {
  __builtin_amdgcn_global_load_lds(
      (const __attribute__((address_space(1))) void*)src,
      (__attribute__((address_space(3))) void*)ldsdst, 16, 0, 0);
}

// ---------------- conversions ----------------

// x -> fp16 [M][1024]
__global__ void xhalf_kernel(const float* __restrict__ x, ushort* __restrict__ xh) {
  size_t i = ((size_t)blockIdx.x * blockDim.x + threadIdx.x) * 8;
  if (i >= NELEM) return;
  float4 a = *(const float4*)(x + i);
  float4 b = *(const float4*)(x + i + 4);
  ushort h[8] = {f2h(a.x), f2h(a.y), f2h(a.z), f2h(a.w),
                 f2h(b.x), f2h(b.y), f2h(b.z), f2h(b.w)};
  *(ushort4*)(xh + i) = *(ushort4*)h;
  *(ushort4*)(xh + i + 4) = *(ushort4*)(h + 4);
}

// W [Kd][Nd] f32 -> Th[n*sh+k] fp16 (transposed). LDS-tiled, coalesced both sides.
__global__ void transpose_convert(const float* __restrict__ W, ushort* __restrict__ Th, int sh,
                                  int Kd, int Nd) {
  __shared__ float tile[64][65];  // +1 pad: conflict-free column reads
  const int k0 = blockIdx.x * 64, n0 = blockIdx.y * 64;
  const int tx = threadIdx.x & 63, ty = threadIdx.x >> 6;  // 64 x 4
#pragma unroll
  for (int i = 0; i < 16; ++i)
    tile[ty * 16 + i][tx] = W[(size_t)(k0 + ty * 16 + i) * Nd + n0 + tx];
  __syncthreads();
#pragma unroll
  for (int i = 0; i < 16; ++i) {
    const int nn = ty * 16 + i;
    Th[(size_t)(n0 + nn) * sh + k0 + tx] = f2h(tile[tx][nn]);
  }
}

// ------- 256x256 fp16 MFMA GEMM, 32x32x16 fragments, BK=32, 1 barrier/K-tile -------
// 8 waves (2m x 4n), wave tile 128x64 = 4m x 2n subtiles of 32x32.
// LDS: 2 buffers x (A 256x32 + B 256x32) = 64 KB; row-pair 128B lines,
// phys granule = ((row&1)*4 + kgran) ^ ((row>>1)&7)  -> <=2-way aliasing (free).
// Depth-1 prefetch: STAGE(t+1) at loop top; vmcnt(0)+barrier once per K-tile.
// !FINAL: writes fp16 planes Ch (col>>10 selects plane; plane 4 -> C4h).
// FINAL+SPLITK: grid 256, K halves; ks=0 -> Cf=out (+x+bias), ks=1 -> C4f partial.
template <int FINAL, int SPLITK>
__global__ __launch_bounds__(512, 2) void gemm256(
    const ushort* __restrict__ A, int lda, const ushort* __restrict__ Bw,
    ushort* __restrict__ Ch, ushort* __restrict__ C4h,
    float* __restrict__ Cf, float* __restrict__ C4f,
    const float* __restrict__ xres, const float* __restrict__ bias,
    int M, int K) {
  __shared__ __align__(16) char ldsc[2 * 32768];
  int bid = blockIdx.x, ks = 0;
  if (SPLITK && bid >= 128) { ks = 1; bid -= 128; }
  const int tm = bid & 31, tn = bid >> 5;
  const int Kb = SPLITK ? (K >> 1) : K;
  const int ldb = K;
  const int nB = tn << 8;
  if (SPLITK) { A += (size_t)ks * Kb; Bw += (size_t)ks * Kb; }
  const int NT = Kb >> 5;
  const int t = threadIdx.x, lane = t & 63, wid = t >> 6;
  const int wm = wid >> 2, wn = wid & 3;

  f32x16 acc[4][2];
#pragma unroll
  for (int i = 0; i < 4; ++i)
#pragma unroll
    for (int j = 0; j < 2; ++j)
#pragma unroll
      for (int r = 0; r < 16; ++r) acc[i][j][r] = 0.f;

  // ---- staging: linear LDS dest t*16; inverse-swizzled global source ----
  const int line1 = t >> 3;
  const int g8s = (t & 7) ^ (line1 & 7);
  const int rowS = line1 * 2 + (g8s >> 2);
  const int kgS = (g8s & 3) << 3;
  const ushort* srcA = A + (size_t)(tm * 256 + rowS) * lda + kgS;
  const ushort* srcB = Bw + (size_t)(nB + rowS) * ldb + kgS;
  char* dstA = ldsc + (size_t)t * 16;
  char* dstB = ldsc + 16384 + (size_t)t * 16;

  auto STAGE = [&](int tile) {
    if (tile >= NT) return;
    char* ba = dstA + (tile & 1) * 32768;
    char* bb = dstB + (tile & 1) * 32768;
    const ushort* sa = srcA + tile * 32;
    const ushort* sb = srcB + tile * 32;
    gload16(sa, ba);
    gload16(sa + (size_t)128 * lda, ba + 8192);
    gload16(sb, bb);
    gload16(sb + (size_t)128 * ldb, bb + 8192);
  };

  // ---- fragment reads (32x32x16): row = sub*32 + (lane&31), kgran = ks*2 + (lane>>5) ----
  const int l31 = lane & 31;
  const int lline = l31 >> 1;                 // line within 32-row subtile (0..15)
  const int lpar4 = (lane & 1) << 2;          // (row&1)*4
  const int khi = lane >> 5;                  // k half
  const int swzk0 = ((lpar4 + 0 + khi) ^ (lline & 7)) << 4;
  const int swzk1 = ((lpar4 + 2 + khi) ^ (lline & 7)) << 4;
  const char* aB = ldsc + wm * 8192 + lline * 128;            // + mt*2048 + swz
  const char* bB = ldsc + 16384 + wn * 4096 + lline * 128;    // + nt*2048 + swz

  STAGE(0);
  asm volatile("s_waitcnt vmcnt(0)" ::: "memory");
  __builtin_amdgcn_sched_barrier(0);
  __builtin_amdgcn_s_barrier();

#pragma unroll 1
  for (int tt = 0; tt < NT; ++tt) {
    STAGE(tt + 1);
    const char* ab = aB + (tt & 1) * 32768;
    const char* bb = bB + (tt & 1) * 32768;
    f16x8 af[4][2], bf_[2][2];
    // issue k-step0 frags first (6), then k-step1 (6)
#pragma unroll
    for (int mt = 0; mt < 4; ++mt) af[mt][0] = *(const f16x8*)(ab + mt * 2048 + swzk0);
#pragma unroll
    for (int nt = 0; nt < 2; ++nt) bf_[nt][0] = *(const f16x8*)(bb + nt * 2048 + swzk0);
#pragma unroll
    for (int mt = 0; mt < 4; ++mt) af[mt][1] = *(const f16x8*)(ab + mt * 2048 + swzk1);
#pragma unroll
    for (int nt = 0; nt < 2; ++nt) bf_[nt][1] = *(const f16x8*)(bb + nt * 2048 + swzk1);
    asm volatile("s_waitcnt lgkmcnt(6)" ::: "memory");  // k-step0 frags landed
    __builtin_amdgcn_sched_barrier(0);
    __builtin_amdgcn_s_setprio(1);
#pragma unroll
    for (int mt = 0; mt < 4; ++mt)
#pragma unroll
      for (int nt = 0; nt < 2; ++nt)
        acc[mt][nt] = __builtin_amdgcn_mfma_f32_32x32x16_f16(af[mt][0], bf_[nt][0], acc[mt][nt], 0, 0, 0);
    __builtin_amdgcn_s_setprio(0);
    asm volatile("s_waitcnt lgkmcnt(0)" ::: "memory");
    __builtin_amdgcn_sched_barrier(0);
    __builtin_amdgcn_s_setprio(1);
#pragma unroll
    for (int mt = 0; mt < 4; ++mt)
#pragma unroll
      for (int nt = 0; nt < 2; ++nt)
        acc[mt][nt] = __builtin_amdgcn_mfma_f32_32x32x16_f16(af[mt][1], bf_[nt][1], acc[mt][nt], 0, 0, 0);
    __builtin_amdgcn_s_setprio(0);
    asm volatile("s_waitcnt vmcnt(0)" ::: "memory");  // tile tt+1 fully landed
    __builtin_amdgcn_sched_barrier(0);
    __builtin_amdgcn_s_barrier();
  }

  // epilogue. 32x32 C/D: col=lane&31, row=(reg&3)+8*(reg>>2)+4*(lane>>5) [m74/m101]
#pragma unroll
  for (int mt = 0; mt < 4; ++mt) {
    const int rowb = tm * 256 + wm * 128 + mt * 32 + 4 * khi;
#pragma unroll
    for (int nt = 0; nt < 2; ++nt) {
      const int col = tn * 256 + wn * 64 + nt * 32 + l31;
      if (SPLITK && ks) {  // partial: plain fp32 store to C4f
#pragma unroll
        for (int r = 0; r < 16; ++r) {
          const int row = rowb + (r & 3) + 8 * (r >> 2);
          C4f[(size_t)row * 1024 + col] = acc[mt][nt][r];
        }
      } else if (FINAL) {
#pragma unroll
        for (int r = 0; r < 16; ++r) {
          const int row = rowb + (r & 3) + 8 * (r >> 2);
          const size_t idx = (size_t)row * 1024 + col;
          Cf[idx] = acc[mt][nt][r] + xres[idx] + bias[col];
        }
      } else {
        const int pl = col >> 10;
        ushort* base = (pl < 4) ? (Ch + (size_t)pl * (size_t)M * 1024) : C4h;
#pragma unroll
        for (int r = 0; r < 16; ++r) {
          const int row = rowb + (r & 3) + 8 * (r >> 2);
          base[(size_t)row * 1024 + (col & 1023)] = f2h(acc[mt][nt][r]);
        }
      }
    }
  }
}

// split-K merge: out += partial
__global__ void add_kernel(float* __restrict__ out, const float* __restrict__ p) {
  size_t i = ((size_t)blockIdx.x * blockDim.x + threadIdx.x) * 4;
  if (i >= NELEM) return;
  float4 a = *(const float4*)(out + i);
  float4 b = *(const float4*)(p + i);
  a.x += b.x; a.y += b.y; a.z += b.z; a.w += b.w;
  *(float4*)(out + i) = a;
}

// ---------------- fused elementwise / scan passes (fp16 planes) ----------------

__device__ __forceinline__ void load4h(const ushort* p, float* f) {
  ushort4 u = *(const ushort4*)p;
  f[0] = h2f(u.x); f[1] = h2f(u.y); f[2] = h2f(u.z); f[3] = h2f(u.w);
}

// P1+P2: gating/sigmoid transforms in place (fp16) + per-(b,chunk,d) fp32 sums
__global__ void prep_chunk_kernel(ushort* __restrict__ omega_go, const ushort* __restrict__ gate_lin,
                                  ushort* __restrict__ mag_io,
                                  const float* __restrict__ b_om, const float* __restrict__ b_gate,
                                  const float* __restrict__ b_mag, const float* __restrict__ isc,
                                  float* __restrict__ gsum, float* __restrict__ msum) {
  int tid = blockIdx.x * blockDim.x + threadIdx.x;
  if (tid >= B_ * CCH * (D_ / 4)) return;
  int d4 = tid & 255, c = (tid >> 8) & (CCH - 1), b = tid >> 14;
  int d = d4 * 4;
  size_t base = ((size_t)(b * S_) + c * LCH) * D_ + d;
  size_t cs = ((size_t)(b * CCH) + c) * D_ + d;
  float bo[4], bg[4], bm[4], is[4];
  *(float4*)bo = *(const float4*)(b_om + d);
  *(float4*)bg = *(const float4*)(b_gate + d);
  *(float4*)bm = *(const float4*)(b_mag + d);
  *(float4*)is = *(const float4*)(isc + d);
  float sg[4] = {0.f, 0.f, 0.f, 0.f}, sm[4] = {0.f, 0.f, 0.f, 0.f};
  for (int s = 0; s < LCH; ++s) {
    size_t i = base + (size_t)s * D_;
    float om[4], gl[4], mg[4];
    load4h(omega_go + i, om);
    load4h(gate_lin + i, gl);
    load4h(mag_io + i, mg);
    ushort wo[4], wm_[4];
#pragma unroll
    for (int j = 0; j < 4; ++j) {
      float g = 1.f / (1.f + __expf(-(gl[j] + bg[j])));
      float m5 = 5.f / (1.f + __expf(-(mg[j] + bm[j])));
      float go = g * ((om[j] + bo[j]) * fabsf(is[j]));
      sg[j] += go;
      sm[j] += m5;
      wo[j] = f2h(go);
      wm_[j] = f2h(m5);
    }
    *(ushort4*)(omega_go + i) = *(ushort4*)wo;
    *(ushort4*)(mag_io + i) = *(ushort4*)wm_;
  }
  *(float4*)(gsum + cs) = *(float4*)sg;
  *(float4*)(msum + cs) = *(float4*)sm;
}

// P3/P5: exclusive scan of chunk totals along c — wave-parallel (lane = chunk)
__global__ void scan_offsets_kernel(float* __restrict__ s1, float* __restrict__ s2) {
  int gw = (blockIdx.x * blockDim.x + threadIdx.x) >> 6;
  int lane = threadIdx.x & 63;
  if (gw >= B_ * D_) return;
  int d = gw & (D_ - 1), b = gw >> 10;
  size_t idx = ((size_t)(b * CCH) + lane) * D_ + d;
  float v1 = s1[idx], v2 = s2[idx];
#pragma unroll
  for (int off = 1; off < 64; off <<= 1) {
    float u1 = __shfl_up(v1, off);
    float u2 = __shfl_up(v2, off);
    if (lane >= off) { v1 += u1; v2 += u2; }
  }
  float e1 = __shfl_up(v1, 1), e2 = __shfl_up(v2, 1);
  if (lane == 0) { e1 = 0.f; e2 = 0.f; }
  s1[idx] = e1;
  s2[idx] = e2;
}

// P4 (slim): chunked scan -> ctx parts 0,1 + tr/ti chunk totals. Planes untouched.
__global__ void phase_scan_kernel(const float* __restrict__ x, const ushort* __restrict__ go,
                                  const ushort* __restrict__ mag, const ushort* __restrict__ p0,
                                  const float* __restrict__ goff,
                                  float* __restrict__ trsum, float* __restrict__ tisum,
                                  const float* __restrict__ b_phi, ushort* __restrict__ ctx) {
  int tid = blockIdx.x * blockDim.x + threadIdx.x;
  if (tid >= B_ * CCH * (D_ / 4)) return;
  int d4 = tid & 255, c = (tid >> 8) & (CCH - 1), b = tid >> 14;
  int d = d4 * 4;
  size_t base = ((size_t)(b * S_) + c * LCH) * D_ + d;
  size_t cs = ((size_t)(b * CCH) + c) * D_ + d;
  float pr[4], bp[4];
  *(float4*)pr = *(const float4*)(goff + cs);
  *(float4*)bp = *(const float4*)(b_phi + d);
  float tr[4] = {0.f, 0.f, 0.f, 0.f}, ti[4] = {0.f, 0.f, 0.f, 0.f};
  size_t crow = ((size_t)(b * S_ + c * LCH)) * 4096 + d;
  for (int s = 0; s < LCH; ++s) {
    size_t i = base + (size_t)s * D_;
    float g[4], ph0[4], m[4], xv[4];
    load4h(go + i, g);
    load4h(p0 + i, ph0);
    load4h(mag + i, m);
    *(float4*)xv = *(const float4*)(x + i);
    ushort c4[4], s4[4];
#pragma unroll
    for (int j = 0; j < 4; ++j) {
      pr[j] += g[j];
      float ph = ph0[j] + bp[j] + pr[j];
      float sp, cp;
      __sincosf(ph, &sp, &cp);
      float wr = m[j] * xv[j];
      tr[j] += wr * cp;
      ti[j] += wr * sp;
      c4[j] = f2h(xv[j] * cp);
      s4[j] = f2h(xv[j] * sp);
    }
    *(ushort4*)(ctx + crow) = *(ushort4*)c4;
    *(ushort4*)(ctx + crow + 1024) = *(ushort4*)s4;
    crow += 4096;
  }
  *(float4*)(trsum + cs) = *(float4*)tr;
  *(float4*)(tisum + cs) = *(float4*)ti;
}

// P6 (recompute): re-run the chunk chains, normalize + retrieve -> ctx parts 2,3
__global__ void retrieve_kernel(const float* __restrict__ x, const ushort* __restrict__ go,
                                const ushort* __restrict__ mag, const ushort* __restrict__ p0,
                                const ushort* __restrict__ q,
                                const float* __restrict__ goff, const float* __restrict__ moff,
                                const float* __restrict__ troff, const float* __restrict__ tioff,
                                const float* __restrict__ b_phi, const float* __restrict__ b_q,
                                ushort* __restrict__ ctx) {
  int tid = blockIdx.x * blockDim.x + threadIdx.x;
  if (tid >= B_ * CCH * (D_ / 4)) return;
  int d4 = tid & 255, c = (tid >> 8) & (CCH - 1), b = tid >> 14;
  int d = d4 * 4;
  size_t base = ((size_t)(b * S_) + c * LCH) * D_ + d;
  size_t cs = ((size_t)(b * CCH) + c) * D_ + d;
  float pr[4], mr[4], tr[4], ti[4], bp[4], bq[4];
  *(float4*)pr = *(const float4*)(goff + cs);
  *(float4*)mr = *(const float4*)(moff + cs);
  *(float4*)tr = *(const float4*)(troff + cs);
  *(float4*)ti = *(const float4*)(tioff + cs);
  *(float4*)bp = *(const float4*)(b_phi + d);
  *(float4*)bq = *(const float4*)(b_q + d);
  size_t crow = ((size_t)(b * S_ + c * LCH)) * 4096 + d;
  for (int s = 0; s < LCH; ++s) {
    size_t i = base + (size_t)s * D_;
    float g[4], ph0[4], m[4], xv[4], qv[4];
    load4h(go + i, g);
    load4h(p0 + i, ph0);
    load4h(mag + i, m);
    load4h(q + i, qv);
    *(float4*)xv = *(const float4*)(x + i);
    ushort r2[4], r3[4];
#pragma unroll
    for (int j = 0; j < 4; ++j) {
      pr[j] += g[j];
      float ph = ph0[j] + bp[j] + pr[j];
      float sp, cp;
      __sincosf(ph, &sp, &cp);
      mr[j] += m[j];
      float wr = m[j] * xv[j];
      tr[j] += wr * cp;
      ti[j] += wr * sp;
      float rs = rsqrtf(mr[j] + 1e-8f);
      float mreal = tr[j] * rs, mimag = ti[j] * rs;
      float phq = ph + qv[j] + bq[j];
      float sq, cq;
      __sincosf(phq, &sq, &cq);
      r2[j] = f2h(mreal * cq + mimag * sq);
      r3[j] = f2h(mimag * cq - mreal * sq);
    }
    *(ushort4*)(ctx + crow + 2048) = *(ushort4*)r2;
    *(ushort4*)(ctx + crow + 3072) = *(ushort4*)r3;
    crow += 4096;
  }
}

// ---------------- launcher ----------------
extern "C" void kernel_launch(void* const* d_in, const int* in_sizes, int n_in,
                              void* d_out, int out_size, void* d_ws, size_t ws_size,
                              hipStream_t stream) {
  const float* x      = (const float*)d_in[0];
  const float* W_om   = (const float*)d_in[1];
  const float* b_om   = (const float*)d_in[2];
  const float* W_mag  = (const float*)d_in[3];
  const float* b_mag  = (const float*)d_in[4];
  const float* W_phi  = (const float*)d_in[5];
  const float* b_phi  = (const float*)d_in[6];
  const float* W_gate = (const float*)d_in[7];
  const float* b_gate = (const float*)d_in[8];
  const float* W_q    = (const float*)d_in[9];
  const float* b_q    = (const float*)d_in[10];
  const float* isc    = (const float*)d_in[11];
  const float* W_out  = (const float*)d_in[12];
  const float* b_out  = (const float*)d_in[13];
  float* out = (float*)d_out;

  // ---- ws layout, 213,909,504 bytes (same envelope as before) ----
  // [0)           4 fp16 planes: omega|gate|mag|phi0 (64MB); final splitK fp32
  //               partial (32MB) reuses this region after retrieve consumed it
  // [134,217,728) ctx fp16 [8192][4096]; overlapped (dead before ctx written):
  //               x_h fp16 (16MB) | W5T [5120][1024] fp16 (10MB)
  // [201,326,592) WoutT [1024][4096] fp16
  // [209,715,200) gsum|msum|trsum|tisum (4 x 1MB)
  // q_lin (fp16) lives in d_out (overwritten by the final GEMM afterwards).
  const size_t WS_NEEDED = 213909504ull;
  if (ws_size < WS_NEEDED) {
    (void)hipMemsetAsync(d_out, 0, (size_t)out_size * sizeof(float), stream);
    return;
  }
  char* w = (char*)d_ws;
  ushort* planes_h = (ushort*)w;                      // 4 x NELEM fp16
  ushort* omega_buf = planes_h;
  ushort* gate_buf  = planes_h + NELEM;
  ushort* mag_buf   = planes_h + 2 * NELEM;
  ushort* phi0_buf  = planes_h + 3 * NELEM;
  float* partial    = (float*)w;                      // fp32, reused after retrieve
  ushort* q_buf     = (ushort*)out;                   // fp16 q plane in d_out
  char* ctxb = w + 4 * NELEM * 4;
  ushort* ctx   = (ushort*)ctxb;
  ushort* x_h   = (ushort*)ctxb;                      // [8192][1024] fp16
  ushort* W5T   = (ushort*)(ctxb + 16777216);         // [5120][1024]: om|gate|mag|phi0|q
  ushort* WoutT = (ushort*)(w + 201326592);           // [1024][4096]
  float* gsum  = (float*)(w + 209715200);
  float* msum  = (float*)(w + 210763776);
  float* trsum = (float*)(w + 211812352);
  float* tisum = (float*)(w + 212860928);

  const size_t DD = (size_t)D_ * D_;

  // conversions
  xhalf_kernel<<<(int)(NELEM / 2048), 256, 0, stream>>>(x, x_h);
  dim3 tg(16, 16);
  transpose_convert<<<tg, 256, 0, stream>>>(W_om,   W5T + 0 * DD, 1024, D_, D_);
  transpose_convert<<<tg, 256, 0, stream>>>(W_gate, W5T + 1 * DD, 1024, D_, D_);
  transpose_convert<<<tg, 256, 0, stream>>>(W_mag,  W5T + 2 * DD, 1024, D_, D_);
  transpose_convert<<<tg, 256, 0, stream>>>(W_phi,  W5T + 3 * DD, 1024, D_, D_);
  transpose_convert<<<tg, 256, 0, stream>>>(W_q,    W5T + 4 * DD, 1024, D_, D_);
  transpose_convert<<<dim3(64, 16), 256, 0, stream>>>(W_out, WoutT, 4096, 4 * D_, D_);

  // GEMM1: 5 projections, N=5120, K=1024, fp16 in/out. q plane -> d_out scratch.
  gemm256<0, 0><<<640, 512, 0, stream>>>(x_h, 1024, W5T, planes_h, q_buf,
                                         nullptr, nullptr, nullptr, nullptr, MROWS, 1024);

  // scans + fused elementwise
  prep_chunk_kernel<<<B_ * CCH * (D_ / 4) / 256, 256, 0, stream>>>(
      omega_buf, gate_buf, mag_buf, b_om, b_gate, b_mag, isc, gsum, msum);
  scan_offsets_kernel<<<B_ * D_ * 64 / 256, 256, 0, stream>>>(gsum, msum);
  phase_scan_kernel<<<B_ * CCH * (D_ / 4) / 256, 256, 0, stream>>>(
      x, omega_buf, mag_buf, phi0_buf, gsum, trsum, tisum, b_phi, ctx);
  scan_offsets_kernel<<<B_ * D_ * 64 / 256, 256, 0, stream>>>(trsum, tisum);
  retrieve_kernel<<<B_ * CCH * (D_ / 4) / 256, 256, 0, stream>>>(
      x, omega_buf, mag_buf, phi0_buf, q_buf, gsum, msum, trsum, tisum, b_phi, b_q, ctx);

  // final: out = x + ctx @ W_out + b_out, split-K x2 (256 blocks, full GPU).
  gemm256<1, 1><<<256, 512, 0, stream>>>(ctx, 4096, WoutT, nullptr, nullptr, out, partial,
                                         x, b_out, MROWS, 4 * D_);
  add_kernel<<<(int)(NELEM / 1024), 256, 0, stream>>>(out, partial);
}

// Round 11
// 318.400 us; speedup vs baseline: 1.6582x; 1.0473x over previous
//
#include <hip/hip_runtime.h>
#include <hip/hip_fp16.h>

// Problem constants (B,S,D fixed by the reference)
#define B_ 4
#define S_ 2048
#define D_ 1024
#define CCH 64                    // chunks along S
#define LCH 32                    // chunk length; CCH*LCH == S_
#define NELEM ((size_t)B_*S_*D_)  // 8388608
#define MROWS (B_*S_)             // 8192

typedef __attribute__((ext_vector_type(4))) float f32x4;
typedef __attribute__((ext_vector_type(8))) _Float16 f16x8;  // 8 x fp16 fragment

__device__ __forceinline__ ushort f2h(float v) {
  __half h = __float2half(v);
  return __builtin_bit_cast(ushort, h);
}
__device__ __forceinline__ float h2f(ushort u) {
  return __half2float(__builtin_bit_cast(__half, u));
}

__device__ __forceinline__ void gload16(const ushort* src, char* ldsdst) {
  __builtin_amdgcn_global_load_lds(
      (const __attribute__((address_space(1))) void*)src,
      (__attribute__((address_space(3))) void*)ldsdst, 16, 0, 0);
}

// ---------------- conversions ----------------

// x -> fp16 [M][1024]
__global__ void xhalf_kernel(const float* __restrict__ x, ushort* __restrict__ xh) {
  size_t i = ((size_t)blockIdx.x * blockDim.x + threadIdx.x) * 8;
  if (i >= NELEM) return;
  float4 a = *(const float4*)(x + i);
  float4 b = *(const float4*)(x + i + 4);
  ushort h[8] = {f2h(a.x), f2h(a.y), f2h(a.z), f2h(a.w),
                 f2h(b.x), f2h(b.y), f2h(b.z), f2h(b.w)};
  *(ushort4*)(xh + i) = *(ushort4*)h;
  *(ushort4*)(xh + i + 4) = *(ushort4*)(h + 4);
}

// Five D x D weights -> W5T[z][n][k] fp16 (transposed), one launch (z selects W).
__global__ void transpose5(const float* __restrict__ W0, const float* __restrict__ W1,
                           const float* __restrict__ W2, const float* __restrict__ W3,
                           const float* __restrict__ W4, ushort* __restrict__ Th) {
  __shared__ float tile[64][65];  // +1 pad: conflict-free column reads
  const int z = blockIdx.z;
  const float* W = (z == 0) ? W0 : (z == 1) ? W1 : (z == 2) ? W2 : (z == 3) ? W3 : W4;
  ushort* T = Th + (size_t)z * D_ * D_;
  const int k0 = blockIdx.x * 64, n0 = blockIdx.y * 64;
  const int tx = threadIdx.x & 63, ty = threadIdx.x >> 6;  // 64 x 4
#pragma unroll
  for (int i = 0; i < 16; ++i)
    tile[ty * 16 + i][tx] = W[(size_t)(k0 + ty * 16 + i) * D_ + n0 + tx];
  __syncthreads();
#pragma unroll
  for (int i = 0; i < 16; ++i) {
    const int nn = ty * 16 + i;
    T[(size_t)(n0 + nn) * D_ + k0 + tx] = f2h(tile[tx][nn]);
  }
}

// W [Kd][Nd] f32 -> Th[n*sh+k] fp16 (transposed). For W_out.
__global__ void transpose_convert(const float* __restrict__ W, ushort* __restrict__ Th, int sh,
                                  int Kd, int Nd) {
  __shared__ float tile[64][65];
  const int k0 = blockIdx.x * 64, n0 = blockIdx.y * 64;
  const int tx = threadIdx.x & 63, ty = threadIdx.x >> 6;
#pragma unroll
  for (int i = 0; i < 16; ++i)
    tile[ty * 16 + i][tx] = W[(size_t)(k0 + ty * 16 + i) * Nd + n0 + tx];
  __syncthreads();
#pragma unroll
  for (int i = 0; i < 16; ++i) {
    const int nn = ty * 16 + i;
    Th[(size_t)(n0 + nn) * sh + k0 + tx] = f2h(tile[tx][nn]);
  }
}

// ------- 256x256 fp16 MFMA GEMM, 16x16x32 fragments, BK=32, 1 barrier/K-tile -------
// 8 waves (2m x 4n), wave tile 128x64. LDS: 2 buffers x (A 256x32 + B 256x32) = 64 KB.
// Row-pair 128B lines, phys granule = ((row&1)*4 + kgran) ^ ((line)&7).
// This exact read pattern measured SQ_LDS_BANK_CONFLICT = 0 (rounds 7 and 9).
// Depth-1 prefetch: STAGE(t+1) at loop top; vmcnt(0)+barrier once per K-tile.
// !FINAL: writes fp16 planes Ch (col>>10 selects plane; plane 4 -> C4h).
// FINAL+SPLITK: grid 256, K halves; ks=0 -> Cf=out (+x+bias), ks=1 -> C4f partial.
template <int FINAL, int SPLITK>
__global__ __launch_bounds__(512, 2) void gemm256(
    const ushort* __restrict__ A, int lda, const ushort* __restrict__ Bw,
    ushort* __restrict__ Ch, ushort* __restrict__ C4h,
    float* __restrict__ Cf, float* __restrict__ C4f,
    const float* __restrict__ xres, const float* __restrict__ bias,
    int M, int K) {
  __shared__ __align__(16) char ldsc[2 * 32768];
  int bid = blockIdx.x, ks = 0;
  if (SPLITK && bid >= 128) { ks = 1; bid -= 128; }
  const int tm = bid & 31, tn = bid >> 5;
  const int Kb = SPLITK ? (K >> 1) : K;
  const int ldb = K;
  const int nB = tn << 8;
  if (SPLITK) { A += (size_t)ks * Kb; Bw += (size_t)ks * Kb; }
  const int NT = Kb >> 5;
  const int t = threadIdx.x, lane = t & 63, wid = t >> 6;
  const int wm = wid >> 2, wn = wid & 3;

  f32x4 acc[8][4];
#pragma unroll
  for (int i = 0; i < 8; ++i)
#pragma unroll
    for (int j = 0; j < 4; ++j) acc[i][j] = (f32x4){0.f, 0.f, 0.f, 0.f};

  // ---- staging: linear LDS dest t*16; inverse-swizzled global source ----
  const int line1 = t >> 3;
  const int g8s = (t & 7) ^ (line1 & 7);
  const int rowS = line1 * 2 + (g8s >> 2);
  const int kgS = (g8s & 3) << 3;
  const ushort* srcA = A + (size_t)(tm * 256 + rowS) * lda + kgS;
  const ushort* srcB = Bw + (size_t)(nB + rowS) * ldb + kgS;
  char* dstA = ldsc + (size_t)t * 16;
  char* dstB = ldsc + 16384 + (size_t)t * 16;

  auto STAGE = [&](int tile) {
    if (tile >= NT) return;
    char* ba = dstA + (tile & 1) * 32768;
    char* bb = dstB + (tile & 1) * 32768;
    const ushort* sa = srcA + tile * 32;
    const ushort* sb = srcB + tile * 32;
    gload16(sa, ba);
    gload16(sa + (size_t)128 * lda, ba + 8192);
    gload16(sb, bb);
    gload16(sb + (size_t)128 * ldb, bb + 8192);
  };

  // ---- fragment reads (16x16x32): row = f*16 + lane15, kgran = lane>>4 ----
  // byte = (row>>1)*128 + ((((row&1)*4 + kgran) ^ ((row>>1)&7))<<4); f*16 rows = f*1024B.
  const int lane15 = lane & 15;
  const int hl = lane15 >> 1;  // half-line (line&7 within any 8-line-aligned block)
  const int swz = ((((lane15 & 1) << 2) + (lane >> 4)) ^ hl) << 4;
  const char* aB = ldsc + wm * 8192 + hl * 128 + swz;
  const char* bB = ldsc + 16384 + wn * 4096 + hl * 128 + swz;

  STAGE(0);
  asm volatile("s_waitcnt vmcnt(0)" ::: "memory");
  __builtin_amdgcn_sched_barrier(0);
  __builtin_amdgcn_s_barrier();

#pragma unroll 1
  for (int tt = 0; tt < NT; ++tt) {
    STAGE(tt + 1);
    const char* ab = aB + (tt & 1) * 32768;
    const char* bb = bB + (tt & 1) * 32768;
    f16x8 af[4], bf_[4], af2[4];
#pragma unroll
    for (int f = 0; f < 4; ++f) af[f] = *(const f16x8*)(ab + f * 1024);
#pragma unroll
    for (int c = 0; c < 4; ++c) bf_[c] = *(const f16x8*)(bb + c * 1024);
#pragma unroll
    for (int f = 0; f < 4; ++f) af2[f] = *(const f16x8*)(ab + 4096 + f * 1024);
    asm volatile("s_waitcnt lgkmcnt(4)" ::: "memory");  // af+bf landed (af2 in flight)
    __builtin_amdgcn_sched_barrier(0);
    __builtin_amdgcn_s_setprio(1);
#pragma unroll
    for (int f = 0; f < 4; ++f)
#pragma unroll
      for (int c = 0; c < 4; ++c)
        acc[f][c] = __builtin_amdgcn_mfma_f32_16x16x32_f16(af[f], bf_[c], acc[f][c], 0, 0, 0);
    __builtin_amdgcn_s_setprio(0);
    asm volatile("s_waitcnt lgkmcnt(0)" ::: "memory");
    __builtin_amdgcn_sched_barrier(0);
    __builtin_amdgcn_s_setprio(1);
#pragma unroll
    for (int f = 0; f < 4; ++f)
#pragma unroll
      for (int c = 0; c < 4; ++c)
        acc[4 + f][c] = __builtin_amdgcn_mfma_f32_16x16x32_f16(af2[f], bf_[c], acc[4 + f][c], 0, 0, 0);
    __builtin_amdgcn_s_setprio(0);
    asm volatile("s_waitcnt vmcnt(0)" ::: "memory");  // tile tt+1 fully landed
    __builtin_amdgcn_sched_barrier(0);
    __builtin_amdgcn_s_barrier();
  }

  // epilogue. C/D layout: col=lane&15, row=(lane>>4)*4+reg  [m89-verified]
#pragma unroll
  for (int i = 0; i < 8; ++i) {
    const int row0 = tm * 256 + wm * 128 + i * 16 + ((lane >> 4) << 2);
#pragma unroll
    for (int jj = 0; jj < 4; ++jj) {
      const int col = tn * 256 + wn * 64 + jj * 16 + lane15;
      if (SPLITK && ks) {  // partial: plain fp32 store to C4f
#pragma unroll
        for (int r = 0; r < 4; ++r)
          C4f[(size_t)(row0 + r) * 1024 + col] = acc[i][jj][r];
      } else if (FINAL) {
#pragma unroll
        for (int r = 0; r < 4; ++r) {
          const size_t idx = (size_t)(row0 + r) * 1024 + col;
          Cf[idx] = acc[i][jj][r] + xres[idx] + bias[col];
        }
      } else {
        const int pl = col >> 10;
        ushort* base = (pl < 4) ? (Ch + (size_t)pl * (size_t)M * 1024) : C4h;
#pragma unroll
        for (int r = 0; r < 4; ++r)
          base[(size_t)(row0 + r) * 1024 + (col & 1023)] = f2h(acc[i][jj][r]);
      }
    }
  }
}

// split-K merge: out += partial
__global__ void add_kernel(float* __restrict__ out, const float* __restrict__ p) {
  size_t i = ((size_t)blockIdx.x * blockDim.x + threadIdx.x) * 4;
  if (i >= NELEM) return;
  float4 a = *(const float4*)(out + i);
  float4 b = *(const float4*)(p + i);
  a.x += b.x; a.y += b.y; a.z += b.z; a.w += b.w;
  *(float4*)(out + i) = a;
}

// ---------------- fused elementwise / scan passes (fp16 planes + fp16 x) ----------------

__device__ __forceinline__ void load4h(const ushort* p, float* f) {
  ushort4 u = *(const ushort4*)p;
  f[0] = h2f(u.x); f[1] = h2f(u.y); f[2] = h2f(u.z); f[3] = h2f(u.w);
}

// P1+P2: gating/sigmoid transforms in place (fp16) + per-(b,chunk,d) fp32 sums
__global__ void prep_chunk_kernel(ushort* __restrict__ omega_go, const ushort* __restrict__ gate_lin,
                                  ushort* __restrict__ mag_io,
                                  const float* __restrict__ b_om, const float* __restrict__ b_gate,
                                  const float* __restrict__ b_mag, const float* __restrict__ isc,
                                  float* __restrict__ gsum, float* __restrict__ msum) {
  int tid = blockIdx.x * blockDim.x + threadIdx.x;
  if (tid >= B_ * CCH * (D_ / 4)) return;
  int d4 = tid & 255, c = (tid >> 8) & (CCH - 1), b = tid >> 14;
  int d = d4 * 4;
  size_t base = ((size_t)(b * S_) + c * LCH) * D_ + d;
  size_t cs = ((size_t)(b * CCH) + c) * D_ + d;
  float bo[4], bg[4], bm[4], is[4];
  *(float4*)bo = *(const float4*)(b_om + d);
  *(float4*)bg = *(const float4*)(b_gate + d);
  *(float4*)bm = *(const float4*)(b_mag + d);
  *(float4*)is = *(const float4*)(isc + d);
  float sg[4] = {0.f, 0.f, 0.f, 0.f}, sm[4] = {0.f, 0.f, 0.f, 0.f};
  for (int s = 0; s < LCH; ++s) {
    size_t i = base + (size_t)s * D_;
    float om[4], gl[4], mg[4];
    load4h(omega_go + i, om);
    load4h(gate_lin + i, gl);
    load4h(mag_io + i, mg);
    ushort wo[4], wm_[4];
#pragma unroll
    for (int j = 0; j < 4; ++j) {
      float g = 1.f / (1.f + __expf(-(gl[j] + bg[j])));
      float m5 = 5.f / (1.f + __expf(-(mg[j] + bm[j])));
      float go = g * ((om[j] + bo[j]) * fabsf(is[j]));
      sg[j] += go;
      sm[j] += m5;
      wo[j] = f2h(go);
      wm_[j] = f2h(m5);
    }
    *(ushort4*)(omega_go + i) = *(ushort4*)wo;
    *(ushort4*)(mag_io + i) = *(ushort4*)wm_;
  }
  *(float4*)(gsum + cs) = *(float4*)sg;
  *(float4*)(msum + cs) = *(float4*)sm;
}

// P3/P5: exclusive scan of chunk totals along c — wave-parallel (lane = chunk)
__global__ void scan_offsets_kernel(float* __restrict__ s1, float* __restrict__ s2) {
  int gw = (blockIdx.x * blockDim.x + threadIdx.x) >> 6;
  int lane = threadIdx.x & 63;
  if (gw >= B_ * D_) return;
  int d = gw & (D_ - 1), b = gw >> 10;
  size_t idx = ((size_t)(b * CCH) + lane) * D_ + d;
  float v1 = s1[idx], v2 = s2[idx];
#pragma unroll
  for (int off = 1; off < 64; off <<= 1) {
    float u1 = __shfl_up(v1, off);
    float u2 = __shfl_up(v2, off);
    if (lane >= off) { v1 += u1; v2 += u2; }
  }
  float e1 = __shfl_up(v1, 1), e2 = __shfl_up(v2, 1);
  if (lane == 0) { e1 = 0.f; e2 = 0.f; }
  s1[idx] = e1;
  s2[idx] = e2;
}

// P4 (slim): chunked scan -> ctx parts 0,1 + tr/ti chunk totals. Planes untouched.
__global__ void phase_scan_kernel(const ushort* __restrict__ xh, const ushort* __restrict__ go,
                                  const ushort* __restrict__ mag, const ushort* __restrict__ p0,
                                  const float* __restrict__ goff,
                                  float* __restrict__ trsum, float* __restrict__ tisum,
                                  const float* __restrict__ b_phi, ushort* __restrict__ ctx) {
  int tid = blockIdx.x * blockDim.x + threadIdx.x;
  if (tid >= B_ * CCH * (D_ / 4)) return;
  int d4 = tid & 255, c = (tid >> 8) & (CCH - 1), b = tid >> 14;
  int d = d4 * 4;
  size_t base = ((size_t)(b * S_) + c * LCH) * D_ + d;
  size_t cs = ((size_t)(b * CCH) + c) * D_ + d;
  float pr[4], bp[4];
  *(float4*)pr = *(const float4*)(goff + cs);
  *(float4*)bp = *(const float4*)(b_phi + d);
  float tr[4] = {0.f, 0.f, 0.f, 0.f}, ti[4] = {0.f, 0.f, 0.f, 0.f};
  size_t crow = ((size_t)(b * S_ + c * LCH)) * 4096 + d;
  for (int s = 0; s < LCH; ++s) {
    size_t i = base + (size_t)s * D_;
    float g[4], ph0[4], m[4], xv[4];
    load4h(go + i, g);
    load4h(p0 + i, ph0);
    load4h(mag + i, m);
    load4h(xh + i, xv);
    ushort c4[4], s4[4];
#pragma unroll
    for (int j = 0; j < 4; ++j) {
      pr[j] += g[j];
      float ph = ph0[j] + bp[j] + pr[j];
      float sp, cp;
      __sincosf(ph, &sp, &cp);
      float wr = m[j] * xv[j];
      tr[j] += wr * cp;
      ti[j] += wr * sp;
      c4[j] = f2h(xv[j] * cp);
      s4[j] = f2h(xv[j] * sp);
    }
    *(ushort4*)(ctx + crow) = *(ushort4*)c4;
    *(ushort4*)(ctx + crow + 1024) = *(ushort4*)s4;
    crow += 4096;
  }
  *(float4*)(trsum + cs) = *(float4*)tr;
  *(float4*)(tisum + cs) = *(float4*)ti;
}

// P6 (recompute): re-run the chunk chains, normalize + retrieve -> ctx parts 2,3
__global__ void retrieve_kernel(const ushort* __restrict__ xh, const ushort* __restrict__ go,
                                const ushort* __restrict__ mag, const ushort* __restrict__ p0,
                                const ushort* __restrict__ q,
                                const float* __restrict__ goff, const float* __restrict__ moff,
                                const float* __restrict__ troff, const float* __restrict__ tioff,
                                const float* __restrict__ b_phi, const float* __restrict__ b_q,
                                ushort* __restrict__ ctx) {
  int tid = blockIdx.x * blockDim.x + threadIdx.x;
  if (tid >= B_ * CCH * (D_ / 4)) return;
  int d4 = tid & 255, c = (tid >> 8) & (CCH - 1), b = tid >> 14;
  int d = d4 * 4;
  size_t base = ((size_t)(b * S_) + c * LCH) * D_ + d;
  size_t cs = ((size_t)(b * CCH) + c) * D_ + d;
  float pr[4], mr[4], tr[4], ti[4], bp[4], bq[4];
  *(float4*)pr = *(const float4*)(goff + cs);
  *(float4*)mr = *(const float4*)(moff + cs);
  *(float4*)tr = *(const float4*)(troff + cs);
  *(float4*)ti = *(const float4*)(tioff + cs);
  *(float4*)bp = *(const float4*)(b_phi + d);
  *(float4*)bq = *(const float4*)(b_q + d);
  size_t crow = ((size_t)(b * S_ + c * LCH)) * 4096 + d;
  for (int s = 0; s < LCH; ++s) {
    size_t i = base + (size_t)s * D_;
    float g[4], ph0[4], m[4], xv[4], qv[4];
    load4h(go + i, g);
    load4h(p0 + i, ph0);
    load4h(mag + i, m);
    load4h(q + i, qv);
    load4h(xh + i, xv);
    ushort r2[4], r3[4];
#pragma unroll
    for (int j = 0; j < 4; ++j) {
      pr[j] += g[j];
      float ph = ph0[j] + bp[j] + pr[j];
      float sp, cp;
      __sincosf(ph, &sp, &cp);
      mr[j] += m[j];
      float wr = m[j] * xv[j];
      tr[j] += wr * cp;
      ti[j] += wr * sp;
      float rs = rsqrtf(mr[j] + 1e-8f);
      float mreal = tr[j] * rs, mimag = ti[j] * rs;
      float phq = ph + qv[j] + bq[j];
      float sq, cq;
      __sincosf(phq, &sq, &cq);
      r2[j] = f2h(mreal * cq + mimag * sq);
      r3[j] = f2h(mimag * cq - mreal * sq);
    }
    *(ushort4*)(ctx + crow + 2048) = *(ushort4*)r2;
    *(ushort4*)(ctx + crow + 3072) = *(ushort4*)r3;
    crow += 4096;
  }
}

// ---------------- launcher ----------------
extern "C" void kernel_launch(void* const* d_in, const int* in_sizes, int n_in,
                              void* d_out, int out_size, void* d_ws, size_t ws_size,
                              hipStream_t stream) {
  const float* x      = (const float*)d_in[0];
  const float* W_om   = (const float*)d_in[1];
  const float* b_om   = (const float*)d_in[2];
  const float* W_mag  = (const float*)d_in[3];
  const float* b_mag  = (const float*)d_in[4];
  const float* W_phi  = (const float*)d_in[5];
  const float* b_phi  = (const float*)d_in[6];
  const float* W_gate = (const float*)d_in[7];
  const float* b_gate = (const float*)d_in[8];
  const float* W_q    = (const float*)d_in[9];
  const float* b_q    = (const float*)d_in[10];
  const float* isc    = (const float*)d_in[11];
  const float* W_out  = (const float*)d_in[12];
  const float* b_out  = (const float*)d_in[13];
  float* out = (float*)d_out;

  // ---- ws layout, 213,909,504 bytes ----
  // [0, 67108864)          4 fp16 planes: omega|gate|mag|phi0
  //   [0, 33554432)        fp32 splitK partial (aliases omega/gate, dead post-retrieve)
  // [67108864, 83886080)   x_h fp16 [8192][1024] (lives through retrieve)
  // [134217728, 201326592) ctx fp16 [8192][4096]; W5T (10.5MB, dead after GEMM1)
  //                        overlapped at +16777216
  // [201326592)            WoutT [1024][4096] fp16
  // [209715200)            gsum|msum|trsum|tisum (4 x 1MB)
  // q_lin (fp16) lives in d_out (overwritten by the final GEMM afterwards).
  const size_t WS_NEEDED = 213909504ull;
  if (ws_size < WS_NEEDED) {
    (void)hipMemsetAsync(d_out, 0, (size_t)out_size * sizeof(float), stream);
    return;
  }
  char* w = (char*)d_ws;
  ushort* planes_h = (ushort*)w;                      // 4 x NELEM fp16
  ushort* omega_buf = planes_h;
  ushort* gate_buf  = planes_h + NELEM;
  ushort* mag_buf   = planes_h + 2 * NELEM;
  ushort* phi0_buf  = planes_h + 3 * NELEM;
  float* partial    = (float*)w;                      // fp32, reused after retrieve
  ushort* x_h   = (ushort*)(w + 67108864);            // [8192][1024] fp16
  ushort* q_buf = (ushort*)out;                       // fp16 q plane in d_out
  char* ctxb = w + 4 * NELEM * 4;
  ushort* ctx   = (ushort*)ctxb;
  ushort* W5T   = (ushort*)(ctxb + 16777216);         // [5120][1024]: om|gate|mag|phi0|q
  ushort* WoutT = (ushort*)(w + 201326592);           // [1024][4096]
  float* gsum  = (float*)(w + 209715200);
  float* msum  = (float*)(w + 210763776);
  float* trsum = (float*)(w + 211812352);
  float* tisum = (float*)(w + 212860928);

  const size_t DD = (size_t)D_ * D_;

  // conversions (batched)
  xhalf_kernel<<<(int)(NELEM / 2048), 256, 0, stream>>>(x, x_h);
  transpose5<<<dim3(16, 16, 5), 256, 0, stream>>>(W_om, W_gate, W_mag, W_phi, W_q, W5T);
  transpose_convert<<<dim3(64, 16), 256, 0, stream>>>(W_out, WoutT, 4096, 4 * D_, D_);

  // GEMM1: 5 projections, N=5120, K=1024, fp16 in/out. q plane -> d_out scratch.
  gemm256<0, 0><<<640, 512, 0, stream>>>(x_h, 1024, W5T, planes_h, q_buf,
                                         nullptr, nullptr, nullptr, nullptr, MROWS, 1024);

  // scans + fused elementwise
  prep_chunk_kernel<<<B_ * CCH * (D_ / 4) / 256, 256, 0, stream>>>(
      omega_buf, gate_buf, mag_buf, b_om, b_gate, b_mag, isc, gsum, msum);
  scan_offsets_kernel<<<B_ * D_ * 64 / 256, 256, 0, stream>>>(gsum, msum);
  phase_scan_kernel<<<B_ * CCH * (D_ / 4) / 256, 256, 0, stream>>>(
      x_h, omega_buf, mag_buf, phi0_buf, gsum, trsum, tisum, b_phi, ctx);
  scan_offsets_kernel<<<B_ * D_ * 64 / 256, 256, 0, stream>>>(trsum, tisum);
  retrieve_kernel<<<B_ * CCH * (D_ / 4) / 256, 256, 0, stream>>>(
      x_h, omega_buf, mag_buf, phi0_buf, q_buf, gsum, msum, trsum, tisum, b_phi, b_q, ctx);

  // final: out = x + ctx @ W_out + b_out, split-K x2 (256 blocks, full GPU).
  gemm256<1, 1><<<256, 512, 0, stream>>>(ctx, 4096, WoutT, nullptr, nullptr, out, partial,
                                         x, b_out, MROWS, 4 * D_);
  add_kernel<<<(int)(NELEM / 1024), 256, 0, stream>>>(out, partial);
}

// Round 12
// 317.273 us; speedup vs baseline: 1.6641x; 1.0036x over previous
//
#include <hip/hip_runtime.h>
#include <hip/hip_fp16.h>

// Problem constants (B,S,D fixed by the reference)
#define B_ 4
#define S_ 2048
#define D_ 1024
#define CCH 64                    // chunks along S
#define LCH 32                    // chunk length; CCH*LCH == S_
#define NELEM ((size_t)B_*S_*D_)  // 8388608
#define MROWS (B_*S_)             // 8192

typedef __attribute__((ext_vector_type(4))) float f32x4;
typedef __attribute__((ext_vector_type(8))) _Float16 f16x8;  // 8 x fp16 fragment

__device__ __forceinline__ ushort f2h(float v) {
  __half h = __float2half(v);
  return __builtin_bit_cast(ushort, h);
}
__device__ __forceinline__ float h2f(ushort u) {
  return __half2float(__builtin_bit_cast(__half, u));
}

__device__ __forceinline__ void gload16(const ushort* src, char* ldsdst) {
  __builtin_amdgcn_global_load_lds(
      (const __attribute__((address_space(1))) void*)src,
      (__attribute__((address_space(3))) void*)ldsdst, 16, 0, 0);
}

// ---------------- conversions ----------------

// x -> fp16 [M][1024]
__global__ void xhalf_kernel(const float* __restrict__ x, ushort* __restrict__ xh) {
  size_t i = ((size_t)blockIdx.x * blockDim.x + threadIdx.x) * 8;
  if (i >= NELEM) return;
  float4 a = *(const float4*)(x + i);
  float4 b = *(const float4*)(x + i + 4);
  ushort h[8] = {f2h(a.x), f2h(a.y), f2h(a.z), f2h(a.w),
                 f2h(b.x), f2h(b.y), f2h(b.z), f2h(b.w)};
  *(ushort4*)(xh + i) = *(ushort4*)h;
  *(ushort4*)(xh + i + 4) = *(ushort4*)(h + 4);
}

// Five D x D weights -> W5T[z][n][k] fp16 (transposed), one launch (z selects W).
__global__ void transpose5(const float* __restrict__ W0, const float* __restrict__ W1,
                           const float* __restrict__ W2, const float* __restrict__ W3,
                           const float* __restrict__ W4, ushort* __restrict__ Th) {
  __shared__ float tile[64][65];  // +1 pad: conflict-free column reads
  const int z = blockIdx.z;
  const float* W = (z == 0) ? W0 : (z == 1) ? W1 : (z == 2) ? W2 : (z == 3) ? W3 : W4;
  ushort* T = Th + (size_t)z * D_ * D_;
  const int k0 = blockIdx.x * 64, n0 = blockIdx.y * 64;
  const int tx = threadIdx.x & 63, ty = threadIdx.x >> 6;  // 64 x 4
#pragma unroll
  for (int i = 0; i < 16; ++i)
    tile[ty * 16 + i][tx] = W[(size_t)(k0 + ty * 16 + i) * D_ + n0 + tx];
  __syncthreads();
#pragma unroll
  for (int i = 0; i < 16; ++i) {
    const int nn = ty * 16 + i;
    T[(size_t)(n0 + nn) * D_ + k0 + tx] = f2h(tile[tx][nn]);
  }
}

// W [Kd][Nd] f32 -> Th[n*sh+k] fp16 (transposed). For W_out.
__global__ void transpose_convert(const float* __restrict__ W, ushort* __restrict__ Th, int sh,
                                  int Kd, int Nd) {
  __shared__ float tile[64][65];
  const int k0 = blockIdx.x * 64, n0 = blockIdx.y * 64;
  const int tx = threadIdx.x & 63, ty = threadIdx.x >> 6;
#pragma unroll
  for (int i = 0; i < 16; ++i)
    tile[ty * 16 + i][tx] = W[(size_t)(k0 + ty * 16 + i) * Nd + n0 + tx];
  __syncthreads();
#pragma unroll
  for (int i = 0; i < 16; ++i) {
    const int nn = ty * 16 + i;
    Th[(size_t)(n0 + nn) * sh + k0 + tx] = f2h(tile[tx][nn]);
  }
}

// ------- 256x256 fp16 MFMA GEMM, 16x16x32 fragments, BK=32 -------
// 8 waves (2m x 4n), wave tile 128x64. LDS: 4 slice buffers x 32KB = 128 KB.
// Row-pair 128B lines, phys granule = ((row&1)*4 + kgran) ^ (line&7); conflicts=0
// (measured r7/r9/r11). T4 counted-vmcnt pipeline: prologue stages tiles 0-2;
// iter tt issues STAGE(tt+3) (clamped: always 4 loads -> fixed in-flight count);
// end-of-tile wait is vmcnt(8) — tile tt+1 landed, 8 loads stay in flight
// across the barrier (never drains to 0 in the main loop).
// !FINAL: writes fp16 planes Ch (col>>10 selects plane; plane 4 -> C4h).
// FINAL+SPLITK: grid 256, K halves; ks=0 -> Cf=out (+x+bias), ks=1 -> C4f partial.
template <int FINAL, int SPLITK>
__global__ __launch_bounds__(512, 2) void gemm256(
    const ushort* __restrict__ A, int lda, const ushort* __restrict__ Bw,
    ushort* __restrict__ Ch, ushort* __restrict__ C4h,
    float* __restrict__ Cf, float* __restrict__ C4f,
    const float* __restrict__ xres, const float* __restrict__ bias,
    int M, int K) {
  __shared__ __align__(16) char ldsc[4 * 32768];
  int bid = blockIdx.x, ks = 0;
  if (SPLITK && bid >= 128) { ks = 1; bid -= 128; }
  const int tm = bid & 31, tn = bid >> 5;
  const int Kb = SPLITK ? (K >> 1) : K;
  const int ldb = K;
  const int nB = tn << 8;
  if (SPLITK) { A += (size_t)ks * Kb; Bw += (size_t)ks * Kb; }
  const int NT = Kb >> 5;
  const int t = threadIdx.x, lane = t & 63, wid = t >> 6;
  const int wm = wid >> 2, wn = wid & 3;

  f32x4 acc[8][4];
#pragma unroll
  for (int i = 0; i < 8; ++i)
#pragma unroll
    for (int j = 0; j < 4; ++j) acc[i][j] = (f32x4){0.f, 0.f, 0.f, 0.f};

  // ---- staging: linear LDS dest t*16; inverse-swizzled global source ----
  const int line1 = t >> 3;
  const int g8s = (t & 7) ^ (line1 & 7);
  const int rowS = line1 * 2 + (g8s >> 2);
  const int kgS = (g8s & 3) << 3;
  const ushort* srcA = A + (size_t)(tm * 256 + rowS) * lda + kgS;
  const ushort* srcB = Bw + (size_t)(nB + rowS) * ldb + kgS;
  char* dstA = ldsc + (size_t)t * 16;
  char* dstB = ldsc + 16384 + (size_t)t * 16;

  auto STAGE = [&](int tile) {
    const int ts = (tile < NT) ? tile : NT - 1;  // clamp: ALWAYS 4 loads (vmcnt fixed)
    char* ba = dstA + (tile & 3) * 32768;
    char* bb = dstB + (tile & 3) * 32768;
    const ushort* sa = srcA + ts * 32;
    const ushort* sb = srcB + ts * 32;
    gload16(sa, ba);
    gload16(sa + (size_t)128 * lda, ba + 8192);
    gload16(sb, bb);
    gload16(sb + (size_t)128 * ldb, bb + 8192);
  };

  // ---- fragment reads (16x16x32): row = f*16 + lane15, kgran = lane>>4 ----
  const int lane15 = lane & 15;
  const int hl = lane15 >> 1;  // half-line (line&7 within any 8-line-aligned block)
  const int swz = ((((lane15 & 1) << 2) + (lane >> 4)) ^ hl) << 4;
  const char* aB = ldsc + wm * 8192 + hl * 128 + swz;
  const char* bB = ldsc + 16384 + wn * 4096 + hl * 128 + swz;

  // prologue: 3 tiles staged (12 loads in flight); wait for tile 0 only
  STAGE(0); STAGE(1); STAGE(2);
  asm volatile("s_waitcnt vmcnt(8)" ::: "memory");
  __builtin_amdgcn_sched_barrier(0);
  __builtin_amdgcn_s_barrier();

#pragma unroll 1
  for (int tt = 0; tt < NT; ++tt) {
    STAGE(tt + 3);  // in flight: tiles tt+1, tt+2, tt+3 (12 loads)
    const char* ab = aB + (tt & 3) * 32768;
    const char* bb = bB + (tt & 3) * 32768;
    f16x8 af[4], bf_[4], af2[4];
#pragma unroll
    for (int f = 0; f < 4; ++f) af[f] = *(const f16x8*)(ab + f * 1024);
#pragma unroll
    for (int c = 0; c < 4; ++c) bf_[c] = *(const f16x8*)(bb + c * 1024);
#pragma unroll
    for (int f = 0; f < 4; ++f) af2[f] = *(const f16x8*)(ab + 4096 + f * 1024);
    asm volatile("s_waitcnt lgkmcnt(4)" ::: "memory");  // af+bf landed (af2 in flight)
    __builtin_amdgcn_sched_barrier(0);
    __builtin_amdgcn_s_setprio(1);
#pragma unroll
    for (int f = 0; f < 4; ++f)
#pragma unroll
      for (int c = 0; c < 4; ++c)
        acc[f][c] = __builtin_amdgcn_mfma_f32_16x16x32_f16(af[f], bf_[c], acc[f][c], 0, 0, 0);
    __builtin_amdgcn_s_setprio(0);
    asm volatile("s_waitcnt lgkmcnt(0)" ::: "memory");
    __builtin_amdgcn_sched_barrier(0);
    __builtin_amdgcn_s_setprio(1);
#pragma unroll
    for (int f = 0; f < 4; ++f)
#pragma unroll
      for (int c = 0; c < 4; ++c)
        acc[4 + f][c] = __builtin_amdgcn_mfma_f32_16x16x32_f16(af2[f], bf_[c], acc[4 + f][c], 0, 0, 0);
    __builtin_amdgcn_s_setprio(0);
    // counted wait: oldest stage (tile tt+1) landed; 8 loads stay in flight
    asm volatile("s_waitcnt vmcnt(8)" ::: "memory");
    __builtin_amdgcn_sched_barrier(0);
    __builtin_amdgcn_s_barrier();
  }

  // epilogue. C/D layout: col=lane&15, row=(lane>>4)*4+reg  [m89-verified]
#pragma unroll
  for (int i = 0; i < 8; ++i) {
    const int row0 = tm * 256 + wm * 128 + i * 16 + ((lane >> 4) << 2);
#pragma unroll
    for (int jj = 0; jj < 4; ++jj) {
      const int col = tn * 256 + wn * 64 + jj * 16 + lane15;
      if (SPLITK && ks) {  // partial: plain fp32 store to C4f
#pragma unroll
        for (int r = 0; r < 4; ++r)
          C4f[(size_t)(row0 + r) * 1024 + col] = acc[i][jj][r];
      } else if (FINAL) {
#pragma unroll
        for (int r = 0; r < 4; ++r) {
          const size_t idx = (size_t)(row0 + r) * 1024 + col;
          Cf[idx] = acc[i][jj][r] + xres[idx] + bias[col];
        }
      } else {
        const int pl = col >> 10;
        ushort* base = (pl < 4) ? (Ch + (size_t)pl * (size_t)M * 1024) : C4h;
#pragma unroll
        for (int r = 0; r < 4; ++r)
          base[(size_t)(row0 + r) * 1024 + (col & 1023)] = f2h(acc[i][jj][r]);
      }
    }
  }
}

// split-K merge: out += partial
__global__ void add_kernel(float* __restrict__ out, const float* __restrict__ p) {
  size_t i = ((size_t)blockIdx.x * blockDim.x + threadIdx.x) * 4;
  if (i >= NELEM) return;
  float4 a = *(const float4*)(out + i);
  float4 b = *(const float4*)(p + i);
  a.x += b.x; a.y += b.y; a.z += b.z; a.w += b.w;
  *(float4*)(out + i) = a;
}

// ---------------- fused elementwise / scan passes (fp16 planes + fp16 x) ----------------

__device__ __forceinline__ void load4h(const ushort* p, float* f) {
  ushort4 u = *(const ushort4*)p;
  f[0] = h2f(u.x); f[1] = h2f(u.y); f[2] = h2f(u.z); f[3] = h2f(u.w);
}

// P1+P2: gating/sigmoid transforms in place (fp16) + per-(b,chunk,d) fp32 sums
__global__ void prep_chunk_kernel(ushort* __restrict__ omega_go, const ushort* __restrict__ gate_lin,
                                  ushort* __restrict__ mag_io,
                                  const float* __restrict__ b_om, const float* __restrict__ b_gate,
                                  const float* __restrict__ b_mag, const float* __restrict__ isc,
                                  float* __restrict__ gsum, float* __restrict__ msum) {
  int tid = blockIdx.x * blockDim.x + threadIdx.x;
  if (tid >= B_ * CCH * (D_ / 4)) return;
  int d4 = tid & 255, c = (tid >> 8) & (CCH - 1), b = tid >> 14;
  int d = d4 * 4;
  size_t base = ((size_t)(b * S_) + c * LCH) * D_ + d;
  size_t cs = ((size_t)(b * CCH) + c) * D_ + d;
  float bo[4], bg[4], bm[4], is[4];
  *(float4*)bo = *(const float4*)(b_om + d);
  *(float4*)bg = *(const float4*)(b_gate + d);
  *(float4*)bm = *(const float4*)(b_mag + d);
  *(float4*)is = *(const float4*)(isc + d);
  float sg[4] = {0.f, 0.f, 0.f, 0.f}, sm[4] = {0.f, 0.f, 0.f, 0.f};
  for (int s = 0; s < LCH; ++s) {
    size_t i = base + (size_t)s * D_;
    float om[4], gl[4], mg[4];
    load4h(omega_go + i, om);
    load4h(gate_lin + i, gl);
    load4h(mag_io + i, mg);
    ushort wo[4], wm_[4];
#pragma unroll
    for (int j = 0; j < 4; ++j) {
      float g = 1.f / (1.f + __expf(-(gl[j] + bg[j])));
      float m5 = 5.f / (1.f + __expf(-(mg[j] + bm[j])));
      float go = g * ((om[j] + bo[j]) * fabsf(is[j]));
      sg[j] += go;
      sm[j] += m5;
      wo[j] = f2h(go);
      wm_[j] = f2h(m5);
    }
    *(ushort4*)(omega_go + i) = *(ushort4*)wo;
    *(ushort4*)(mag_io + i) = *(ushort4*)wm_;
  }
  *(float4*)(gsum + cs) = *(float4*)sg;
  *(float4*)(msum + cs) = *(float4*)sm;
}

// P3/P5: exclusive scan of chunk totals along c — wave-parallel (lane = chunk)
__global__ void scan_offsets_kernel(float* __restrict__ s1, float* __restrict__ s2) {
  int gw = (blockIdx.x * blockDim.x + threadIdx.x) >> 6;
  int lane = threadIdx.x & 63;
  if (gw >= B_ * D_) return;
  int d = gw & (D_ - 1), b = gw >> 10;
  size_t idx = ((size_t)(b * CCH) + lane) * D_ + d;
  float v1 = s1[idx], v2 = s2[idx];
#pragma unroll
  for (int off = 1; off < 64; off <<= 1) {
    float u1 = __shfl_up(v1, off);
    float u2 = __shfl_up(v2, off);
    if (lane >= off) { v1 += u1; v2 += u2; }
  }
  float e1 = __shfl_up(v1, 1), e2 = __shfl_up(v2, 1);
  if (lane == 0) { e1 = 0.f; e2 = 0.f; }
  s1[idx] = e1;
  s2[idx] = e2;
}

// P4 (slim): chunked scan -> ctx parts 0,1 + tr/ti chunk totals. Planes untouched.
__global__ void phase_scan_kernel(const ushort* __restrict__ xh, const ushort* __restrict__ go,
                                  const ushort* __restrict__ mag, const ushort* __restrict__ p0,
                                  const float* __restrict__ goff,
                                  float* __restrict__ trsum, float* __restrict__ tisum,
                                  const float* __restrict__ b_phi, ushort* __restrict__ ctx) {
  int tid = blockIdx.x * blockDim.x + threadIdx.x;
  if (tid >= B_ * CCH * (D_ / 4)) return;
  int d4 = tid & 255, c = (tid >> 8) & (CCH - 1), b = tid >> 14;
  int d = d4 * 4;
  size_t base = ((size_t)(b * S_) + c * LCH) * D_ + d;
  size_t cs = ((size_t)(b * CCH) + c) * D_ + d;
  float pr[4], bp[4];
  *(float4*)pr = *(const float4*)(goff + cs);
  *(float4*)bp = *(const float4*)(b_phi + d);
  float tr[4] = {0.f, 0.f, 0.f, 0.f}, ti[4] = {0.f, 0.f, 0.f, 0.f};
  size_t crow = ((size_t)(b * S_ + c * LCH)) * 4096 + d;
  for (int s = 0; s < LCH; ++s) {
    size_t i = base + (size_t)s * D_;
    float g[4], ph0[4], m[4], xv[4];
    load4h(go + i, g);
    load4h(p0 + i, ph0);
    load4h(mag + i, m);
    load4h(xh + i, xv);
    ushort c4[4], s4[4];
#pragma unroll
    for (int j = 0; j < 4; ++j) {
      pr[j] += g[j];
      float ph = ph0[j] + bp[j] + pr[j];
      float sp, cp;
      __sincosf(ph, &sp, &cp);
      float wr = m[j] * xv[j];
      tr[j] += wr * cp;
      ti[j] += wr * sp;
      c4[j] = f2h(xv[j] * cp);
      s4[j] = f2h(xv[j] * sp);
    }
    *(ushort4*)(ctx + crow) = *(ushort4*)c4;
    *(ushort4*)(ctx + crow + 1024) = *(ushort4*)s4;
    crow += 4096;
  }
  *(float4*)(trsum + cs) = *(float4*)tr;
  *(float4*)(tisum + cs) = *(float4*)ti;
}

// P6 (recompute): re-run the chunk chains, normalize + retrieve -> ctx parts 2,3
__global__ void retrieve_kernel(const ushort* __restrict__ xh, const ushort* __restrict__ go,
                                const ushort* __restrict__ mag, const ushort* __restrict__ p0,
                                const ushort* __restrict__ q,
                                const float* __restrict__ goff, const float* __restrict__ moff,
                                const float* __restrict__ troff, const float* __restrict__ tioff,
                                const float* __restrict__ b_phi, const float* __restrict__ b_q,
                                ushort* __restrict__ ctx) {
  int tid = blockIdx.x * blockDim.x + threadIdx.x;
  if (tid >= B_ * CCH * (D_ / 4)) return;
  int d4 = tid & 255, c = (tid >> 8) & (CCH - 1), b = tid >> 14;
  int d = d4 * 4;
  size_t base = ((size_t)(b * S_) + c * LCH) * D_ + d;
  size_t cs = ((size_t)(b * CCH) + c) * D_ + d;
  float pr[4], mr[4], tr[4], ti[4], bp[4], bq[4];
  *(float4*)pr = *(const float4*)(goff + cs);
  *(float4*)mr = *(const float4*)(moff + cs);
  *(float4*)tr = *(const float4*)(troff + cs);
  *(float4*)ti = *(const float4*)(tioff + cs);
  *(float4*)bp = *(const float4*)(b_phi + d);
  *(float4*)bq = *(const float4*)(b_q + d);
  size_t crow = ((size_t)(b * S_ + c * LCH)) * 4096 + d;
  for (int s = 0; s < LCH; ++s) {
    size_t i = base + (size_t)s * D_;
    float g[4], ph0[4], m[4], xv[4], qv[4];
    load4h(go + i, g);
    load4h(p0 + i, ph0);
    load4h(mag + i, m);
    load4h(q + i, qv);
    load4h(xh + i, xv);
    ushort r2[4], r3[4];
#pragma unroll
    for (int j = 0; j < 4; ++j) {
      pr[j] += g[j];
      float ph = ph0[j] + bp[j] + pr[j];
      float sp, cp;
      __sincosf(ph, &sp, &cp);
      mr[j] += m[j];
      float wr = m[j] * xv[j];
      tr[j] += wr * cp;
      ti[j] += wr * sp;
      float rs = rsqrtf(mr[j] + 1e-8f);
      float mreal = tr[j] * rs, mimag = ti[j] * rs;
      float phq = ph + qv[j] + bq[j];
      float sq, cq;
      __sincosf(phq, &sq, &cq);
      r2[j] = f2h(mreal * cq + mimag * sq);
      r3[j] = f2h(mimag * cq - mreal * sq);
    }
    *(ushort4*)(ctx + crow + 2048) = *(ushort4*)r2;
    *(ushort4*)(ctx + crow + 3072) = *(ushort4*)r3;
    crow += 4096;
  }
}

// ---------------- launcher ----------------
extern "C" void kernel_launch(void* const* d_in, const int* in_sizes, int n_in,
                              void* d_out, int out_size, void* d_ws, size_t ws_size,
                              hipStream_t stream) {
  const float* x      = (const float*)d_in[0];
  const float* W_om   = (const float*)d_in[1];
  const float* b_om   = (const float*)d_in[2];
  const float* W_mag  = (const float*)d_in[3];
  const float* b_mag  = (const float*)d_in[4];
  const float* W_phi  = (const float*)d_in[5];
  const float* b_phi  = (const float*)d_in[6];
  const float* W_gate = (const float*)d_in[7];
  const float* b_gate = (const float*)d_in[8];
  const float* W_q    = (const float*)d_in[9];
  const float* b_q    = (const float*)d_in[10];
  const float* isc    = (const float*)d_in[11];
  const float* W_out  = (const float*)d_in[12];
  const float* b_out  = (const float*)d_in[13];
  float* out = (float*)d_out;

  // ---- ws layout, 213,909,504 bytes ----
  // [0, 67108864)          4 fp16 planes: omega|gate|mag|phi0
  //   [0, 33554432)        fp32 splitK partial (aliases omega/gate, dead post-retrieve)
  // [67108864, 83886080)   x_h fp16 [8192][1024] (lives through retrieve)
  // [134217728, 201326592) ctx fp16 [8192][4096]; W5T (10.5MB, dead after GEMM1)
  //                        overlapped at +16777216
  // [201326592)            WoutT [1024][4096] fp16
  // [209715200)            gsum|msum|trsum|tisum (4 x 1MB)
  // q_lin (fp16) lives in d_out (overwritten by the final GEMM afterwards).
  const size_t WS_NEEDED = 213909504ull;
  if (ws_size < WS_NEEDED) {
    (void)hipMemsetAsync(d_out, 0, (size_t)out_size * sizeof(float), stream);
    return;
  }
  char* w = (char*)d_ws;
  ushort* planes_h = (ushort*)w;                      // 4 x NELEM fp16
  ushort* omega_buf = planes_h;
  ushort* gate_buf  = planes_h + NELEM;
  ushort* mag_buf   = planes_h + 2 * NELEM;
  ushort* phi0_buf  = planes_h + 3 * NELEM;
  float* partial    = (float*)w;                      // fp32, reused after retrieve
  ushort* x_h   = (ushort*)(w + 67108864);            // [8192][1024] fp16
  ushort* q_buf = (ushort*)out;                       // fp16 q plane in d_out
  char* ctxb = w + 4 * NELEM * 4;
  ushort* ctx   = (ushort*)ctxb;
  ushort* W5T   = (ushort*)(ctxb + 16777216);         // [5120][1024]: om|gate|mag|phi0|q
  ushort* WoutT = (ushort*)(w + 201326592);           // [1024][4096]
  float* gsum  = (float*)(w + 209715200);
  float* msum  = (float*)(w + 210763776);
  float* trsum = (float*)(w + 211812352);
  float* tisum = (float*)(w + 212860928);

  const size_t DD = (size_t)D_ * D_;

  // conversions (batched)
  xhalf_kernel<<<(int)(NELEM / 2048), 256, 0, stream>>>(x, x_h);
  transpose5<<<dim3(16, 16, 5), 256, 0, stream>>>(W_om, W_gate, W_mag, W_phi, W_q, W5T);
  transpose_convert<<<dim3(64, 16), 256, 0, stream>>>(W_out, WoutT, 4096, 4 * D_, D_);

  // GEMM1: 5 projections, N=5120, K=1024, fp16 in/out. q plane -> d_out scratch.
  gemm256<0, 0><<<640, 512, 0, stream>>>(x_h, 1024, W5T, planes_h, q_buf,
                                         nullptr, nullptr, nullptr, nullptr, MROWS, 1024);

  // scans + fused elementwise
  prep_chunk_kernel<<<B_ * CCH * (D_ / 4) / 256, 256, 0, stream>>>(
      omega_buf, gate_buf, mag_buf, b_om, b_gate, b_mag, isc, gsum, msum);
  scan_offsets_kernel<<<B_ * D_ * 64 / 256, 256, 0, stream>>>(gsum, msum);
  phase_scan_kernel<<<B_ * CCH * (D_ / 4) / 256, 256, 0, stream>>>(
      x_h, omega_buf, mag_buf, phi0_buf, gsum, trsum, tisum, b_phi, ctx);
  scan_offsets_kernel<<<B_ * D_ * 64 / 256, 256, 0, stream>>>(trsum, tisum);
  retrieve_kernel<<<B_ * CCH * (D_ / 4) / 256, 256, 0, stream>>>(
      x_h, omega_buf, mag_buf, phi0_buf, q_buf, gsum, msum, trsum, tisum, b_phi, b_q, ctx);

  // final: out = x + ctx @ W_out + b_out, split-K x2 (256 blocks, full GPU).
  gemm256<1, 1><<<256, 512, 0, stream>>>(ctx, 4096, WoutT, nullptr, nullptr, out, partial,
                                         x, b_out, MROWS, 4 * D_);
  add_kernel<<<(int)(NELEM / 1024), 256, 0, stream>>>(out, partial);
}

// Round 13
// 291.113 us; speedup vs baseline: 1.8137x; 1.0899x over previous
//
#include <hip/hip_runtime.h>
#include <hip/hip_fp16.h>

// Problem constants (B,S,D fixed by the reference)
#define B_ 4
#define S_ 2048
#define D_ 1024
#define CCH 64                    // chunks along S
#define LCH 32                    // chunk length; CCH*LCH == S_
#define NELEM ((size_t)B_*S_*D_)  // 8388608
#define MROWS (B_*S_)             // 8192

typedef __attribute__((ext_vector_type(4))) float f32x4;
typedef __attribute__((ext_vector_type(8))) _Float16 f16x8;  // 8 x fp16 fragment

__device__ __forceinline__ ushort f2h(float v) {
  __half h = __float2half(v);
  return __builtin_bit_cast(ushort, h);
}
__device__ __forceinline__ float h2f(ushort u) {
  return __half2float(__builtin_bit_cast(__half, u));
}

__device__ __forceinline__ void gload16(const ushort* src, char* ldsdst) {
  __builtin_amdgcn_global_load_lds(
      (const __attribute__((address_space(1))) void*)src,
      (__attribute__((address_space(3))) void*)ldsdst, 16, 0, 0);
}

// ---------------- conversions ----------------

// x -> fp16 [M][1024]
__global__ void xhalf_kernel(const float* __restrict__ x, ushort* __restrict__ xh) {
  size_t i = ((size_t)blockIdx.x * blockDim.x + threadIdx.x) * 8;
  if (i >= NELEM) return;
  float4 a = *(const float4*)(x + i);
  float4 b = *(const float4*)(x + i + 4);
  ushort h[8] = {f2h(a.x), f2h(a.y), f2h(a.z), f2h(a.w),
                 f2h(b.x), f2h(b.y), f2h(b.z), f2h(b.w)};
  *(ushort4*)(xh + i) = *(ushort4*)h;
  *(ushort4*)(xh + i + 4) = *(ushort4*)(h + 4);
}

// Five D x D weights -> W5T[z][n][k] fp16 (transposed), one launch (z selects W).
__global__ void transpose5(const float* __restrict__ W0, const float* __restrict__ W1,
                           const float* __restrict__ W2, const float* __restrict__ W3,
                           const float* __restrict__ W4, ushort* __restrict__ Th) {
  __shared__ float tile[64][65];  // +1 pad: conflict-free column reads
  const int z = blockIdx.z;
  const float* W = (z == 0) ? W0 : (z == 1) ? W1 : (z == 2) ? W2 : (z == 3) ? W3 : W4;
  ushort* T = Th + (size_t)z * D_ * D_;
  const int k0 = blockIdx.x * 64, n0 = blockIdx.y * 64;
  const int tx = threadIdx.x & 63, ty = threadIdx.x >> 6;  // 64 x 4
#pragma unroll
  for (int i = 0; i < 16; ++i)
    tile[ty * 16 + i][tx] = W[(size_t)(k0 + ty * 16 + i) * D_ + n0 + tx];
  __syncthreads();
#pragma unroll
  for (int i = 0; i < 16; ++i) {
    const int nn = ty * 16 + i;
    T[(size_t)(n0 + nn) * D_ + k0 + tx] = f2h(tile[tx][nn]);
  }
}

// W [Kd][Nd] f32 -> Th[n*sh+k] fp16 (transposed). For W_out.
__global__ void transpose_convert(const float* __restrict__ W, ushort* __restrict__ Th, int sh,
                                  int Kd, int Nd) {
  __shared__ float tile[64][65];
  const int k0 = blockIdx.x * 64, n0 = blockIdx.y * 64;
  const int tx = threadIdx.x & 63, ty = threadIdx.x >> 6;
#pragma unroll
  for (int i = 0; i < 16; ++i)
    tile[ty * 16 + i][tx] = W[(size_t)(k0 + ty * 16 + i) * Nd + n0 + tx];
  __syncthreads();
#pragma unroll
  for (int i = 0; i < 16; ++i) {
    const int nn = ty * 16 + i;
    Th[(size_t)(n0 + nn) * sh + k0 + tx] = f2h(tile[tx][nn]);
  }
}

// ------- 128x256 fp16 MFMA GEMM, 16x16x32 fragments, BK=32 -------
// 8 waves (2m x 4n), wave tile 64x64. LDS: 3 slice buffers x 24KB = 72 KB
// (A 128x32 = 8KB | B 256x32 = 16KB) -> 2 blocks/CU (independent barriers:
// cross-block overlap). Row-pair 128B lines, phys granule =
// ((row&1)*4 + kgran) ^ (line&7); conflicts = 0 (measured r7/r9/r11).
// Depth-2 counted pipeline: prologue stages tiles 0,1; iter tt issues
// STAGE(tt+2) (clamped: always 3 loads); end-of-tile wait vmcnt(3) —
// tile tt+1 landed, 3 loads stay in flight across the barrier.
// !FINAL: writes fp16 planes Ch (col>>10 selects plane; plane 4 -> C4h).
// FINAL: Cf = acc + xres + bias (fp32 out).
template <int FINAL>
__global__ __launch_bounds__(512, 2) void gemm128(
    const ushort* __restrict__ A, int lda, const ushort* __restrict__ Bw,
    ushort* __restrict__ Ch, ushort* __restrict__ C4h,
    float* __restrict__ Cf, const float* __restrict__ xres, const float* __restrict__ bias,
    int M, int K) {
  __shared__ __align__(16) char ldsc[3 * 24576];
  const int bid = blockIdx.x;
  const int tm = bid & 63, tn = bid >> 6;
  const int ldb = K;
  const int NT = K >> 5;
  const int t = threadIdx.x, lane = t & 63, wid = t >> 6;
  const int wm = wid >> 2, wn = wid & 3;

  f32x4 acc[4][4];
#pragma unroll
  for (int i = 0; i < 4; ++i)
#pragma unroll
    for (int j = 0; j < 4; ++j) acc[i][j] = (f32x4){0.f, 0.f, 0.f, 0.f};

  // ---- staging: linear LDS dest t*16; inverse-swizzled global source ----
  const int line1 = t >> 3;
  const int g8s = (t & 7) ^ (line1 & 7);
  const int rowS = line1 * 2 + (g8s >> 2);   // 0..127
  const int kgS = (g8s & 3) << 3;
  const ushort* srcA = A + (size_t)(tm * 128 + rowS) * lda + kgS;
  const ushort* srcB = Bw + (size_t)(tn * 256 + rowS) * ldb + kgS;
  char* dstA = ldsc + (size_t)t * 16;
  char* dstB = ldsc + 8192 + (size_t)t * 16;

  auto STAGE = [&](int tile, int slot) {
    const int ts = (tile < NT) ? tile : NT - 1;  // clamp: ALWAYS 3 loads (vmcnt fixed)
    char* ba = dstA + slot * 24576;
    char* bb = dstB + slot * 24576;
    const ushort* sa = srcA + ts * 32;
    const ushort* sb = srcB + ts * 32;
    gload16(sa, ba);
    gload16(sb, bb);
    gload16(sb + (size_t)128 * ldb, bb + 8192);
  };

  // ---- fragment reads (16x16x32): row = f*16 + lane15, kgran = lane>>4 ----
  const int lane15 = lane & 15;
  const int hl = lane15 >> 1;
  const int swz = ((((lane15 & 1) << 2) + (lane >> 4)) ^ hl) << 4;
  const char* aB = ldsc + wm * 4096 + hl * 128 + swz;
  const char* bB = ldsc + 8192 + wn * 4096 + hl * 128 + swz;

  // prologue: 2 tiles staged (6 loads in flight); wait for tile 0 only
  STAGE(0, 0); STAGE(1, 1);
  asm volatile("s_waitcnt vmcnt(3)" ::: "memory");
  __builtin_amdgcn_sched_barrier(0);
  __builtin_amdgcn_s_barrier();

  int s_rd = 0, s_st = 2;
#pragma unroll 1
  for (int tt = 0; tt < NT; ++tt) {
    STAGE(tt + 2, s_st);  // in flight: tiles tt+1, tt+2 (6 loads)
    const char* ab = aB + s_rd * 24576;
    const char* bb = bB + s_rd * 24576;
    f16x8 af[4], bf_[4];
#pragma unroll
    for (int f = 0; f < 4; ++f) af[f] = *(const f16x8*)(ab + f * 1024);
#pragma unroll
    for (int c = 0; c < 4; ++c) bf_[c] = *(const f16x8*)(bb + c * 1024);
    asm volatile("s_waitcnt lgkmcnt(0)" ::: "memory");
    __builtin_amdgcn_sched_barrier(0);
    __builtin_amdgcn_s_setprio(1);
#pragma unroll
    for (int f = 0; f < 4; ++f)
#pragma unroll
      for (int c = 0; c < 4; ++c)
        acc[f][c] = __builtin_amdgcn_mfma_f32_16x16x32_f16(af[f], bf_[c], acc[f][c], 0, 0, 0);
    __builtin_amdgcn_s_setprio(0);
    // counted wait: oldest stage (tile tt+1) landed; 3 loads stay in flight
    asm volatile("s_waitcnt vmcnt(3)" ::: "memory");
    __builtin_amdgcn_sched_barrier(0);
    __builtin_amdgcn_s_barrier();
    s_rd = (s_rd == 2) ? 0 : s_rd + 1;
    s_st = (s_st == 2) ? 0 : s_st + 1;
  }

  // epilogue. C/D layout: col=lane&15, row=(lane>>4)*4+reg  [m89-verified]
#pragma unroll
  for (int i = 0; i < 4; ++i) {
    const int row0 = tm * 128 + wm * 64 + i * 16 + ((lane >> 4) << 2);
#pragma unroll
    for (int jj = 0; jj < 4; ++jj) {
      const int col = tn * 256 + wn * 64 + jj * 16 + lane15;
      if (FINAL) {
#pragma unroll
        for (int r = 0; r < 4; ++r) {
          const size_t idx = (size_t)(row0 + r) * 1024 + col;
          Cf[idx] = acc[i][jj][r] + xres[idx] + bias[col];
        }
      } else {
        const int pl = col >> 10;
        ushort* base = (pl < 4) ? (Ch + (size_t)pl * (size_t)M * 1024) : C4h;
#pragma unroll
        for (int r = 0; r < 4; ++r)
          base[(size_t)(row0 + r) * 1024 + (col & 1023)] = f2h(acc[i][jj][r]);
      }
    }
  }
}

// ---------------- fused elementwise / scan passes (fp16 planes + fp16 x) ----------------

__device__ __forceinline__ void load4h(const ushort* p, float* f) {
  ushort4 u = *(const ushort4*)p;
  f[0] = h2f(u.x); f[1] = h2f(u.y); f[2] = h2f(u.z); f[3] = h2f(u.w);
}

// P1+P2: gating/sigmoid transforms in place (fp16) + per-(b,chunk,d) fp32 sums
__global__ void prep_chunk_kernel(ushort* __restrict__ omega_go, const ushort* __restrict__ gate_lin,
                                  ushort* __restrict__ mag_io,
                                  const float* __restrict__ b_om, const float* __restrict__ b_gate,
                                  const float* __restrict__ b_mag, const float* __restrict__ isc,
                                  float* __restrict__ gsum, float* __restrict__ msum) {
  int tid = blockIdx.x * blockDim.x + threadIdx.x;
  if (tid >= B_ * CCH * (D_ / 4)) return;
  int d4 = tid & 255, c = (tid >> 8) & (CCH - 1), b = tid >> 14;
  int d = d4 * 4;
  size_t base = ((size_t)(b * S_) + c * LCH) * D_ + d;
  size_t cs = ((size_t)(b * CCH) + c) * D_ + d;
  float bo[4], bg[4], bm[4], is[4];
  *(float4*)bo = *(const float4*)(b_om + d);
  *(float4*)bg = *(const float4*)(b_gate + d);
  *(float4*)bm = *(const float4*)(b_mag + d);
  *(float4*)is = *(const float4*)(isc + d);
  float sg[4] = {0.f, 0.f, 0.f, 0.f}, sm[4] = {0.f, 0.f, 0.f, 0.f};
  for (int s = 0; s < LCH; ++s) {
    size_t i = base + (size_t)s * D_;
    float om[4], gl[4], mg[4];
    load4h(omega_go + i, om);
    load4h(gate_lin + i, gl);
    load4h(mag_io + i, mg);
    ushort wo[4], wm_[4];
#pragma unroll
    for (int j = 0; j < 4; ++j) {
      float g = 1.f / (1.f + __expf(-(gl[j] + bg[j])));
      float m5 = 5.f / (1.f + __expf(-(mg[j] + bm[j])));
      float go = g * ((om[j] + bo[j]) * fabsf(is[j]));
      sg[j] += go;
      sm[j] += m5;
      wo[j] = f2h(go);
      wm_[j] = f2h(m5);
    }
    *(ushort4*)(omega_go + i) = *(ushort4*)wo;
    *(ushort4*)(mag_io + i) = *(ushort4*)wm_;
  }
  *(float4*)(gsum + cs) = *(float4*)sg;
  *(float4*)(msum + cs) = *(float4*)sm;
}

// P3/P5: exclusive scan of chunk totals along c — wave-parallel (lane = chunk)
__global__ void scan_offsets_kernel(float* __restrict__ s1, float* __restrict__ s2) {
  int gw = (blockIdx.x * blockDim.x + threadIdx.x) >> 6;
  int lane = threadIdx.x & 63;
  if (gw >= B_ * D_) return;
  int d = gw & (D_ - 1), b = gw >> 10;
  size_t idx = ((size_t)(b * CCH) + lane) * D_ + d;
  float v1 = s1[idx], v2 = s2[idx];
#pragma unroll
  for (int off = 1; off < 64; off <<= 1) {
    float u1 = __shfl_up(v1, off);
    float u2 = __shfl_up(v2, off);
    if (lane >= off) { v1 += u1; v2 += u2; }
  }
  float e1 = __shfl_up(v1, 1), e2 = __shfl_up(v2, 1);
  if (lane == 0) { e1 = 0.f; e2 = 0.f; }
  s1[idx] = e1;
  s2[idx] = e2;
}

// P4 (slim): chunked scan -> ctx parts 0,1 + tr/ti chunk totals. Planes untouched.
__global__ void phase_scan_kernel(const ushort* __restrict__ xh, const ushort* __restrict__ go,
                                  const ushort* __restrict__ mag, const ushort* __restrict__ p0,
                                  const float* __restrict__ goff,
                                  float* __restrict__ trsum, float* __restrict__ tisum,
                                  const float* __restrict__ b_phi, ushort* __restrict__ ctx) {
  int tid = blockIdx.x * blockDim.x + threadIdx.x;
  if (tid >= B_ * CCH * (D_ / 4)) return;
  int d4 = tid & 255, c = (tid >> 8) & (CCH - 1), b = tid >> 14;
  int d = d4 * 4;
  size_t base = ((size_t)(b * S_) + c * LCH) * D_ + d;
  size_t cs = ((size_t)(b * CCH) + c) * D_ + d;
  float pr[4], bp[4];
  *(float4*)pr = *(const float4*)(goff + cs);
  *(float4*)bp = *(const float4*)(b_phi + d);
  float tr[4] = {0.f, 0.f, 0.f, 0.f}, ti[4] = {0.f, 0.f, 0.f, 0.f};
  size_t crow = ((size_t)(b * S_ + c * LCH)) * 4096 + d;
  for (int s = 0; s < LCH; ++s) {
    size_t i = base + (size_t)s * D_;
    float g[4], ph0[4], m[4], xv[4];
    load4h(go + i, g);
    load4h(p0 + i, ph0);
    load4h(mag + i, m);
    load4h(xh + i, xv);
    ushort c4[4], s4[4];
#pragma unroll
    for (int j = 0; j < 4; ++j) {
      pr[j] += g[j];
      float ph = ph0[j] + bp[j] + pr[j];
      float sp, cp;
      __sincosf(ph, &sp, &cp);
      float wr = m[j] * xv[j];
      tr[j] += wr * cp;
      ti[j] += wr * sp;
      c4[j] = f2h(xv[j] * cp);
      s4[j] = f2h(xv[j] * sp);
    }
    *(ushort4*)(ctx + crow) = *(ushort4*)c4;
    *(ushort4*)(ctx + crow + 1024) = *(ushort4*)s4;
    crow += 4096;
  }
  *(float4*)(trsum + cs) = *(float4*)tr;
  *(float4*)(tisum + cs) = *(float4*)ti;
}

// P6 (recompute): re-run the chunk chains, normalize + retrieve -> ctx parts 2,3
__global__ void retrieve_kernel(const ushort* __restrict__ xh, const ushort* __restrict__ go,
                                const ushort* __restrict__ mag, const ushort* __restrict__ p0,
                                const ushort* __restrict__ q,
                                const float* __restrict__ goff, const float* __restrict__ moff,
                                const float* __restrict__ troff, const float* __restrict__ tioff,
                                const float* __restrict__ b_phi, const float* __restrict__ b_q,
                                ushort* __restrict__ ctx) {
  int tid = blockIdx.x * blockDim.x + threadIdx.x;
  if (tid >= B_ * CCH * (D_ / 4)) return;
  int d4 = tid & 255, c = (tid >> 8) & (CCH - 1), b = tid >> 14;
  int d = d4 * 4;
  size_t base = ((size_t)(b * S_) + c * LCH) * D_ + d;
  size_t cs = ((size_t)(b * CCH) + c) * D_ + d;
  float pr[4], mr[4], tr[4], ti[4], bp[4], bq[4];
  *(float4*)pr = *(const float4*)(goff + cs);
  *(float4*)mr = *(const float4*)(moff + cs);
  *(float4*)tr = *(const float4*)(troff + cs);
  *(float4*)ti = *(const float4*)(tioff + cs);
  *(float4*)bp = *(const float4*)(b_phi + d);
  *(float4*)bq = *(const float4*)(b_q + d);
  size_t crow = ((size_t)(b * S_ + c * LCH)) * 4096 + d;
  for (int s = 0; s < LCH; ++s) {
    size_t i = base + (size_t)s * D_;
    float g[4], ph0[4], m[4], xv[4], qv[4];
    load4h(go + i, g);
    load4h(p0 + i, ph0);
    load4h(mag + i, m);
    load4h(q + i, qv);
    load4h(xh + i, xv);
    ushort r2[4], r3[4];
#pragma unroll
    for (int j = 0; j < 4; ++j) {
      pr[j] += g[j];
      float ph = ph0[j] + bp[j] + pr[j];
      float sp, cp;
      __sincosf(ph, &sp, &cp);
      mr[j] += m[j];
      float wr = m[j] * xv[j];
      tr[j] += wr * cp;
      ti[j] += wr * sp;
      float rs = rsqrtf(mr[j] + 1e-8f);
      float mreal = tr[j] * rs, mimag = ti[j] * rs;
      float phq = ph + qv[j] + bq[j];
      float sq, cq;
      __sincosf(phq, &sq, &cq);
      r2[j] = f2h(mreal * cq + mimag * sq);
      r3[j] = f2h(mimag * cq - mreal * sq);
    }
    *(ushort4*)(ctx + crow + 2048) = *(ushort4*)r2;
    *(ushort4*)(ctx + crow + 3072) = *(ushort4*)r3;
    crow += 4096;
  }
}

// ---------------- launcher ----------------
extern "C" void kernel_launch(void* const* d_in, const int* in_sizes, int n_in,
                              void* d_out, int out_size, void* d_ws, size_t ws_size,
                              hipStream_t stream) {
  const float* x      = (const float*)d_in[0];
  const float* W_om   = (const float*)d_in[1];
  const float* b_om   = (const float*)d_in[2];
  const float* W_mag  = (const float*)d_in[3];
  const float* b_mag  = (const float*)d_in[4];
  const float* W_phi  = (const float*)d_in[5];
  const float* b_phi  = (const float*)d_in[6];
  const float* W_gate = (const float*)d_in[7];
  const float* b_gate = (const float*)d_in[8];
  const float* W_q    = (const float*)d_in[9];
  const float* b_q    = (const float*)d_in[10];
  const float* isc    = (const float*)d_in[11];
  const float* W_out  = (const float*)d_in[12];
  const float* b_out  = (const float*)d_in[13];
  float* out = (float*)d_out;

  // ---- ws layout, 213,909,504 bytes ----
  // [0, 67108864)          4 fp16 planes: omega|gate|mag|phi0
  // [67108864, 83886080)   x_h fp16 [8192][1024] (lives through retrieve)
  // [134217728, 201326592) ctx fp16 [8192][4096]; W5T (10.5MB, dead after GEMM1)
  //                        overlapped at +16777216
  // [201326592)            WoutT [1024][4096] fp16
  // [209715200)            gsum|msum|trsum|tisum (4 x 1MB)
  // q_lin (fp16) lives in d_out (overwritten by the final GEMM afterwards).
  const size_t WS_NEEDED = 213909504ull;
  if (ws_size < WS_NEEDED) {
    (void)hipMemsetAsync(d_out, 0, (size_t)out_size * sizeof(float), stream);
    return;
  }
  char* w = (char*)d_ws;
  ushort* planes_h = (ushort*)w;                      // 4 x NELEM fp16
  ushort* omega_buf = planes_h;
  ushort* gate_buf  = planes_h + NELEM;
  ushort* mag_buf   = planes_h + 2 * NELEM;
  ushort* phi0_buf  = planes_h + 3 * NELEM;
  ushort* x_h   = (ushort*)(w + 67108864);            // [8192][1024] fp16
  ushort* q_buf = (ushort*)out;                       // fp16 q plane in d_out
  char* ctxb = w + 4 * NELEM * 4;
  ushort* ctx   = (ushort*)ctxb;
  ushort* W5T   = (ushort*)(ctxb + 16777216);         // [5120][1024]: om|gate|mag|phi0|q
  ushort* WoutT = (ushort*)(w + 201326592);           // [1024][4096]
  float* gsum  = (float*)(w + 209715200);
  float* msum  = (float*)(w + 210763776);
  float* trsum = (float*)(w + 211812352);
  float* tisum = (float*)(w + 212860928);

  // conversions (batched)
  xhalf_kernel<<<(int)(NELEM / 2048), 256, 0, stream>>>(x, x_h);
  transpose5<<<dim3(16, 16, 5), 256, 0, stream>>>(W_om, W_gate, W_mag, W_phi, W_q, W5T);
  transpose_convert<<<dim3(64, 16), 256, 0, stream>>>(W_out, WoutT, 4096, 4 * D_, D_);

  // GEMM1: 5 projections, N=5120, K=1024, fp16 in/out. 1280 blocks = 5 exact
  // rounds on 256 CUs (no grid quantization), 2 blocks/CU resident.
  gemm128<0><<<1280, 512, 0, stream>>>(x_h, 1024, W5T, planes_h, q_buf,
                                       nullptr, nullptr, nullptr, MROWS, 1024);

  // scans + fused elementwise
  prep_chunk_kernel<<<B_ * CCH * (D_ / 4) / 256, 256, 0, stream>>>(
      omega_buf, gate_buf, mag_buf, b_om, b_gate, b_mag, isc, gsum, msum);
  scan_offsets_kernel<<<B_ * D_ * 64 / 256, 256, 0, stream>>>(gsum, msum);
  phase_scan_kernel<<<B_ * CCH * (D_ / 4) / 256, 256, 0, stream>>>(
      x_h, omega_buf, mag_buf, phi0_buf, gsum, trsum, tisum, b_phi, ctx);
  scan_offsets_kernel<<<B_ * D_ * 64 / 256, 256, 0, stream>>>(trsum, tisum);
  retrieve_kernel<<<B_ * CCH * (D_ / 4) / 256, 256, 0, stream>>>(
      x_h, omega_buf, mag_buf, phi0_buf, q_buf, gsum, msum, trsum, tisum, b_phi, b_q, ctx);

  // final: out = x + ctx @ W_out + b_out. 256 exact blocks, K=4096 — no
  // split-K, no partial, no add_kernel.
  gemm128<1><<<256, 512, 0, stream>>>(ctx, 4096, WoutT, nullptr, nullptr, out,
                                      x, b_out, MROWS, 4 * D_);
}